// Round 3
// baseline (1964.505 us; speedup 1.0000x reference)
//
#include <hip/hip_runtime.h>
#include <hip/hip_bf16.h>
#include <math.h>

#define NB 4
#define NHW 4096

typedef const float* fp;

__device__ __forceinline__ float b2f(__hip_bfloat16 v) { return __bfloat162float(v); }
__device__ __forceinline__ __hip_bfloat16 f2b(float v) { return __float2bfloat16(v); }
__device__ __forceinline__ float gelu_ex(float x) { return 0.5f * x * (1.0f + erff(x * 0.70710678118654752f)); }

// ---------------- 1. bilinear upsample skip [4,64,32,32] -> su [4,64,64,64] f32
__global__ __launch_bounds__(256) void k_upsample(fp skip, float* su) {
  int idx = blockIdx.x * 256 + threadIdx.x;
  if (idx >= NB * 64 * NHW) return;
  int hw = idx & 4095, bc = idx >> 12;
  int y = hw >> 6, x = hw & 63;
  float fy = 0.5f * y - 0.25f, fx = 0.5f * x - 0.25f;
  float y0f = floorf(fy), x0f = floorf(fx);
  float wy = fy - y0f, wx = fx - x0f;
  int y0 = (int)y0f, x0 = (int)x0f;
  int y0c = min(31, max(0, y0)), y1c = min(31, max(0, y0 + 1));
  int x0c = min(31, max(0, x0)), x1c = min(31, max(0, x0 + 1));
  const float* p = skip + (size_t)bc * 1024;
  float v00 = p[y0c * 32 + x0c], v01 = p[y0c * 32 + x1c];
  float v10 = p[y1c * 32 + x0c], v11 = p[y1c * 32 + x1c];
  su[idx] = (1.f - wy) * ((1.f - wx) * v00 + wx * v01) + wy * ((1.f - wx) * v10 + wx * v11);
}

// ---------------- 2. qkv 1x1 conv: x[4,256,4096] -> qkv [4,96,4096] f32
__global__ __launch_bounds__(256) void k_qkv(fp x, fp w, fp bias, float* qkv) {
  int idx = blockIdx.x * 256 + threadIdx.x;
  if (idx >= NB * 96 * NHW) return;
  int hw = idx & 4095, t = idx >> 12;
  int o = t % 96, b = t / 96;
  const float* xin = x + (size_t)b * 256 * NHW + hw;
  const float* wr = w + o * 256;
  float acc = bias[o];
#pragma unroll 8
  for (int c = 0; c < 256; c++) acc += xin[(size_t)c * NHW] * wr[c];
  qkv[idx] = acc;
}

// ---------------- 3. attention: one wave per query token, online softmax
__global__ __launch_bounds__(256) void k_attn(const float* qkv, float* av) {
  __shared__ float kt[32][64];
  __shared__ float vt[32][64];
  int wave = threadIdx.x >> 6;
  int lane = threadIdx.x & 63;
  int qid = blockIdx.x * 4 + wave;      // [0, B*N); b uniform per block (4096%4==0)
  int b = qid >> 12;
  int n = qid & 4095;
  const float* qb = qkv + (size_t)(b * 96 + 0) * NHW;
  const float* kb = qkv + (size_t)(b * 96 + 32) * NHW;
  const float* vb = qkv + (size_t)(b * 96 + 64) * NHW;
  float qreg[32];
#pragma unroll
  for (int c = 0; c < 32; c++) qreg[c] = qb[c * NHW + n] * 0.17677669529663688f; // /sqrt(32)
  float m_i = -1e30f, l_i = 0.f;
  float acc[32];
#pragma unroll
  for (int c = 0; c < 32; c++) acc[c] = 0.f;

  for (int tile = 0; tile < 64; tile++) {
    int base = tile * 64;
    __syncthreads();
#pragma unroll
    for (int e = 0; e < 8; e++) {
      int flat = threadIdx.x + e * 256;   // 0..2047
      int c = flat >> 6, m = flat & 63;
      kt[c][m] = kb[c * NHW + base + m];
      vt[c][m] = vb[c * NHW + base + m];
    }
    __syncthreads();
    float s = 0.f;
#pragma unroll
    for (int c = 0; c < 32; c++) s += qreg[c] * kt[c][lane];
    float mnew = fmaxf(m_i, s);
    float alpha = __expf(m_i - mnew);
    float p = __expf(s - mnew);
    l_i = l_i * alpha + p;
#pragma unroll
    for (int c = 0; c < 32; c++) acc[c] = acc[c] * alpha + p * vt[c][lane];
    m_i = mnew;
  }
  float m_tot = m_i;
#pragma unroll
  for (int off = 32; off; off >>= 1) m_tot = fmaxf(m_tot, __shfl_xor(m_tot, off, 64));
  float f = __expf(m_i - m_tot);
  float lw = l_i * f;
#pragma unroll
  for (int off = 32; off; off >>= 1) lw += __shfl_xor(lw, off, 64);
  float inv = 1.f / lw;
#pragma unroll
  for (int c = 0; c < 32; c++) {
    float a = acc[c] * f;
#pragma unroll
    for (int off = 32; off; off >>= 1) a += __shfl_xor(a, off, 64);
    acc[c] = a * inv;
  }
  if (lane == 0) {
    float* o = av + (size_t)b * 32 * NHW + n;
#pragma unroll
    for (int c = 0; c < 32; c++) o[c * NHW] = acc[c];
  }
}

// ---------------- 4. proj 1x1 (32->256) + residual x -> x2 (bf16)
__global__ __launch_bounds__(256) void k_proj(const float* av, fp x, fp w, fp bias, __hip_bfloat16* x2) {
  int idx = blockIdx.x * 256 + threadIdx.x;
  if (idx >= NB * 256 * NHW) return;
  int hw = idx & 4095, t = idx >> 12;
  int o = t & 255, b = t >> 8;
  const float* a = av + (size_t)b * 32 * NHW + hw;
  const float* wr = w + o * 32;
  float acc = bias[o] + x[idx];
#pragma unroll
  for (int c = 0; c < 32; c++) acc += a[(size_t)c * NHW] * wr[c];
  x2[idx] = f2b(acc);
}

// ---------------- 5. channel mean + thick(sigmoid 1x1)
__global__ __launch_bounds__(256) void k_meanthick(const float* su, fp tw, fp tb, float* sm, float* thick) {
  int idx = blockIdx.x * 256 + threadIdx.x;
  if (idx >= NB * NHW) return;
  int hw = idx & 4095, b = idx >> 12;
  const float* p = su + (size_t)b * 64 * NHW + hw;
  float s = 0.f, ts = 0.f;
#pragma unroll 8
  for (int c = 0; c < 64; c++) {
    float v = p[(size_t)c * NHW];
    s += v;
    ts += v * tw[c];
  }
  sm[idx] = s * (1.f / 64.f);
  float z = ts + tb[0];
  thick[idx] = 1.f / (1.f + __expf(-z));
}

// ---------------- 6. edge conv 3x3 (1 -> 64), no bias
__global__ __launch_bounds__(256) void k_edge(const float* sm, fp ew, float* edge) {
  int idx = blockIdx.x * 256 + threadIdx.x;
  if (idx >= NB * 64 * NHW) return;
  int hw = idx & 4095, t = idx >> 12;
  int o = t & 63, b = t >> 6;
  int y = hw >> 6, x = hw & 63;
  const float* s = sm + (size_t)b * NHW;
  float acc = 0.f;
#pragma unroll
  for (int ky = 0; ky < 3; ky++) {
#pragma unroll
    for (int kx = 0; kx < 3; kx++) {
      int yy = y + ky - 1, xx = x + kx - 1;
      if (yy >= 0 && yy < 64 && xx >= 0 && xx < 64)
        acc += s[yy * 64 + xx] * ew[o * 9 + ky * 3 + kx];
    }
  }
  edge[idx] = acc;
}

// ---------------- 7. offset conv 3x3 (64 -> 18) * (1 + 16*thick)
__global__ __launch_bounds__(256) void k_off(const float* edge, fp ow, fp ob, const float* thick, float* off) {
  int idx = blockIdx.x * 256 + threadIdx.x;
  if (idx >= NB * 18 * NHW) return;
  int hw = idx & 4095, t = idx >> 12;
  int o = t % 18, b = t / 18;
  int y = hw >> 6, x = hw & 63;
  const float* e = edge + (size_t)b * 64 * NHW;
  float acc = ob[o];
  for (int j = 0; j < 9; j++) {
    int yy = y + j / 3 - 1, xx = x + j % 3 - 1;
    if (yy < 0 || yy > 63 || xx < 0 || xx > 63) continue;
    int p = yy * 64 + xx;
    const float* wr = ow + o * 576 + j;
#pragma unroll 8
    for (int c = 0; c < 64; c++) acc += e[(size_t)c * NHW + p] * wr[c * 9];
  }
  off[idx] = acc * (1.f + 16.f * thick[b * NHW + hw]);
}

// ---------------- 8. FUSED deformable conv: sample + (576->64) matmul + bias + edge
__global__ __launch_bounds__(256) void k_deform(const float* su, const float* offb,
                                                fp dw, fp db, const float* edge,
                                                __hip_bfloat16* dbuf) {
  __shared__ float sam[64][64];   // [c][px]
  __shared__ float wsm[64][64];   // [o][c]
  int bid = blockIdx.x;           // 256 blocks
  int b = bid >> 6, row = bid & 63;
  int t = threadIdx.x;
  int px = t & 63, q = t >> 6;    // q in [0,4)
  float acc[16];
#pragma unroll
  for (int i = 0; i < 16; i++) acc[i] = 0.f;
  const float* sub = su + (size_t)b * 64 * NHW;
  int hw = row * 64 + px;

  for (int k = 0; k < 9; k++) {
    __syncthreads();              // protect previous tap's LDS reads
#pragma unroll
    for (int i = 0; i < 16; i++) {
      int flat = t * 16 + i;      // 0..4095
      int o = flat >> 6, c = flat & 63;
      wsm[o][c] = dw[(o * 64 + c) * 9 + k];
    }
    float dy = offb[((size_t)(b * 18 + 2 * k)) * NHW + hw];
    float dx = offb[((size_t)(b * 18 + 2 * k + 1)) * NHW + hw];
    float py = (float)(row + k / 3 - 1) + dy;
    float pxf = (float)(px + k % 3 - 1) + dx;
    float y0f = floorf(py), x0f = floorf(pxf);
    float wy = py - y0f, wx = pxf - x0f;
    int y0 = (int)y0f, x0 = (int)x0f;
    int y1 = y0 + 1, x1 = x0 + 1;
    float vy0 = (y0 >= 0 && y0 < 64) ? 1.f : 0.f;
    float vy1 = (y1 >= 0 && y1 < 64) ? 1.f : 0.f;
    float vx0 = (x0 >= 0 && x0 < 64) ? 1.f : 0.f;
    float vx1 = (x1 >= 0 && x1 < 64) ? 1.f : 0.f;
    float w00 = (1.f - wy) * (1.f - wx) * vy0 * vx0;
    float w01 = (1.f - wy) * wx * vy0 * vx1;
    float w10 = wy * (1.f - wx) * vy1 * vx0;
    float w11 = wy * wx * vy1 * vx1;
    int y0c = min(63, max(0, y0)), y1c = min(63, max(0, y1));
    int x0c = min(63, max(0, x0)), x1c = min(63, max(0, x1));
    int i00 = y0c * 64 + x0c, i01 = y0c * 64 + x1c;
    int i10 = y1c * 64 + x0c, i11 = y1c * 64 + x1c;
#pragma unroll
    for (int i = 0; i < 16; i++) {
      int c = q * 16 + i;
      const float* sc = sub + (size_t)c * NHW;
      sam[c][px] = w00 * sc[i00] + w01 * sc[i01] + w10 * sc[i10] + w11 * sc[i11];
    }
    __syncthreads();
#pragma unroll 8
    for (int c = 0; c < 64; c++) {
      float v = sam[c][px];
#pragma unroll
      for (int i = 0; i < 16; i++) acc[i] += v * wsm[q * 16 + i][c];
    }
  }
#pragma unroll
  for (int i = 0; i < 16; i++) {
    int o = q * 16 + i;
    size_t oidx = ((size_t)(b * 64 + o)) * NHW + hw;
    dbuf[oidx] = f2b(acc[i] + db[o] + edge[oidx]);
  }
}

// ---------------- 9. down 1x1 (320 -> 64) -> ebuf f32
__global__ __launch_bounds__(256) void k_down(const __hip_bfloat16* x2, const __hip_bfloat16* dd,
                                              fp w, fp bias, float* e) {
  int idx = blockIdx.x * 256 + threadIdx.x;
  if (idx >= NB * 64 * NHW) return;
  int hw = idx & 4095, t = idx >> 12;
  int o = t & 63, b = t >> 6;
  const float* wr = w + o * 320;
  float acc = bias[o];
  const __hip_bfloat16* xp = x2 + (size_t)b * 256 * NHW + hw;
#pragma unroll 8
  for (int c = 0; c < 256; c++) acc += b2f(xp[(size_t)c * NHW]) * wr[c];
  const __hip_bfloat16* dp = dd + (size_t)b * 64 * NHW + hw;
#pragma unroll 8
  for (int c = 0; c < 64; c++) acc += b2f(dp[(size_t)c * NHW]) * wr[256 + c];
  e[idx] = acc;
}

// ---------------- 10. LayerNorm over 64 channels -> hn bf16
__global__ __launch_bounds__(256) void k_ln(const float* e, fp g, fp bt, __hip_bfloat16* hn) {
  int idx = blockIdx.x * 256 + threadIdx.x;
  if (idx >= NB * NHW) return;
  int hw = idx & 4095, b = idx >> 12;
  const float* p = e + (size_t)b * 64 * NHW + hw;
  float v[64];
  float s = 0.f;
#pragma unroll
  for (int c = 0; c < 64; c++) { v[c] = p[(size_t)c * NHW]; s += v[c]; }
  float mu = s * (1.f / 64.f);
  float q = 0.f;
#pragma unroll
  for (int c = 0; c < 64; c++) { float d = v[c] - mu; q += d * d; }
  float rstd = rsqrtf(q * (1.f / 64.f) + 1e-5f);
  __hip_bfloat16* o = hn + (size_t)b * 64 * NHW + hw;
#pragma unroll
  for (int c = 0; c < 64; c++) o[(size_t)c * NHW] = f2b((v[c] - mu) * rstd * g[c] + bt[c]);
}

// ---------------- 11. mlp1 1x1 (64 -> 256) + exact GELU -> h1 bf16
__global__ __launch_bounds__(256) void k_mlp1(const __hip_bfloat16* hn, fp w, fp bias, __hip_bfloat16* h1) {
  int idx = blockIdx.x * 256 + threadIdx.x;
  if (idx >= NB * 256 * NHW) return;
  int hw = idx & 4095, t = idx >> 12;
  int o = t & 255, b = t >> 8;
  const __hip_bfloat16* p = hn + (size_t)b * 64 * NHW + hw;
  const float* wr = w + o * 64;
  float acc = bias[o];
#pragma unroll 8
  for (int c = 0; c < 64; c++) acc += b2f(p[(size_t)c * NHW]) * wr[c];
  h1[idx] = f2b(gelu_ex(acc));
}

// ---------------- 12. depthwise 3x3 (256 groups) + exact GELU -> h2 bf16
__global__ __launch_bounds__(256) void k_dw(const __hip_bfloat16* h1, fp w, fp bias, __hip_bfloat16* h2) {
  int idx = blockIdx.x * 256 + threadIdx.x;
  if (idx >= NB * 256 * NHW) return;
  int hw = idx & 4095, t = idx >> 12;
  int c = t & 255, b = t >> 8;
  int y = hw >> 6, x = hw & 63;
  const __hip_bfloat16* p = h1 + ((size_t)(b * 256 + c)) * NHW;
  float acc = bias[c];
#pragma unroll
  for (int ky = 0; ky < 3; ky++) {
#pragma unroll
    for (int kx = 0; kx < 3; kx++) {
      int yy = y + ky - 1, xx = x + kx - 1;
      if (yy >= 0 && yy < 64 && xx >= 0 && xx < 64)
        acc += b2f(p[yy * 64 + xx]) * w[c * 9 + ky * 3 + kx];
    }
  }
  h2[idx] = f2b(gelu_ex(acc));
}

// ---------------- 13. mlp2 1x1 (256 -> 64) + bias + residual e -> tbuf f32
__global__ __launch_bounds__(256) void k_mlp2(const __hip_bfloat16* h2, fp w, fp bias, const float* e, float* tb_) {
  int idx = blockIdx.x * 256 + threadIdx.x;
  if (idx >= NB * 64 * NHW) return;
  int hw = idx & 4095, t = idx >> 12;
  int o = t & 63, b = t >> 6;
  const __hip_bfloat16* p = h2 + (size_t)b * 256 * NHW + hw;
  const float* wr = w + o * 256;
  float acc = bias[o];
#pragma unroll 8
  for (int c = 0; c < 256; c++) acc += b2f(p[(size_t)c * NHW]) * wr[c];
  tb_[idx] = acc + e[idx];
}

// ---------------- 14. up 1x1 (64 -> 256), write f32 out
__global__ __launch_bounds__(256) void k_up(const float* tb_, fp w, fp bias, float* out) {
  int idx = blockIdx.x * 256 + threadIdx.x;
  if (idx >= NB * 256 * NHW) return;
  int hw = idx & 4095, t = idx >> 12;
  int o = t & 255, b = t >> 8;
  const float* p = tb_ + (size_t)b * 64 * NHW + hw;
  const float* wr = w + o * 64;
  float acc = bias[o];
#pragma unroll 8
  for (int c = 0; c < 64; c++) acc += p[(size_t)c * NHW] * wr[c];
  out[idx] = acc;
}

extern "C" void kernel_launch(void* const* d_in, const int* in_sizes, int n_in,
                              void* d_out, int out_size, void* d_ws, size_t ws_size,
                              hipStream_t stream) {
  fp x = (fp)d_in[0], skip = (fp)d_in[1], qkv_w = (fp)d_in[2], qkv_b = (fp)d_in[3],
     proj_w = (fp)d_in[4], proj_b = (fp)d_in[5], edge_w = (fp)d_in[6], thick_w = (fp)d_in[7],
     thick_b = (fp)d_in[8], off_w = (fp)d_in[9], off_b = (fp)d_in[10], deform_w = (fp)d_in[11],
     deform_b = (fp)d_in[12], ln_g = (fp)d_in[13], ln_b = (fp)d_in[14], mlp1_w = (fp)d_in[15],
     mlp1_b = (fp)d_in[16], dw_w = (fp)d_in[17], dw_b = (fp)d_in[18], mlp2_w = (fp)d_in[19],
     mlp2_b = (fp)d_in[20], down_w = (fp)d_in[21], down_b = (fp)d_in[22], up_w = (fp)d_in[23],
     up_b = (fp)d_in[24];

  float* ws = (float*)d_ws;
  // ---- workspace layout, float-slot offsets; total 8,192,000 floats = 31.25 MB ----
  float* su    = ws + 0;              // f32 [0, 1048576)
  float* qkv   = ws + 1048576;        // f32 [1048576, 2621440)
  float* av    = ws + 2621440;        // f32 [2621440, 3145728)
  __hip_bfloat16* x2   = (__hip_bfloat16*)(ws + 3145728);  // 4,194,304 bf16 [3145728, 5242880)
  float* edge  = ws + 5242880;        // f32 [5242880, 6291456)
  float* offb  = ws + 6291456;        // f32 [6291456, 6586368)
  float* sm    = ws + 6586368;        // f32 [.., 6602752)
  float* thick = ws + 6602752;        // f32 [.., 6619136)
  __hip_bfloat16* dbuf = (__hip_bfloat16*)(ws + 6619136);  // 1,048,576 bf16 [6619136, 7143424)
  float* ebuf  = ws + 7143424;        // f32 [7143424, 8192000)
  // aliases of dead regions:
  __hip_bfloat16* hn = (__hip_bfloat16*)qkv;               // qkv dead after k_attn
  __hip_bfloat16* h1 = x2;                                  // x2 dead after k_down
  __hip_bfloat16* h2 = (__hip_bfloat16*)ws;                 // su dead after k_deform; spans su+qkv
  float* tbuf  = edge;                                      // edge dead after k_deform

  dim3 blk(256);
  k_upsample<<<(NB * 64 * NHW) / 256, blk, 0, stream>>>(skip, su);
  k_qkv<<<(NB * 96 * NHW) / 256, blk, 0, stream>>>(x, qkv_w, qkv_b, qkv);
  k_attn<<<(NB * NHW) / 4, blk, 0, stream>>>(qkv, av);
  k_proj<<<(NB * 256 * NHW) / 256, blk, 0, stream>>>(av, x, proj_w, proj_b, x2);
  k_meanthick<<<(NB * NHW) / 256, blk, 0, stream>>>(su, thick_w, thick_b, sm, thick);
  k_edge<<<(NB * 64 * NHW) / 256, blk, 0, stream>>>(sm, edge_w, edge);
  k_off<<<(NB * 18 * NHW) / 256, blk, 0, stream>>>(edge, off_w, off_b, thick, offb);
  k_deform<<<NB * 64, blk, 0, stream>>>(su, offb, deform_w, deform_b, edge, dbuf);
  k_down<<<(NB * 64 * NHW) / 256, blk, 0, stream>>>(x2, dbuf, down_w, down_b, ebuf);
  k_ln<<<(NB * NHW) / 256, blk, 0, stream>>>(ebuf, ln_g, ln_b, hn);
  k_mlp1<<<(NB * 256 * NHW) / 256, blk, 0, stream>>>(hn, mlp1_w, mlp1_b, h1);
  k_dw<<<(NB * 256 * NHW) / 256, blk, 0, stream>>>(h1, dw_w, dw_b, h2);
  k_mlp2<<<(NB * 64 * NHW) / 256, blk, 0, stream>>>(h2, mlp2_w, mlp2_b, ebuf, tbuf);
  k_up<<<(NB * 256 * NHW) / 256, blk, 0, stream>>>(tbuf, up_w, up_b, (float*)d_out);
}

// Round 4
// 843.448 us; speedup vs baseline: 2.3291x; 2.3291x over previous
//
#include <hip/hip_runtime.h>
#include <hip/hip_bf16.h>
#include <math.h>

#define NB 4
#define NHW 4096

typedef const float* fp;
typedef __attribute__((ext_vector_type(8))) short short8;
typedef __attribute__((ext_vector_type(4))) float floatx4;

__device__ __forceinline__ float b2f(__hip_bfloat16 v) { return __bfloat162float(v); }
__device__ __forceinline__ __hip_bfloat16 f2b(float v) { return __float2bfloat16(v); }
__device__ __forceinline__ unsigned short f2bu(float f) {
  __hip_bfloat16 h = __float2bfloat16(f);
  return *reinterpret_cast<unsigned short*>(&h);
}
__device__ __forceinline__ float bu2f(unsigned short u) {
  __hip_bfloat16 h = *reinterpret_cast<__hip_bfloat16*>(&u);
  return __bfloat162float(h);
}
__device__ __forceinline__ float gelu_ex(float x) { return 0.5f * x * (1.0f + erff(x * 0.70710678118654752f)); }

// ---------------- 1. bilinear upsample skip [4,64,32,32] -> su [4,64,64,64] f32
__global__ __launch_bounds__(256) void k_upsample(fp skip, float* su) {
  int idx = blockIdx.x * 256 + threadIdx.x;
  if (idx >= NB * 64 * NHW) return;
  int hw = idx & 4095, bc = idx >> 12;
  int y = hw >> 6, x = hw & 63;
  float fy = 0.5f * y - 0.25f, fx = 0.5f * x - 0.25f;
  float y0f = floorf(fy), x0f = floorf(fx);
  float wy = fy - y0f, wx = fx - x0f;
  int y0 = (int)y0f, x0 = (int)x0f;
  int y0c = min(31, max(0, y0)), y1c = min(31, max(0, y0 + 1));
  int x0c = min(31, max(0, x0)), x1c = min(31, max(0, x0 + 1));
  const float* p = skip + (size_t)bc * 1024;
  float v00 = p[y0c * 32 + x0c], v01 = p[y0c * 32 + x1c];
  float v10 = p[y1c * 32 + x0c], v11 = p[y1c * 32 + x1c];
  su[idx] = (1.f - wy) * ((1.f - wx) * v00 + wx * v01) + wy * ((1.f - wx) * v10 + wx * v11);
}

// ---------------- 2. qkv 1x1 conv -> bf16 [b][96][N]; q channels pre-scaled by 1/sqrt(32)
__global__ __launch_bounds__(256) void k_qkv(fp x, fp w, fp bias, unsigned short* qkvb) {
  int idx = blockIdx.x * 256 + threadIdx.x;
  if (idx >= NB * 96 * NHW) return;
  int hw = idx & 4095, t = idx >> 12;
  int o = t % 96, b = t / 96;
  const float* xin = x + (size_t)b * 256 * NHW + hw;
  const float* wr = w + o * 256;
  float acc = bias[o];
#pragma unroll 8
  for (int c = 0; c < 256; c++) acc += xin[(size_t)c * NHW] * wr[c];
  if (o < 32) acc *= 0.17677669529663688f;
  qkvb[idx] = f2bu(acc);
}

// ---------------- 3. MFMA flash attention.  qkvb [b][96][N] bf16, av [b][N][32] f32
// 256 blocks (1/CU), 256 threads = 4 waves, wave handles 16 queries, block 64.
__global__ __launch_bounds__(256) void k_attn(const unsigned short* qkvb, float* av) {
  __shared__ __align__(16) unsigned short kt[128 * 40];   // [key][chan] pad 40
  __shared__ __align__(16) unsigned short vt[32 * 136];   // [chan][key] pad 136
  __shared__ __align__(16) unsigned short pt[4][16 * 136]; // per-wave P [q][key] pad 136
  int tid = threadIdx.x;
  int wave = tid >> 6, lane = tid & 63;
  int quad = lane >> 4, l16 = lane & 15;
  int blk = blockIdx.x;
  int b = blk >> 6;
  int qbase = (blk & 63) * 64 + wave * 16;
  const unsigned short* qp = qkvb + (size_t)b * 96 * NHW;
  const unsigned short* kp = qp + 32 * NHW;
  const unsigned short* vp = qp + 64 * NHW;

  // Q A-frag: lane holds Q[qbase+l16][chan quad*8+j]
  short8 aq;
#pragma unroll
  for (int j = 0; j < 8; j++)
    aq[j] = (short)qp[(size_t)(quad * 8 + j) * NHW + qbase + l16];

  float m_r[4], l_r[4];
  floatx4 o0 = {0.f, 0.f, 0.f, 0.f}, o1 = {0.f, 0.f, 0.f, 0.f};
#pragma unroll
  for (int r = 0; r < 4; r++) { m_r[r] = -1e30f; l_r[r] = 0.f; }

  // staging index precompute
  int sc = tid & 31, sg = tid >> 5;        // kt transpose: chan sc, key-group sg
  int vc = tid >> 3, vs = tid & 7;         // vt copy: chan vc, key-seg vs

  for (int kb = 0; kb < NHW; kb += 128) {
    __syncthreads();   // previous iteration's LDS reads complete
    {
      const unsigned short* src = kp + (size_t)sc * NHW + kb + sg * 16;
#pragma unroll
      for (int j = 0; j < 16; j++) kt[(sg * 16 + j) * 40 + sc] = src[j];
      const unsigned short* sv = vp + (size_t)vc * NHW + kb + vs * 16;
      uint4 d0 = *(const uint4*)sv;
      uint4 d1 = *(const uint4*)(sv + 8);
      *(uint4*)&vt[vc * 136 + vs * 16] = d0;
      *(uint4*)&vt[vc * 136 + vs * 16 + 8] = d1;
    }
    __syncthreads();

    // QK^T: 8 sub-tiles of 16 keys
    floatx4 s[8];
#pragma unroll
    for (int t = 0; t < 8; t++) {
      short8 bk = *(const short8*)&kt[(t * 16 + l16) * 40 + quad * 8];
      floatx4 z = {0.f, 0.f, 0.f, 0.f};
      s[t] = __builtin_amdgcn_mfma_f32_16x16x32_bf16(aq, bk, z, 0, 0, 0);
    }

    // online softmax (row = quad*4 + r, cols spread over 16 lanes x 8 tiles)
    float mnew[4], alpha[4];
#pragma unroll
    for (int r = 0; r < 4; r++) {
      float mx = s[0][r];
#pragma unroll
      for (int t = 1; t < 8; t++) mx = fmaxf(mx, s[t][r]);
#pragma unroll
      for (int msk = 1; msk < 16; msk <<= 1) mx = fmaxf(mx, __shfl_xor(mx, msk, 64));
      mnew[r] = fmaxf(m_r[r], mx);
      alpha[r] = __expf(m_r[r] - mnew[r]);
      m_r[r] = mnew[r];
    }
    float rs[4] = {0.f, 0.f, 0.f, 0.f};
#pragma unroll
    for (int t = 0; t < 8; t++) {
#pragma unroll
      for (int r = 0; r < 4; r++) {
        float p = __expf(s[t][r] - mnew[r]);
        rs[r] += p;
        pt[wave][(quad * 4 + r) * 136 + t * 16 + l16] = f2bu(p);
      }
    }
#pragma unroll
    for (int r = 0; r < 4; r++) {
      float sm = rs[r];
#pragma unroll
      for (int msk = 1; msk < 16; msk <<= 1) sm += __shfl_xor(sm, msk, 64);
      l_r[r] = l_r[r] * alpha[r] + sm;
      o0[r] *= alpha[r];
      o1[r] *= alpha[r];
    }

    // PV: 4 sub-tiles of 32 keys; same-wave LDS RAW handled by compiler waitcnt
#pragma unroll
    for (int t = 0; t < 4; t++) {
      short8 ap  = *(const short8*)&pt[wave][l16 * 136 + t * 32 + quad * 8];
      short8 bv0 = *(const short8*)&vt[l16 * 136 + t * 32 + quad * 8];
      short8 bv1 = *(const short8*)&vt[(l16 + 16) * 136 + t * 32 + quad * 8];
      o0 = __builtin_amdgcn_mfma_f32_16x16x32_bf16(ap, bv0, o0, 0, 0, 0);
      o1 = __builtin_amdgcn_mfma_f32_16x16x32_bf16(ap, bv1, o1, 0, 0, 0);
    }
  }

#pragma unroll
  for (int r = 0; r < 4; r++) {
    float inv = 1.f / l_r[r];
    int q = qbase + quad * 4 + r;
    float* dst = av + ((size_t)b * NHW + q) * 32;
    dst[l16] = o0[r] * inv;
    dst[l16 + 16] = o1[r] * inv;
  }
}

// ---------------- 4. proj 1x1 (32->256) + residual x -> x2 (bf16); av is [b][n][32]
__global__ __launch_bounds__(256) void k_proj(const float* av, fp x, fp w, fp bias, __hip_bfloat16* x2) {
  int idx = blockIdx.x * 256 + threadIdx.x;
  if (idx >= NB * 256 * NHW) return;
  int hw = idx & 4095, t = idx >> 12;
  int o = t & 255, b = t >> 8;
  const float* a = av + ((size_t)b * NHW + hw) * 32;
  const float* wr = w + o * 32;
  float acc = bias[o] + x[idx];
#pragma unroll
  for (int c = 0; c < 32; c++) acc += a[c] * wr[c];
  x2[idx] = f2b(acc);
}

// ---------------- 5. channel mean + thick(sigmoid 1x1)
__global__ __launch_bounds__(256) void k_meanthick(const float* su, fp tw, fp tb, float* sm, float* thick) {
  int idx = blockIdx.x * 256 + threadIdx.x;
  if (idx >= NB * NHW) return;
  int hw = idx & 4095, b = idx >> 12;
  const float* p = su + (size_t)b * 64 * NHW + hw;
  float s = 0.f, ts = 0.f;
#pragma unroll 8
  for (int c = 0; c < 64; c++) {
    float v = p[(size_t)c * NHW];
    s += v;
    ts += v * tw[c];
  }
  sm[idx] = s * (1.f / 64.f);
  float z = ts + tb[0];
  thick[idx] = 1.f / (1.f + __expf(-z));
}

// ---------------- 6. edge conv 3x3 (1 -> 64), no bias
__global__ __launch_bounds__(256) void k_edge(const float* sm, fp ew, float* edge) {
  int idx = blockIdx.x * 256 + threadIdx.x;
  if (idx >= NB * 64 * NHW) return;
  int hw = idx & 4095, t = idx >> 12;
  int o = t & 63, b = t >> 6;
  int y = hw >> 6, x = hw & 63;
  const float* s = sm + (size_t)b * NHW;
  float acc = 0.f;
#pragma unroll
  for (int ky = 0; ky < 3; ky++) {
#pragma unroll
    for (int kx = 0; kx < 3; kx++) {
      int yy = y + ky - 1, xx = x + kx - 1;
      if (yy >= 0 && yy < 64 && xx >= 0 && xx < 64)
        acc += s[yy * 64 + xx] * ew[o * 9 + ky * 3 + kx];
    }
  }
  edge[idx] = acc;
}

// ---------------- 7. offset conv 3x3 (64 -> 18) * (1 + 16*thick)
__global__ __launch_bounds__(256) void k_off(const float* edge, fp ow, fp ob, const float* thick, float* off) {
  int idx = blockIdx.x * 256 + threadIdx.x;
  if (idx >= NB * 18 * NHW) return;
  int hw = idx & 4095, t = idx >> 12;
  int o = t % 18, b = t / 18;
  int y = hw >> 6, x = hw & 63;
  const float* e = edge + (size_t)b * 64 * NHW;
  float acc = ob[o];
  for (int j = 0; j < 9; j++) {
    int yy = y + j / 3 - 1, xx = x + j % 3 - 1;
    if (yy < 0 || yy > 63 || xx < 0 || xx > 63) continue;
    int p = yy * 64 + xx;
    const float* wr = ow + o * 576 + j;
#pragma unroll 8
    for (int c = 0; c < 64; c++) acc += e[(size_t)c * NHW + p] * wr[c * 9];
  }
  off[idx] = acc * (1.f + 16.f * thick[b * NHW + hw]);
}

// ---------------- 8. FUSED deformable conv: sample + (576->64) matmul + bias + edge
__global__ __launch_bounds__(256) void k_deform(const float* su, const float* offb,
                                                fp dw, fp db, const float* edge,
                                                __hip_bfloat16* dbuf) {
  __shared__ float sam[64][64];   // [c][px]
  __shared__ float wsm[64][64];   // [o][c]
  int bid = blockIdx.x;           // 256 blocks
  int b = bid >> 6, row = bid & 63;
  int t = threadIdx.x;
  int px = t & 63, q = t >> 6;    // q in [0,4)
  float acc[16];
#pragma unroll
  for (int i = 0; i < 16; i++) acc[i] = 0.f;
  const float* sub = su + (size_t)b * 64 * NHW;
  int hw = row * 64 + px;

  for (int k = 0; k < 9; k++) {
    __syncthreads();
#pragma unroll
    for (int i = 0; i < 16; i++) {
      int flat = t * 16 + i;
      int o = flat >> 6, c = flat & 63;
      wsm[o][c] = dw[(o * 64 + c) * 9 + k];
    }
    float dy = offb[((size_t)(b * 18 + 2 * k)) * NHW + hw];
    float dx = offb[((size_t)(b * 18 + 2 * k + 1)) * NHW + hw];
    float py = (float)(row + k / 3 - 1) + dy;
    float pxf = (float)(px + k % 3 - 1) + dx;
    float y0f = floorf(py), x0f = floorf(pxf);
    float wy = py - y0f, wx = pxf - x0f;
    int y0 = (int)y0f, x0 = (int)x0f;
    int y1 = y0 + 1, x1 = x0 + 1;
    float vy0 = (y0 >= 0 && y0 < 64) ? 1.f : 0.f;
    float vy1 = (y1 >= 0 && y1 < 64) ? 1.f : 0.f;
    float vx0 = (x0 >= 0 && x0 < 64) ? 1.f : 0.f;
    float vx1 = (x1 >= 0 && x1 < 64) ? 1.f : 0.f;
    float w00 = (1.f - wy) * (1.f - wx) * vy0 * vx0;
    float w01 = (1.f - wy) * wx * vy0 * vx1;
    float w10 = wy * (1.f - wx) * vy1 * vx0;
    float w11 = wy * wx * vy1 * vx1;
    int y0c = min(63, max(0, y0)), y1c = min(63, max(0, y1));
    int x0c = min(63, max(0, x0)), x1c = min(63, max(0, x1));
    int i00 = y0c * 64 + x0c, i01 = y0c * 64 + x1c;
    int i10 = y1c * 64 + x0c, i11 = y1c * 64 + x1c;
#pragma unroll
    for (int i = 0; i < 16; i++) {
      int c = q * 16 + i;
      const float* sc = sub + (size_t)c * NHW;
      sam[c][px] = w00 * sc[i00] + w01 * sc[i01] + w10 * sc[i10] + w11 * sc[i11];
    }
    __syncthreads();
#pragma unroll 8
    for (int c = 0; c < 64; c++) {
      float v = sam[c][px];
#pragma unroll
      for (int i = 0; i < 16; i++) acc[i] += v * wsm[q * 16 + i][c];
    }
  }
#pragma unroll
  for (int i = 0; i < 16; i++) {
    int o = q * 16 + i;
    size_t oidx = ((size_t)(b * 64 + o)) * NHW + hw;
    dbuf[oidx] = f2b(acc[i] + db[o] + edge[oidx]);
  }
}

// ---------------- 9. down 1x1 (320 -> 64) -> ebuf f32
__global__ __launch_bounds__(256) void k_down(const __hip_bfloat16* x2, const __hip_bfloat16* dd,
                                              fp w, fp bias, float* e) {
  int idx = blockIdx.x * 256 + threadIdx.x;
  if (idx >= NB * 64 * NHW) return;
  int hw = idx & 4095, t = idx >> 12;
  int o = t & 63, b = t >> 6;
  const float* wr = w + o * 320;
  float acc = bias[o];
  const __hip_bfloat16* xp = x2 + (size_t)b * 256 * NHW + hw;
#pragma unroll 8
  for (int c = 0; c < 256; c++) acc += b2f(xp[(size_t)c * NHW]) * wr[c];
  const __hip_bfloat16* dp = dd + (size_t)b * 64 * NHW + hw;
#pragma unroll 8
  for (int c = 0; c < 64; c++) acc += b2f(dp[(size_t)c * NHW]) * wr[256 + c];
  e[idx] = acc;
}

// ---------------- 10. LayerNorm over 64 channels -> hn bf16
__global__ __launch_bounds__(256) void k_ln(const float* e, fp g, fp bt, __hip_bfloat16* hn) {
  int idx = blockIdx.x * 256 + threadIdx.x;
  if (idx >= NB * NHW) return;
  int hw = idx & 4095, b = idx >> 12;
  const float* p = e + (size_t)b * 64 * NHW + hw;
  float v[64];
  float s = 0.f;
#pragma unroll
  for (int c = 0; c < 64; c++) { v[c] = p[(size_t)c * NHW]; s += v[c]; }
  float mu = s * (1.f / 64.f);
  float q = 0.f;
#pragma unroll
  for (int c = 0; c < 64; c++) { float d = v[c] - mu; q += d * d; }
  float rstd = rsqrtf(q * (1.f / 64.f) + 1e-5f);
  __hip_bfloat16* o = hn + (size_t)b * 64 * NHW + hw;
#pragma unroll
  for (int c = 0; c < 64; c++) o[(size_t)c * NHW] = f2b((v[c] - mu) * rstd * g[c] + bt[c]);
}

// ---------------- 11. mlp1 1x1 (64 -> 256) + exact GELU -> h1 bf16
__global__ __launch_bounds__(256) void k_mlp1(const __hip_bfloat16* hn, fp w, fp bias, __hip_bfloat16* h1) {
  int idx = blockIdx.x * 256 + threadIdx.x;
  if (idx >= NB * 256 * NHW) return;
  int hw = idx & 4095, t = idx >> 12;
  int o = t & 255, b = t >> 8;
  const __hip_bfloat16* p = hn + (size_t)b * 64 * NHW + hw;
  const float* wr = w + o * 64;
  float acc = bias[o];
#pragma unroll 8
  for (int c = 0; c < 64; c++) acc += b2f(p[(size_t)c * NHW]) * wr[c];
  h1[idx] = f2b(gelu_ex(acc));
}

// ---------------- 12. depthwise 3x3 (256 groups) + exact GELU -> h2 bf16
__global__ __launch_bounds__(256) void k_dw(const __hip_bfloat16* h1, fp w, fp bias, __hip_bfloat16* h2) {
  int idx = blockIdx.x * 256 + threadIdx.x;
  if (idx >= NB * 256 * NHW) return;
  int hw = idx & 4095, t = idx >> 12;
  int c = t & 255, b = t >> 8;
  int y = hw >> 6, x = hw & 63;
  const __hip_bfloat16* p = h1 + ((size_t)(b * 256 + c)) * NHW;
  float acc = bias[c];
#pragma unroll
  for (int ky = 0; ky < 3; ky++) {
#pragma unroll
    for (int kx = 0; kx < 3; kx++) {
      int yy = y + ky - 1, xx = x + kx - 1;
      if (yy >= 0 && yy < 64 && xx >= 0 && xx < 64)
        acc += b2f(p[yy * 64 + xx]) * w[c * 9 + ky * 3 + kx];
    }
  }
  h2[idx] = f2b(gelu_ex(acc));
}

// ---------------- 13. mlp2 1x1 (256 -> 64) + bias + residual e -> tbuf f32
__global__ __launch_bounds__(256) void k_mlp2(const __hip_bfloat16* h2, fp w, fp bias, const float* e, float* tb_) {
  int idx = blockIdx.x * 256 + threadIdx.x;
  if (idx >= NB * 64 * NHW) return;
  int hw = idx & 4095, t = idx >> 12;
  int o = t & 63, b = t >> 6;
  const __hip_bfloat16* p = h2 + (size_t)b * 256 * NHW + hw;
  const float* wr = w + o * 256;
  float acc = bias[o];
#pragma unroll 8
  for (int c = 0; c < 256; c++) acc += b2f(p[(size_t)c * NHW]) * wr[c];
  tb_[idx] = acc + e[idx];
}

// ---------------- 14. up 1x1 (64 -> 256), write f32 out
__global__ __launch_bounds__(256) void k_up(const float* tb_, fp w, fp bias, float* out) {
  int idx = blockIdx.x * 256 + threadIdx.x;
  if (idx >= NB * 256 * NHW) return;
  int hw = idx & 4095, t = idx >> 12;
  int o = t & 255, b = t >> 8;
  const float* p = tb_ + (size_t)b * 64 * NHW + hw;
  const float* wr = w + o * 64;
  float acc = bias[o];
#pragma unroll 8
  for (int c = 0; c < 64; c++) acc += p[(size_t)c * NHW] * wr[c];
  out[idx] = acc;
}

extern "C" void kernel_launch(void* const* d_in, const int* in_sizes, int n_in,
                              void* d_out, int out_size, void* d_ws, size_t ws_size,
                              hipStream_t stream) {
  fp x = (fp)d_in[0], skip = (fp)d_in[1], qkv_w = (fp)d_in[2], qkv_b = (fp)d_in[3],
     proj_w = (fp)d_in[4], proj_b = (fp)d_in[5], edge_w = (fp)d_in[6], thick_w = (fp)d_in[7],
     thick_b = (fp)d_in[8], off_w = (fp)d_in[9], off_b = (fp)d_in[10], deform_w = (fp)d_in[11],
     deform_b = (fp)d_in[12], ln_g = (fp)d_in[13], ln_b = (fp)d_in[14], mlp1_w = (fp)d_in[15],
     mlp1_b = (fp)d_in[16], dw_w = (fp)d_in[17], dw_b = (fp)d_in[18], mlp2_w = (fp)d_in[19],
     mlp2_b = (fp)d_in[20], down_w = (fp)d_in[21], down_b = (fp)d_in[22], up_w = (fp)d_in[23],
     up_b = (fp)d_in[24];

  float* ws = (float*)d_ws;
  // ---- workspace layout, float-slot offsets; total 8,192,000 floats = 31.25 MB ----
  float* su    = ws + 0;              // f32 [0, 1048576)
  unsigned short* qkvb = (unsigned short*)(ws + 1048576);  // bf16 [b][96][N]: 1,572,864 shorts = 786,432 f-slots
  float* av    = ws + 2621440;        // f32 [b][n][32]: [2621440, 3145728)
  __hip_bfloat16* x2   = (__hip_bfloat16*)(ws + 3145728);  // bf16 [3145728, 5242880)
  float* edge  = ws + 5242880;        // f32 [5242880, 6291456)
  float* offb  = ws + 6291456;        // f32 [6291456, 6586368)
  float* sm    = ws + 6586368;        // f32
  float* thick = ws + 6602752;        // f32
  __hip_bfloat16* dbuf = (__hip_bfloat16*)(ws + 6619136);  // bf16 [6619136, 7143424)
  float* ebuf  = ws + 7143424;        // f32 [7143424, 8192000)
  // aliases of dead regions:
  __hip_bfloat16* hn = (__hip_bfloat16*)qkvb;              // qkv dead after k_attn
  __hip_bfloat16* h1 = x2;                                  // x2 dead after k_down
  __hip_bfloat16* h2 = (__hip_bfloat16*)ws;                 // su dead after k_deform
  float* tbuf  = edge;                                      // edge dead after k_deform

  dim3 blk(256);
  k_upsample<<<(NB * 64 * NHW) / 256, blk, 0, stream>>>(skip, su);
  k_qkv<<<(NB * 96 * NHW) / 256, blk, 0, stream>>>(x, qkv_w, qkv_b, qkvb);
  k_attn<<<(NB * NHW) / 64, blk, 0, stream>>>(qkvb, av);
  k_proj<<<(NB * 256 * NHW) / 256, blk, 0, stream>>>(av, x, proj_w, proj_b, x2);
  k_meanthick<<<(NB * NHW) / 256, blk, 0, stream>>>(su, thick_w, thick_b, sm, thick);
  k_edge<<<(NB * 64 * NHW) / 256, blk, 0, stream>>>(sm, edge_w, edge);
  k_off<<<(NB * 18 * NHW) / 256, blk, 0, stream>>>(edge, off_w, off_b, thick, offb);
  k_deform<<<NB * 64, blk, 0, stream>>>(su, offb, deform_w, deform_b, edge, dbuf);
  k_down<<<(NB * 64 * NHW) / 256, blk, 0, stream>>>(x2, dbuf, down_w, down_b, ebuf);
  k_ln<<<(NB * NHW) / 256, blk, 0, stream>>>(ebuf, ln_g, ln_b, hn);
  k_mlp1<<<(NB * 256 * NHW) / 256, blk, 0, stream>>>(hn, mlp1_w, mlp1_b, h1);
  k_dw<<<(NB * 256 * NHW) / 256, blk, 0, stream>>>(h1, dw_w, dw_b, h2);
  k_mlp2<<<(NB * 64 * NHW) / 256, blk, 0, stream>>>(h2, mlp2_w, mlp2_b, ebuf, tbuf);
  k_up<<<(NB * 256 * NHW) / 256, blk, 0, stream>>>(tbuf, up_w, up_b, (float*)d_out);
}

// Round 5
// 757.206 us; speedup vs baseline: 2.5944x; 1.1139x over previous
//
#include <hip/hip_runtime.h>
#include <hip/hip_bf16.h>
#include <math.h>

#define NB 4
#define NHW 4096

typedef const float* fp;
typedef __attribute__((ext_vector_type(8))) short short8;
typedef __attribute__((ext_vector_type(4))) float floatx4;

__device__ __forceinline__ float b2f(__hip_bfloat16 v) { return __bfloat162float(v); }
__device__ __forceinline__ __hip_bfloat16 f2b(float v) { return __float2bfloat16(v); }
__device__ __forceinline__ unsigned short f2bu(float f) {
  __hip_bfloat16 h = __float2bfloat16(f);
  return *reinterpret_cast<unsigned short*>(&h);
}
__device__ __forceinline__ float gelu_ex(float x) { return 0.5f * x * (1.0f + erff(x * 0.70710678118654752f)); }

// ---------------- 1. bilinear upsample skip [4,64,32,32] -> su [4,64,64,64] f32
__global__ __launch_bounds__(256) void k_upsample(fp skip, float* su) {
  int idx = blockIdx.x * 256 + threadIdx.x;
  if (idx >= NB * 64 * NHW) return;
  int hw = idx & 4095, bc = idx >> 12;
  int y = hw >> 6, x = hw & 63;
  float fy = 0.5f * y - 0.25f, fx = 0.5f * x - 0.25f;
  float y0f = floorf(fy), x0f = floorf(fx);
  float wy = fy - y0f, wx = fx - x0f;
  int y0 = (int)y0f, x0 = (int)x0f;
  int y0c = min(31, max(0, y0)), y1c = min(31, max(0, y0 + 1));
  int x0c = min(31, max(0, x0)), x1c = min(31, max(0, x0 + 1));
  const float* p = skip + (size_t)bc * 1024;
  float v00 = p[y0c * 32 + x0c], v01 = p[y0c * 32 + x1c];
  float v10 = p[y1c * 32 + x0c], v11 = p[y1c * 32 + x1c];
  su[idx] = (1.f - wy) * ((1.f - wx) * v00 + wx * v01) + wy * ((1.f - wx) * v10 + wx * v11);
}

// ---------------- 2. qkv 1x1 conv -> bf16 [b][96][N]; q channels pre-scaled by 1/sqrt(32)
__global__ __launch_bounds__(256) void k_qkv(fp x, fp w, fp bias, unsigned short* qkvb) {
  int idx = blockIdx.x * 256 + threadIdx.x;
  if (idx >= NB * 96 * NHW) return;
  int hw = idx & 4095, t = idx >> 12;
  int o = t % 96, b = t / 96;
  const float* xin = x + (size_t)b * 256 * NHW + hw;
  const float* wr = w + o * 256;
  float acc = bias[o];
#pragma unroll 8
  for (int c = 0; c < 256; c++) acc += xin[(size_t)c * NHW] * wr[c];
  if (o < 32) acc *= 0.17677669529663688f;
  qkvb[idx] = f2bu(acc);
}

// ---------------- 3. MFMA flash attention.  qkvb [b][96][N] bf16, av [b][N][32] f32
__global__ __launch_bounds__(256) void k_attn(const unsigned short* qkvb, float* av) {
  __shared__ __align__(16) unsigned short kt[128 * 40];   // [key][chan] pad 40
  __shared__ __align__(16) unsigned short vt[32 * 136];   // [chan][key] pad 136
  __shared__ __align__(16) unsigned short pt[4][16 * 136]; // per-wave P [q][key] pad 136
  int tid = threadIdx.x;
  int wave = tid >> 6, lane = tid & 63;
  int quad = lane >> 4, l16 = lane & 15;
  int blk = blockIdx.x;
  int b = blk >> 6;
  int qbase = (blk & 63) * 64 + wave * 16;
  const unsigned short* qp = qkvb + (size_t)b * 96 * NHW;
  const unsigned short* kp = qp + 32 * NHW;
  const unsigned short* vp = qp + 64 * NHW;

  short8 aq;
#pragma unroll
  for (int j = 0; j < 8; j++)
    aq[j] = (short)qp[(size_t)(quad * 8 + j) * NHW + qbase + l16];

  float m_r[4], l_r[4];
  floatx4 o0 = {0.f, 0.f, 0.f, 0.f}, o1 = {0.f, 0.f, 0.f, 0.f};
#pragma unroll
  for (int r = 0; r < 4; r++) { m_r[r] = -1e30f; l_r[r] = 0.f; }

  int sc = tid & 31, sg = tid >> 5;        // kt transpose: chan sc, key-group sg
  int vc = tid >> 3, vs = tid & 7;         // vt copy: chan vc, key-seg vs

  for (int kb = 0; kb < NHW; kb += 128) {
    __syncthreads();
    {
      const unsigned short* src = kp + (size_t)sc * NHW + kb + sg * 16;
#pragma unroll
      for (int j = 0; j < 16; j++) kt[(sg * 16 + j) * 40 + sc] = src[j];
      const unsigned short* sv = vp + (size_t)vc * NHW + kb + vs * 16;
      uint4 d0 = *(const uint4*)sv;
      uint4 d1 = *(const uint4*)(sv + 8);
      *(uint4*)&vt[vc * 136 + vs * 16] = d0;
      *(uint4*)&vt[vc * 136 + vs * 16 + 8] = d1;
    }
    __syncthreads();

    floatx4 s[8];
#pragma unroll
    for (int t = 0; t < 8; t++) {
      short8 bk = *(const short8*)&kt[(t * 16 + l16) * 40 + quad * 8];
      floatx4 z = {0.f, 0.f, 0.f, 0.f};
      s[t] = __builtin_amdgcn_mfma_f32_16x16x32_bf16(aq, bk, z, 0, 0, 0);
    }

    float mnew[4], alpha[4];
#pragma unroll
    for (int r = 0; r < 4; r++) {
      float mx = s[0][r];
#pragma unroll
      for (int t = 1; t < 8; t++) mx = fmaxf(mx, s[t][r]);
#pragma unroll
      for (int msk = 1; msk < 16; msk <<= 1) mx = fmaxf(mx, __shfl_xor(mx, msk, 64));
      mnew[r] = fmaxf(m_r[r], mx);
      alpha[r] = __expf(m_r[r] - mnew[r]);
      m_r[r] = mnew[r];
    }
    float rs[4] = {0.f, 0.f, 0.f, 0.f};
#pragma unroll
    for (int t = 0; t < 8; t++) {
#pragma unroll
      for (int r = 0; r < 4; r++) {
        float p = __expf(s[t][r] - mnew[r]);
        rs[r] += p;
        pt[wave][(quad * 4 + r) * 136 + t * 16 + l16] = f2bu(p);
      }
    }
#pragma unroll
    for (int r = 0; r < 4; r++) {
      float sm = rs[r];
#pragma unroll
      for (int msk = 1; msk < 16; msk <<= 1) sm += __shfl_xor(sm, msk, 64);
      l_r[r] = l_r[r] * alpha[r] + sm;
      o0[r] *= alpha[r];
      o1[r] *= alpha[r];
    }

#pragma unroll
    for (int t = 0; t < 4; t++) {
      short8 ap  = *(const short8*)&pt[wave][l16 * 136 + t * 32 + quad * 8];
      short8 bv0 = *(const short8*)&vt[l16 * 136 + t * 32 + quad * 8];
      short8 bv1 = *(const short8*)&vt[(l16 + 16) * 136 + t * 32 + quad * 8];
      o0 = __builtin_amdgcn_mfma_f32_16x16x32_bf16(ap, bv0, o0, 0, 0, 0);
      o1 = __builtin_amdgcn_mfma_f32_16x16x32_bf16(ap, bv1, o1, 0, 0, 0);
    }
  }

#pragma unroll
  for (int r = 0; r < 4; r++) {
    float inv = 1.f / l_r[r];
    int q = qbase + quad * 4 + r;
    float* dst = av + ((size_t)b * NHW + q) * 32;
    dst[l16] = o0[r] * inv;
    dst[l16 + 16] = o1[r] * inv;
  }
}

// ---------------- 4. proj 1x1 (32->256) + residual x -> x2 (bf16); av is [b][n][32]
__global__ __launch_bounds__(256) void k_proj(const float* av, fp x, fp w, fp bias, __hip_bfloat16* x2) {
  int idx = blockIdx.x * 256 + threadIdx.x;
  if (idx >= NB * 256 * NHW) return;
  int hw = idx & 4095, t = idx >> 12;
  int o = t & 255, b = t >> 8;
  const float* a = av + ((size_t)b * NHW + hw) * 32;
  const float* wr = w + o * 32;
  float acc = bias[o] + x[idx];
#pragma unroll
  for (int c = 0; c < 32; c++) acc += a[c] * wr[c];
  x2[idx] = f2b(acc);
}

// ---------------- 5. channel mean + thick(sigmoid 1x1)
__global__ __launch_bounds__(256) void k_meanthick(const float* su, fp tw, fp tb, float* sm, float* thick) {
  int idx = blockIdx.x * 256 + threadIdx.x;
  if (idx >= NB * NHW) return;
  int hw = idx & 4095, b = idx >> 12;
  const float* p = su + (size_t)b * 64 * NHW + hw;
  float s = 0.f, ts = 0.f;
#pragma unroll 8
  for (int c = 0; c < 64; c++) {
    float v = p[(size_t)c * NHW];
    s += v;
    ts += v * tw[c];
  }
  sm[idx] = s * (1.f / 64.f);
  float z = ts + tb[0];
  thick[idx] = 1.f / (1.f + __expf(-z));
}

// ---------------- 6. edge conv 3x3 (1 -> 64), no bias
__global__ __launch_bounds__(256) void k_edge(const float* sm, fp ew, float* edge) {
  int idx = blockIdx.x * 256 + threadIdx.x;
  if (idx >= NB * 64 * NHW) return;
  int hw = idx & 4095, t = idx >> 12;
  int o = t & 63, b = t >> 6;
  int y = hw >> 6, x = hw & 63;
  const float* s = sm + (size_t)b * NHW;
  float acc = 0.f;
#pragma unroll
  for (int ky = 0; ky < 3; ky++) {
#pragma unroll
    for (int kx = 0; kx < 3; kx++) {
      int yy = y + ky - 1, xx = x + kx - 1;
      if (yy >= 0 && yy < 64 && xx >= 0 && xx < 64)
        acc += s[yy * 64 + xx] * ew[o * 9 + ky * 3 + kx];
    }
  }
  edge[idx] = acc;
}

// ---------------- 7. offset conv 3x3 (64 -> 18) * (1 + 16*thick)
__global__ __launch_bounds__(256) void k_off(const float* edge, fp ow, fp ob, const float* thick, float* off) {
  int idx = blockIdx.x * 256 + threadIdx.x;
  if (idx >= NB * 18 * NHW) return;
  int hw = idx & 4095, t = idx >> 12;
  int o = t % 18, b = t / 18;
  int y = hw >> 6, x = hw & 63;
  const float* e = edge + (size_t)b * 64 * NHW;
  float acc = ob[o];
  for (int j = 0; j < 9; j++) {
    int yy = y + j / 3 - 1, xx = x + j % 3 - 1;
    if (yy < 0 || yy > 63 || xx < 0 || xx > 63) continue;
    int p = yy * 64 + xx;
    const float* wr = ow + o * 576 + j;
#pragma unroll 8
    for (int c = 0; c < 64; c++) acc += e[(size_t)c * NHW + p] * wr[c * 9];
  }
  off[idx] = acc * (1.f + 16.f * thick[b * NHW + hw]);
}

// ---------------- 7b. weight prep: dw[oc][c][tap] f32 -> wbf[tap][oc][c] bf16
__global__ __launch_bounds__(256) void k_wprep(fp dw, unsigned short* wbf) {
  int idx = blockIdx.x * 256 + threadIdx.x;
  if (idx >= 9 * 64 * 64) return;
  int c = idx & 63, oc = (idx >> 6) & 63, k = idx >> 12;
  wbf[idx] = f2bu(dw[(oc * 64 + c) * 9 + k]);
}

// ---------------- 8. MFMA deformable conv: per-wave sample 16px + 64x16 GEMM, no barriers
// grid 256 = (b, row); 4 waves, wave w owns px = w*16..w*16+15
__global__ __launch_bounds__(256) void k_deform(const float* su, const float* offb,
                                                const unsigned short* wbf, fp db,
                                                const float* edge, __hip_bfloat16* dbuf) {
  __shared__ __align__(16) unsigned short samT[4][16][72];  // [wave][px_local][c], stride 72 (144B, 16B-aligned)
  int tid = threadIdx.x;
  int wave = tid >> 6, lane = tid & 63;
  int quad = lane >> 4, l16 = lane & 15;
  int b = blockIdx.x >> 6, row = blockIdx.x & 63;
  const float* sub = su + (size_t)b * 64 * NHW;

  // sampling roles: lane = (sq, sp): sp = px_local, sq = channel quarter (16 ch each)
  int sp = lane & 15, sq = lane >> 4;
  int hw_s = row * 64 + wave * 16 + sp;
  int x_s = wave * 16 + sp;

  floatx4 acc[4];
#pragma unroll
  for (int a = 0; a < 4; a++) acc[a] = (floatx4){0.f, 0.f, 0.f, 0.f};

  for (int k = 0; k < 9; k++) {
    float dy = offb[((size_t)(b * 18 + 2 * k)) * NHW + hw_s];
    float dx = offb[((size_t)(b * 18 + 2 * k + 1)) * NHW + hw_s];
    float py = (float)(row + k / 3 - 1) + dy;
    float pxf = (float)(x_s + k % 3 - 1) + dx;
    float y0f = floorf(py), x0f = floorf(pxf);
    float wy = py - y0f, wx = pxf - x0f;
    int y0 = (int)y0f, x0 = (int)x0f;
    int y1 = y0 + 1, x1 = x0 + 1;
    float vy0 = (y0 >= 0 && y0 < 64) ? 1.f : 0.f;
    float vy1 = (y1 >= 0 && y1 < 64) ? 1.f : 0.f;
    float vx0 = (x0 >= 0 && x0 < 64) ? 1.f : 0.f;
    float vx1 = (x1 >= 0 && x1 < 64) ? 1.f : 0.f;
    float w00 = (1.f - wy) * (1.f - wx) * vy0 * vx0;
    float w01 = (1.f - wy) * wx * vy0 * vx1;
    float w10 = wy * (1.f - wx) * vy1 * vx0;
    float w11 = wy * wx * vy1 * vx1;
    int y0c = min(63, max(0, y0)), y1c = min(63, max(0, y1));
    int x0c = min(63, max(0, x0)), x1c = min(63, max(0, x1));
    int i00 = y0c * 64 + x0c, i01 = y0c * 64 + x1c;
    int i10 = y1c * 64 + x0c, i11 = y1c * 64 + x1c;

    // sample 16 channels (pairs -> b32 writes into this wave's private LDS region)
#pragma unroll
    for (int i = 0; i < 16; i += 2) {
      int c0 = sq * 16 + i;
      const float* s0 = sub + (size_t)c0 * NHW;
      const float* s1 = s0 + NHW;
      float v0 = w00 * s0[i00] + w01 * s0[i01] + w10 * s0[i10] + w11 * s0[i11];
      float v1 = w00 * s1[i00] + w01 * s1[i01] + w10 * s1[i10] + w11 * s1[i11];
      unsigned int pk = (unsigned int)f2bu(v0) | ((unsigned int)f2bu(v1) << 16);
      *(unsigned int*)&samT[wave][sp][c0] = pk;
    }
    // same-wave LDS RAW: compiler inserts lgkmcnt wait; no barrier needed.

    // D[oc][px] += W[oc][c] * S[c][px]; 2 k-steps x 4 oc-tiles
#pragma unroll
    for (int s = 0; s < 2; s++) {
      short8 bfrag = *(const short8*)&samT[wave][l16][s * 32 + quad * 8];
#pragma unroll
      for (int a = 0; a < 4; a++) {
        const unsigned short* wp = wbf + ((size_t)(k * 64 + a * 16 + l16) * 64 + s * 32 + quad * 8);
        short8 afrag = *(const short8*)wp;
        acc[a] = __builtin_amdgcn_mfma_f32_16x16x32_bf16(afrag, bfrag, acc[a], 0, 0, 0);
      }
    }
  }

#pragma unroll
  for (int a = 0; a < 4; a++) {
#pragma unroll
    for (int r = 0; r < 4; r++) {
      int oc = a * 16 + quad * 4 + r;
      int px = wave * 16 + l16;
      size_t oidx = ((size_t)(b * 64 + oc)) * NHW + row * 64 + px;
      dbuf[oidx] = f2b(acc[a][r] + db[oc] + edge[oidx]);
    }
  }
}

// ---------------- 9. down 1x1 (320 -> 64) -> ebuf f32
__global__ __launch_bounds__(256) void k_down(const __hip_bfloat16* x2, const __hip_bfloat16* dd,
                                              fp w, fp bias, float* e) {
  int idx = blockIdx.x * 256 + threadIdx.x;
  if (idx >= NB * 64 * NHW) return;
  int hw = idx & 4095, t = idx >> 12;
  int o = t & 63, b = t >> 6;
  const float* wr = w + o * 320;
  float acc = bias[o];
  const __hip_bfloat16* xp = x2 + (size_t)b * 256 * NHW + hw;
#pragma unroll 8
  for (int c = 0; c < 256; c++) acc += b2f(xp[(size_t)c * NHW]) * wr[c];
  const __hip_bfloat16* dp = dd + (size_t)b * 64 * NHW + hw;
#pragma unroll 8
  for (int c = 0; c < 64; c++) acc += b2f(dp[(size_t)c * NHW]) * wr[256 + c];
  e[idx] = acc;
}

// ---------------- 10. LayerNorm over 64 channels -> hn bf16
__global__ __launch_bounds__(256) void k_ln(const float* e, fp g, fp bt, __hip_bfloat16* hn) {
  int idx = blockIdx.x * 256 + threadIdx.x;
  if (idx >= NB * NHW) return;
  int hw = idx & 4095, b = idx >> 12;
  const float* p = e + (size_t)b * 64 * NHW + hw;
  float v[64];
  float s = 0.f;
#pragma unroll
  for (int c = 0; c < 64; c++) { v[c] = p[(size_t)c * NHW]; s += v[c]; }
  float mu = s * (1.f / 64.f);
  float q = 0.f;
#pragma unroll
  for (int c = 0; c < 64; c++) { float d = v[c] - mu; q += d * d; }
  float rstd = rsqrtf(q * (1.f / 64.f) + 1e-5f);
  __hip_bfloat16* o = hn + (size_t)b * 64 * NHW + hw;
#pragma unroll
  for (int c = 0; c < 64; c++) o[(size_t)c * NHW] = f2b((v[c] - mu) * rstd * g[c] + bt[c]);
}

// ---------------- 11. mlp1 1x1 (64 -> 256) + exact GELU -> h1 bf16
__global__ __launch_bounds__(256) void k_mlp1(const __hip_bfloat16* hn, fp w, fp bias, __hip_bfloat16* h1) {
  int idx = blockIdx.x * 256 + threadIdx.x;
  if (idx >= NB * 256 * NHW) return;
  int hw = idx & 4095, t = idx >> 12;
  int o = t & 255, b = t >> 8;
  const __hip_bfloat16* p = hn + (size_t)b * 64 * NHW + hw;
  const float* wr = w + o * 64;
  float acc = bias[o];
#pragma unroll 8
  for (int c = 0; c < 64; c++) acc += b2f(p[(size_t)c * NHW]) * wr[c];
  h1[idx] = f2b(gelu_ex(acc));
}

// ---------------- 12. depthwise 3x3 (256 groups) + exact GELU -> h2 bf16
__global__ __launch_bounds__(256) void k_dw(const __hip_bfloat16* h1, fp w, fp bias, __hip_bfloat16* h2) {
  int idx = blockIdx.x * 256 + threadIdx.x;
  if (idx >= NB * 256 * NHW) return;
  int hw = idx & 4095, t = idx >> 12;
  int c = t & 255, b = t >> 8;
  int y = hw >> 6, x = hw & 63;
  const __hip_bfloat16* p = h1 + ((size_t)(b * 256 + c)) * NHW;
  float acc = bias[c];
#pragma unroll
  for (int ky = 0; ky < 3; ky++) {
#pragma unroll
    for (int kx = 0; kx < 3; kx++) {
      int yy = y + ky - 1, xx = x + kx - 1;
      if (yy >= 0 && yy < 64 && xx >= 0 && xx < 64)
        acc += b2f(p[yy * 64 + xx]) * w[c * 9 + ky * 3 + kx];
    }
  }
  h2[idx] = f2b(gelu_ex(acc));
}

// ---------------- 13. mlp2 1x1 (256 -> 64) + bias + residual e -> tbuf f32
__global__ __launch_bounds__(256) void k_mlp2(const __hip_bfloat16* h2, fp w, fp bias, const float* e, float* tb_) {
  int idx = blockIdx.x * 256 + threadIdx.x;
  if (idx >= NB * 64 * NHW) return;
  int hw = idx & 4095, t = idx >> 12;
  int o = t & 63, b = t >> 6;
  const __hip_bfloat16* p = h2 + (size_t)b * 256 * NHW + hw;
  const float* wr = w + o * 256;
  float acc = bias[o];
#pragma unroll 8
  for (int c = 0; c < 256; c++) acc += b2f(p[(size_t)c * NHW]) * wr[c];
  tb_[idx] = acc + e[idx];
}

// ---------------- 14. up 1x1 (64 -> 256), write f32 out
__global__ __launch_bounds__(256) void k_up(const float* tb_, fp w, fp bias, float* out) {
  int idx = blockIdx.x * 256 + threadIdx.x;
  if (idx >= NB * 256 * NHW) return;
  int hw = idx & 4095, t = idx >> 12;
  int o = t & 255, b = t >> 8;
  const float* p = tb_ + (size_t)b * 64 * NHW + hw;
  const float* wr = w + o * 64;
  float acc = bias[o];
#pragma unroll 8
  for (int c = 0; c < 64; c++) acc += p[(size_t)c * NHW] * wr[c];
  out[idx] = acc;
}

extern "C" void kernel_launch(void* const* d_in, const int* in_sizes, int n_in,
                              void* d_out, int out_size, void* d_ws, size_t ws_size,
                              hipStream_t stream) {
  fp x = (fp)d_in[0], skip = (fp)d_in[1], qkv_w = (fp)d_in[2], qkv_b = (fp)d_in[3],
     proj_w = (fp)d_in[4], proj_b = (fp)d_in[5], edge_w = (fp)d_in[6], thick_w = (fp)d_in[7],
     thick_b = (fp)d_in[8], off_w = (fp)d_in[9], off_b = (fp)d_in[10], deform_w = (fp)d_in[11],
     deform_b = (fp)d_in[12], ln_g = (fp)d_in[13], ln_b = (fp)d_in[14], mlp1_w = (fp)d_in[15],
     mlp1_b = (fp)d_in[16], dw_w = (fp)d_in[17], dw_b = (fp)d_in[18], mlp2_w = (fp)d_in[19],
     mlp2_b = (fp)d_in[20], down_w = (fp)d_in[21], down_b = (fp)d_in[22], up_w = (fp)d_in[23],
     up_b = (fp)d_in[24];

  float* ws = (float*)d_ws;
  // ---- workspace layout, float-slot offsets; total 8,192,000 floats = 31.25 MB ----
  float* su    = ws + 0;              // f32 [0, 1048576)
  unsigned short* qkvb = (unsigned short*)(ws + 1048576);  // bf16 [b][96][N]
  float* av    = ws + 2621440;        // f32 [b][n][32]
  __hip_bfloat16* x2   = (__hip_bfloat16*)(ws + 3145728);  // bf16
  float* edge  = ws + 5242880;        // f32
  float* offb  = ws + 6291456;        // f32
  float* sm    = ws + 6586368;        // f32 (dead after k_edge)
  float* thick = ws + 6602752;        // f32 (dead after k_off)
  __hip_bfloat16* dbuf = (__hip_bfloat16*)(ws + 6619136);  // bf16
  float* ebuf  = ws + 7143424;        // f32
  // aliases of dead regions:
  unsigned short* wbf = (unsigned short*)sm;               // 36,864 shorts, fits sm+thick region; written after k_off
  __hip_bfloat16* hn = (__hip_bfloat16*)qkvb;              // qkv dead after k_attn
  __hip_bfloat16* h1 = x2;                                  // x2 dead after k_down
  __hip_bfloat16* h2 = (__hip_bfloat16*)ws;                 // su dead after k_deform
  float* tbuf  = edge;                                      // edge dead after k_deform

  dim3 blk(256);
  k_upsample<<<(NB * 64 * NHW) / 256, blk, 0, stream>>>(skip, su);
  k_qkv<<<(NB * 96 * NHW) / 256, blk, 0, stream>>>(x, qkv_w, qkv_b, qkvb);
  k_attn<<<(NB * NHW) / 64, blk, 0, stream>>>(qkvb, av);
  k_proj<<<(NB * 256 * NHW) / 256, blk, 0, stream>>>(av, x, proj_w, proj_b, x2);
  k_meanthick<<<(NB * NHW) / 256, blk, 0, stream>>>(su, thick_w, thick_b, sm, thick);
  k_edge<<<(NB * 64 * NHW) / 256, blk, 0, stream>>>(sm, edge_w, edge);
  k_off<<<(NB * 18 * NHW) / 256, blk, 0, stream>>>(edge, off_w, off_b, thick, offb);
  k_wprep<<<144, blk, 0, stream>>>(deform_w, wbf);
  k_deform<<<NB * 64, blk, 0, stream>>>(su, offb, wbf, deform_b, edge, dbuf);
  k_down<<<(NB * 64 * NHW) / 256, blk, 0, stream>>>(x2, dbuf, down_w, down_b, ebuf);
  k_ln<<<(NB * NHW) / 256, blk, 0, stream>>>(ebuf, ln_g, ln_b, hn);
  k_mlp1<<<(NB * 256 * NHW) / 256, blk, 0, stream>>>(hn, mlp1_w, mlp1_b, h1);
  k_dw<<<(NB * 256 * NHW) / 256, blk, 0, stream>>>(h1, dw_w, dw_b, h2);
  k_mlp2<<<(NB * 64 * NHW) / 256, blk, 0, stream>>>(h2, mlp2_w, mlp2_b, ebuf, tbuf);
  k_up<<<(NB * 256 * NHW) / 256, blk, 0, stream>>>(tbuf, up_w, up_b, (float*)d_out);
}

// Round 8
// 685.406 us; speedup vs baseline: 2.8662x; 1.1048x over previous
//
#include <hip/hip_runtime.h>
#include <hip/hip_bf16.h>
#include <math.h>

#define NB 4
#define NHW 4096

typedef const float* fp;
typedef unsigned short us;
typedef __attribute__((ext_vector_type(8))) short short8;
typedef __attribute__((ext_vector_type(4))) float floatx4;

__device__ __forceinline__ float b2f(__hip_bfloat16 v) { return __bfloat162float(v); }
__device__ __forceinline__ __hip_bfloat16 f2b(float v) { return __float2bfloat16(v); }
__device__ __forceinline__ us f2bu(float f) {
  __hip_bfloat16 h = __float2bfloat16(f);
  return *reinterpret_cast<us*>(&h);
}
__device__ __forceinline__ float bu2f(us u) {
  __hip_bfloat16 h = *reinterpret_cast<__hip_bfloat16*>(&u);
  return __bfloat162float(h);
}
__device__ __forceinline__ float gelu_ex(float x) { return 0.5f * x * (1.0f + erff(x * 0.70710678118654752f)); }
__device__ __forceinline__ short8 ld8(const us* p) { return *(const short8*)p; }

// ---------------- 0a. cast qkv weights f32 [96][256] -> bf16 [96][256]
__global__ __launch_bounds__(256) void k_wq(fp qw, us* wq) {
  int i = blockIdx.x * 256 + threadIdx.x;
  if (i >= 96 * 256) return;
  wq[i] = f2bu(qw[i]);
}

// ---------------- 0b. weight prep (deform): dw[oc][c][tap] f32 -> wbf[tap][oc][c] bf16 (r5 verbatim)
__global__ __launch_bounds__(256) void k_wprep(fp dw, us* wbf) {
  int idx = blockIdx.x * 256 + threadIdx.x;
  if (idx >= 9 * 64 * 64) return;
  int c = idx & 63, oc = (idx >> 6) & 63, k = idx >> 12;
  wbf[idx] = f2bu(dw[(oc * 64 + c) * 9 + k]);
}

// ---------------- 1. bilinear upsample skip [4,64,32,32] -> su [4,64,64,64] f32 (r5 verbatim)
__global__ __launch_bounds__(256) void k_upsample(fp skip, float* su) {
  int idx = blockIdx.x * 256 + threadIdx.x;
  if (idx >= NB * 64 * NHW) return;
  int hw = idx & 4095, bc = idx >> 12;
  int y = hw >> 6, x = hw & 63;
  float fy = 0.5f * y - 0.25f, fx = 0.5f * x - 0.25f;
  float y0f = floorf(fy), x0f = floorf(fx);
  float wy = fy - y0f, wx = fx - x0f;
  int y0 = (int)y0f, x0 = (int)x0f;
  int y0c = min(31, max(0, y0)), y1c = min(31, max(0, y0 + 1));
  int x0c = min(31, max(0, x0)), x1c = min(31, max(0, x0 + 1));
  const float* p = skip + (size_t)bc * 1024;
  float v00 = p[y0c * 32 + x0c], v01 = p[y0c * 32 + x1c];
  float v10 = p[y1c * 32 + x0c], v11 = p[y1c * 32 + x1c];
  su[idx] = (1.f - wy) * ((1.f - wx) * v00 + wx * v01) + wy * ((1.f - wx) * v10 + wx * v11);
}

// ---------------- 2. transpose x f32 [b][256][4096] -> xT bf16 [b*4096][256]
__global__ __launch_bounds__(256) void k_xpose(fp x, us* xT) {
  __shared__ float tile[64][65];
  int bid = blockIdx.x;                 // 1024 = b(4) x ct(4) x pt(64)
  int pt = bid & 63, ct = (bid >> 6) & 3, b = bid >> 8;
  int px0 = pt * 64, c0 = ct * 64;
  int tx = threadIdx.x & 63, ty = threadIdx.x >> 6;
  const float* src = x + ((size_t)(b * 256 + c0)) * NHW + px0;
#pragma unroll
  for (int i = 0; i < 16; i++) {
    int r = i * 4 + ty;
    tile[r][tx] = src[(size_t)r * NHW + tx];
  }
  __syncthreads();
  int cseg = threadIdx.x & 7, p0 = threadIdx.x >> 3;
#pragma unroll
  for (int h = 0; h < 2; h++) {
    int p = p0 + h * 32;
    short8 v;
#pragma unroll
    for (int j = 0; j < 8; j++) v[j] = (short)f2bu(tile[cseg * 8 + j][p]);
    *(short8*)&xT[((size_t)(b * NHW) + px0 + p) * 256 + c0 + cseg * 8] = v;
  }
}

// ---------------- 3. qkv GEMM -> bf16 [b][96][N] channel-major; q channels pre-scaled
__global__ __launch_bounds__(256) void k_qkv_g(const us* xT, const us* wq, fp bias, us* qkvb) {
  int wave = threadIdx.x >> 6, lane = threadIdx.x & 63;
  int quad = lane >> 4, l16 = lane & 15;
  int pxg0 = blockIdx.x * 64 + wave * 16;
  int b = pxg0 >> 12, hw0 = pxg0 & 4095;
  floatx4 acc[6];
#pragma unroll
  for (int m = 0; m < 6; m++) acc[m] = (floatx4){0.f, 0.f, 0.f, 0.f};
  const us* xrow = xT + (size_t)(pxg0 + l16) * 256 + quad * 8;
#pragma unroll
  for (int k0 = 0; k0 < 256; k0 += 32) {
    short8 bf = ld8(xrow + k0);
#pragma unroll
    for (int m = 0; m < 6; m++) {
      short8 af = ld8(wq + (size_t)(m * 16 + l16) * 256 + k0 + quad * 8);
      acc[m] = __builtin_amdgcn_mfma_f32_16x16x32_bf16(af, bf, acc[m], 0, 0, 0);
    }
  }
#pragma unroll
  for (int m = 0; m < 6; m++)
#pragma unroll
    for (int r = 0; r < 4; r++) {
      int oc = m * 16 + quad * 4 + r;
      float v = acc[m][r] + bias[oc];
      if (oc < 32) v *= 0.17677669529663688f;
      qkvb[(size_t)(b * 96 + oc) * NHW + hw0 + l16] = f2bu(v);
    }
}

// ---------------- 4. MFMA flash attention (r5 verbatim).  qkvb [b][96][N] -> av f32 [b][N][32]
__global__ __launch_bounds__(256) void k_attn(const us* qkvb, float* av) {
  __shared__ __align__(16) us kt[128 * 40];
  __shared__ __align__(16) us vt[32 * 136];
  __shared__ __align__(16) us pt[4][16 * 136];
  int tid = threadIdx.x;
  int wave = tid >> 6, lane = tid & 63;
  int quad = lane >> 4, l16 = lane & 15;
  int blk = blockIdx.x;
  int b = blk >> 6;
  int qbase = (blk & 63) * 64 + wave * 16;
  const us* qp = qkvb + (size_t)b * 96 * NHW;
  const us* kp = qp + 32 * NHW;
  const us* vp = qp + 64 * NHW;

  short8 aq;
#pragma unroll
  for (int j = 0; j < 8; j++)
    aq[j] = (short)qp[(size_t)(quad * 8 + j) * NHW + qbase + l16];

  float m_r[4], l_r[4];
  floatx4 o0 = {0.f, 0.f, 0.f, 0.f}, o1 = {0.f, 0.f, 0.f, 0.f};
#pragma unroll
  for (int r = 0; r < 4; r++) { m_r[r] = -1e30f; l_r[r] = 0.f; }

  int sc = tid & 31, sg = tid >> 5;
  int vc = tid >> 3, vs = tid & 7;

  for (int kb = 0; kb < NHW; kb += 128) {
    __syncthreads();
    {
      const us* src = kp + (size_t)sc * NHW + kb + sg * 16;
#pragma unroll
      for (int j = 0; j < 16; j++) kt[(sg * 16 + j) * 40 + sc] = src[j];
      const us* sv = vp + (size_t)vc * NHW + kb + vs * 16;
      uint4 d0 = *(const uint4*)sv;
      uint4 d1 = *(const uint4*)(sv + 8);
      *(uint4*)&vt[vc * 136 + vs * 16] = d0;
      *(uint4*)&vt[vc * 136 + vs * 16 + 8] = d1;
    }
    __syncthreads();

    floatx4 s[8];
#pragma unroll
    for (int t = 0; t < 8; t++) {
      short8 bk = *(const short8*)&kt[(t * 16 + l16) * 40 + quad * 8];
      floatx4 z = {0.f, 0.f, 0.f, 0.f};
      s[t] = __builtin_amdgcn_mfma_f32_16x16x32_bf16(aq, bk, z, 0, 0, 0);
    }

    float mnew[4], alpha[4];
#pragma unroll
    for (int r = 0; r < 4; r++) {
      float mx = s[0][r];
#pragma unroll
      for (int t = 1; t < 8; t++) mx = fmaxf(mx, s[t][r]);
#pragma unroll
      for (int msk = 1; msk < 16; msk <<= 1) mx = fmaxf(mx, __shfl_xor(mx, msk, 64));
      mnew[r] = fmaxf(m_r[r], mx);
      alpha[r] = __expf(m_r[r] - mnew[r]);
      m_r[r] = mnew[r];
    }
    float rs[4] = {0.f, 0.f, 0.f, 0.f};
#pragma unroll
    for (int t = 0; t < 8; t++) {
#pragma unroll
      for (int r = 0; r < 4; r++) {
        float p = __expf(s[t][r] - mnew[r]);
        rs[r] += p;
        pt[wave][(quad * 4 + r) * 136 + t * 16 + l16] = f2bu(p);
      }
    }
#pragma unroll
    for (int r = 0; r < 4; r++) {
      float sm = rs[r];
#pragma unroll
      for (int msk = 1; msk < 16; msk <<= 1) sm += __shfl_xor(sm, msk, 64);
      l_r[r] = l_r[r] * alpha[r] + sm;
      o0[r] *= alpha[r];
      o1[r] *= alpha[r];
    }

#pragma unroll
    for (int t = 0; t < 4; t++) {
      short8 ap  = *(const short8*)&pt[wave][l16 * 136 + t * 32 + quad * 8];
      short8 bv0 = *(const short8*)&vt[l16 * 136 + t * 32 + quad * 8];
      short8 bv1 = *(const short8*)&vt[(l16 + 16) * 136 + t * 32 + quad * 8];
      o0 = __builtin_amdgcn_mfma_f32_16x16x32_bf16(ap, bv0, o0, 0, 0, 0);
      o1 = __builtin_amdgcn_mfma_f32_16x16x32_bf16(ap, bv1, o1, 0, 0, 0);
    }
  }

#pragma unroll
  for (int r = 0; r < 4; r++) {
    float inv = 1.f / l_r[r];
    int q = qbase + quad * 4 + r;
    float* dst = av + ((size_t)b * NHW + q) * 32;
    dst[l16] = o0[r] * inv;
    dst[l16 + 16] = o1[r] * inv;
  }
}

// ---------------- 5. proj 1x1 (32->256) + residual x -> x2 bf16 (r5 verbatim)
__global__ __launch_bounds__(256) void k_proj(const float* av, fp x, fp w, fp bias, __hip_bfloat16* x2) {
  int idx = blockIdx.x * 256 + threadIdx.x;
  if (idx >= NB * 256 * NHW) return;
  int hw = idx & 4095, t = idx >> 12;
  int o = t & 255, b = t >> 8;
  const float* a = av + ((size_t)b * NHW + hw) * 32;
  const float* wr = w + o * 32;
  float acc = bias[o] + x[idx];
#pragma unroll
  for (int c = 0; c < 32; c++) acc += a[c] * wr[c];
  x2[idx] = f2b(acc);
}

// ---------------- 6. channel mean + thick (r5 verbatim)
__global__ __launch_bounds__(256) void k_meanthick(const float* su, fp tw, fp tb, float* sm, float* thick) {
  int idx = blockIdx.x * 256 + threadIdx.x;
  if (idx >= NB * NHW) return;
  int hw = idx & 4095, b = idx >> 12;
  const float* p = su + (size_t)b * 64 * NHW + hw;
  float s = 0.f, ts = 0.f;
#pragma unroll 8
  for (int c = 0; c < 64; c++) {
    float v = p[(size_t)c * NHW];
    s += v;
    ts += v * tw[c];
  }
  sm[idx] = s * (1.f / 64.f);
  float z = ts + tb[0];
  thick[idx] = 1.f / (1.f + __expf(-z));
}

// ---------------- 7. edge conv 3x3 (r5 verbatim)
__global__ __launch_bounds__(256) void k_edge(const float* sm, fp ew, float* edge) {
  int idx = blockIdx.x * 256 + threadIdx.x;
  if (idx >= NB * 64 * NHW) return;
  int hw = idx & 4095, t = idx >> 12;
  int o = t & 63, b = t >> 6;
  int y = hw >> 6, x = hw & 63;
  const float* s = sm + (size_t)b * NHW;
  float acc = 0.f;
#pragma unroll
  for (int ky = 0; ky < 3; ky++) {
#pragma unroll
    for (int kx = 0; kx < 3; kx++) {
      int yy = y + ky - 1, xx = x + kx - 1;
      if (yy >= 0 && yy < 64 && xx >= 0 && xx < 64)
        acc += s[yy * 64 + xx] * ew[o * 9 + ky * 3 + kx];
    }
  }
  edge[idx] = acc;
}

// ---------------- 8. offset conv 3x3 (r5 verbatim)
__global__ __launch_bounds__(256) void k_off(const float* edge, fp ow, fp ob, const float* thick, float* off) {
  int idx = blockIdx.x * 256 + threadIdx.x;
  if (idx >= NB * 18 * NHW) return;
  int hw = idx & 4095, t = idx >> 12;
  int o = t % 18, b = t / 18;
  int y = hw >> 6, x = hw & 63;
  const float* e = edge + (size_t)b * 64 * NHW;
  float acc = ob[o];
  for (int j = 0; j < 9; j++) {
    int yy = y + j / 3 - 1, xx = x + j % 3 - 1;
    if (yy < 0 || yy > 63 || xx < 0 || xx > 63) continue;
    int p = yy * 64 + xx;
    const float* wr = ow + o * 576 + j;
#pragma unroll 8
    for (int c = 0; c < 64; c++) acc += e[(size_t)c * NHW + p] * wr[c * 9];
  }
  off[idx] = acc * (1.f + 16.f * thick[b * NHW + hw]);
}

// ---------------- 9. MFMA deformable conv (r5 verbatim, f32 su in, ch-major bf16 out)
__global__ __launch_bounds__(256) void k_deform(const float* su, const float* offb,
                                                const us* wbf, fp db,
                                                const float* edge, __hip_bfloat16* dbuf) {
  __shared__ __align__(16) us samT[4][16][72];
  int tid = threadIdx.x;
  int wave = tid >> 6, lane = tid & 63;
  int quad = lane >> 4, l16 = lane & 15;
  int b = blockIdx.x >> 6, row = blockIdx.x & 63;
  const float* sub = su + (size_t)b * 64 * NHW;

  int sp = lane & 15, sq = lane >> 4;
  int hw_s = row * 64 + wave * 16 + sp;
  int x_s = wave * 16 + sp;

  floatx4 acc[4];
#pragma unroll
  for (int a = 0; a < 4; a++) acc[a] = (floatx4){0.f, 0.f, 0.f, 0.f};

  for (int k = 0; k < 9; k++) {
    float dy = offb[((size_t)(b * 18 + 2 * k)) * NHW + hw_s];
    float dx = offb[((size_t)(b * 18 + 2 * k + 1)) * NHW + hw_s];
    float py = (float)(row + k / 3 - 1) + dy;
    float pxf = (float)(x_s + k % 3 - 1) + dx;
    float y0f = floorf(py), x0f = floorf(pxf);
    float wy = py - y0f, wx = pxf - x0f;
    int y0 = (int)y0f, x0 = (int)x0f;
    int y1 = y0 + 1, x1 = x0 + 1;
    float vy0 = (y0 >= 0 && y0 < 64) ? 1.f : 0.f;
    float vy1 = (y1 >= 0 && y1 < 64) ? 1.f : 0.f;
    float vx0 = (x0 >= 0 && x0 < 64) ? 1.f : 0.f;
    float vx1 = (x1 >= 0 && x1 < 64) ? 1.f : 0.f;
    float w00 = (1.f - wy) * (1.f - wx) * vy0 * vx0;
    float w01 = (1.f - wy) * wx * vy0 * vx1;
    float w10 = wy * (1.f - wx) * vy1 * vx0;
    float w11 = wy * wx * vy1 * vx1;
    int y0c = min(63, max(0, y0)), y1c = min(63, max(0, y1));
    int x0c = min(63, max(0, x0)), x1c = min(63, max(0, x1));
    int i00 = y0c * 64 + x0c, i01 = y0c * 64 + x1c;
    int i10 = y1c * 64 + x0c, i11 = y1c * 64 + x1c;

#pragma unroll
    for (int i = 0; i < 16; i += 2) {
      int c0 = sq * 16 + i;
      const float* s0 = sub + (size_t)c0 * NHW;
      const float* s1 = s0 + NHW;
      float v0 = w00 * s0[i00] + w01 * s0[i01] + w10 * s0[i10] + w11 * s0[i11];
      float v1 = w00 * s1[i00] + w01 * s1[i01] + w10 * s1[i10] + w11 * s1[i11];
      unsigned int pk = (unsigned int)f2bu(v0) | ((unsigned int)f2bu(v1) << 16);
      *(unsigned int*)&samT[wave][sp][c0] = pk;
    }

#pragma unroll
    for (int s = 0; s < 2; s++) {
      short8 bfrag = *(const short8*)&samT[wave][l16][s * 32 + quad * 8];
#pragma unroll
      for (int a = 0; a < 4; a++) {
        short8 afrag = ld8(wbf + ((size_t)(k * 64 + a * 16 + l16) * 64 + s * 32 + quad * 8));
        acc[a] = __builtin_amdgcn_mfma_f32_16x16x32_bf16(afrag, bfrag, acc[a], 0, 0, 0);
      }
    }
  }

#pragma unroll
  for (int a = 0; a < 4; a++)
#pragma unroll
    for (int r = 0; r < 4; r++) {
      int oc = a * 16 + quad * 4 + r;
      int px = wave * 16 + l16;
      size_t oidx = ((size_t)(b * 64 + oc)) * NHW + row * 64 + px;
      dbuf[oidx] = f2b(acc[a][r] + db[oc] + edge[oidx]);
    }
}

// ---------------- 10. down 1x1 (r5 verbatim)
__global__ __launch_bounds__(256) void k_down(const __hip_bfloat16* x2, const __hip_bfloat16* dd,
                                              fp w, fp bias, float* e) {
  int idx = blockIdx.x * 256 + threadIdx.x;
  if (idx >= NB * 64 * NHW) return;
  int hw = idx & 4095, t = idx >> 12;
  int o = t & 63, b = t >> 6;
  const float* wr = w + o * 320;
  float acc = bias[o];
  const __hip_bfloat16* xp = x2 + (size_t)b * 256 * NHW + hw;
#pragma unroll 8
  for (int c = 0; c < 256; c++) acc += b2f(xp[(size_t)c * NHW]) * wr[c];
  const __hip_bfloat16* dp = dd + (size_t)b * 64 * NHW + hw;
#pragma unroll 8
  for (int c = 0; c < 64; c++) acc += b2f(dp[(size_t)c * NHW]) * wr[256 + c];
  e[idx] = acc;
}

// ---------------- 11. LayerNorm (r5 verbatim)
__global__ __launch_bounds__(256) void k_ln(const float* e, fp g, fp bt, __hip_bfloat16* hn) {
  int idx = blockIdx.x * 256 + threadIdx.x;
  if (idx >= NB * NHW) return;
  int hw = idx & 4095, b = idx >> 12;
  const float* p = e + (size_t)b * 64 * NHW + hw;
  float v[64];
  float s = 0.f;
#pragma unroll
  for (int c = 0; c < 64; c++) { v[c] = p[(size_t)c * NHW]; s += v[c]; }
  float mu = s * (1.f / 64.f);
  float q = 0.f;
#pragma unroll
  for (int c = 0; c < 64; c++) { float d = v[c] - mu; q += d * d; }
  float rstd = rsqrtf(q * (1.f / 64.f) + 1e-5f);
  __hip_bfloat16* o = hn + (size_t)b * 64 * NHW + hw;
#pragma unroll
  for (int c = 0; c < 64; c++) o[(size_t)c * NHW] = f2b((v[c] - mu) * rstd * g[c] + bt[c]);
}

// ---------------- 12. mlp1 1x1 (r5 verbatim)
__global__ __launch_bounds__(256) void k_mlp1(const __hip_bfloat16* hn, fp w, fp bias, __hip_bfloat16* h1) {
  int idx = blockIdx.x * 256 + threadIdx.x;
  if (idx >= NB * 256 * NHW) return;
  int hw = idx & 4095, t = idx >> 12;
  int o = t & 255, b = t >> 8;
  const __hip_bfloat16* p = hn + (size_t)b * 64 * NHW + hw;
  const float* wr = w + o * 64;
  float acc = bias[o];
#pragma unroll 8
  for (int c = 0; c < 64; c++) acc += b2f(p[(size_t)c * NHW]) * wr[c];
  h1[idx] = f2b(gelu_ex(acc));
}

// ---------------- 13. depthwise 3x3 (r5 verbatim)
__global__ __launch_bounds__(256) void k_dw(const __hip_bfloat16* h1, fp w, fp bias, __hip_bfloat16* h2) {
  int idx = blockIdx.x * 256 + threadIdx.x;
  if (idx >= NB * 256 * NHW) return;
  int hw = idx & 4095, t = idx >> 12;
  int c = t & 255, b = t >> 8;
  int y = hw >> 6, x = hw & 63;
  const __hip_bfloat16* p = h1 + ((size_t)(b * 256 + c)) * NHW;
  float acc = bias[c];
#pragma unroll
  for (int ky = 0; ky < 3; ky++) {
#pragma unroll
    for (int kx = 0; kx < 3; kx++) {
      int yy = y + ky - 1, xx = x + kx - 1;
      if (yy >= 0 && yy < 64 && xx >= 0 && xx < 64)
        acc += b2f(p[yy * 64 + xx]) * w[c * 9 + ky * 3 + kx];
    }
  }
  h2[idx] = f2b(gelu_ex(acc));
}

// ---------------- 14. mlp2 1x1 (r5 verbatim)
__global__ __launch_bounds__(256) void k_mlp2(const __hip_bfloat16* h2, fp w, fp bias, const float* e, float* tb_) {
  int idx = blockIdx.x * 256 + threadIdx.x;
  if (idx >= NB * 64 * NHW) return;
  int hw = idx & 4095, t = idx >> 12;
  int o = t & 63, b = t >> 6;
  const __hip_bfloat16* p = h2 + (size_t)b * 256 * NHW + hw;
  const float* wr = w + o * 256;
  float acc = bias[o];
#pragma unroll 8
  for (int c = 0; c < 256; c++) acc += b2f(p[(size_t)c * NHW]) * wr[c];
  tb_[idx] = acc + e[idx];
}

// ---------------- 15. up 1x1 (r5 verbatim)
__global__ __launch_bounds__(256) void k_up(const float* tb_, fp w, fp bias, float* out) {
  int idx = blockIdx.x * 256 + threadIdx.x;
  if (idx >= NB * 256 * NHW) return;
  int hw = idx & 4095, t = idx >> 12;
  int o = t & 255, b = t >> 8;
  const float* p = tb_ + (size_t)b * 64 * NHW + hw;
  const float* wr = w + o * 64;
  float acc = bias[o];
#pragma unroll 8
  for (int c = 0; c < 64; c++) acc += p[(size_t)c * NHW] * wr[c];
  out[idx] = acc;
}

extern "C" void kernel_launch(void* const* d_in, const int* in_sizes, int n_in,
                              void* d_out, int out_size, void* d_ws, size_t ws_size,
                              hipStream_t stream) {
  fp x = (fp)d_in[0], skip = (fp)d_in[1], qkv_w = (fp)d_in[2], qkv_b = (fp)d_in[3],
     proj_w = (fp)d_in[4], proj_b = (fp)d_in[5], edge_w = (fp)d_in[6], thick_w = (fp)d_in[7],
     thick_b = (fp)d_in[8], off_w = (fp)d_in[9], off_b = (fp)d_in[10], deform_w = (fp)d_in[11],
     deform_b = (fp)d_in[12], ln_g = (fp)d_in[13], ln_b = (fp)d_in[14], mlp1_w = (fp)d_in[15],
     mlp1_b = (fp)d_in[16], dw_w = (fp)d_in[17], dw_b = (fp)d_in[18], mlp2_w = (fp)d_in[19],
     mlp2_b = (fp)d_in[20], down_w = (fp)d_in[21], down_b = (fp)d_in[22], up_w = (fp)d_in[23],
     up_b = (fp)d_in[24];

  float* ws = (float*)d_ws;
  // ---- r5's EXACT workspace layout (8,192,000 slots = 31.25 MB proven) ----
  float* su    = ws + 0;              // f32 [0, 1048576)
  us* qkvb  = (us*)(ws + 1048576);    // bf16 [b][96][N]: [1048576, 1835008)
  float* av    = ws + 2621440;        // f32 [b][n][32]: [2621440, 3145728)
  __hip_bfloat16* x2   = (__hip_bfloat16*)(ws + 3145728);  // bf16 [3145728, 5242880)
  float* edge  = ws + 5242880;        // f32 [5242880, 6291456)
  float* offb  = ws + 6291456;        // f32 [6291456, 6586368)
  float* sm    = ws + 6586368;        // f32 (dead after k_edge)
  float* thick = ws + 6602752;        // f32 (dead after k_off)
  __hip_bfloat16* dbuf = (__hip_bfloat16*)(ws + 6619136);  // bf16 [6619136, 7143424)
  float* ebuf  = ws + 7143424;        // f32 [7143424, 8192000)
  // aliases of dead/late regions:
  us* xT   = (us*)x2;                 // xT live launches #2..#3; x2 written at #5 — disjoint
  us* wq   = (us*)dbuf;               // wq live #0..#3; dbuf written at #10 — disjoint (12,288 slots)
  us* wbf  = (us*)sm;                 // deform weights: written after k_off (r5 discipline)
  __hip_bfloat16* hn = (__hip_bfloat16*)qkvb;  // qkvb dead after k_attn
  __hip_bfloat16* h1 = x2;            // x2 dead after k_down
  __hip_bfloat16* h2 = (__hip_bfloat16*)ws;    // su dead after k_deform (spans su+qkvb+gap as r5)
  float* tbuf  = edge;                // edge dead after k_deform

  dim3 blk(256);
  k_wq<<<96, blk, 0, stream>>>(qkv_w, wq);
  k_upsample<<<(NB * 64 * NHW) / 256, blk, 0, stream>>>(skip, su);
  k_xpose<<<1024, blk, 0, stream>>>(x, xT);
  k_qkv_g<<<(NB * NHW) / 64, blk, 0, stream>>>(xT, wq, qkv_b, qkvb);
  k_attn<<<(NB * NHW) / 64, blk, 0, stream>>>(qkvb, av);
  k_proj<<<(NB * 256 * NHW) / 256, blk, 0, stream>>>(av, x, proj_w, proj_b, x2);
  k_meanthick<<<(NB * NHW) / 256, blk, 0, stream>>>(su, thick_w, thick_b, sm, thick);
  k_edge<<<(NB * 64 * NHW) / 256, blk, 0, stream>>>(sm, edge_w, edge);
  k_off<<<(NB * 18 * NHW) / 256, blk, 0, stream>>>(edge, off_w, off_b, thick, offb);
  k_wprep<<<144, blk, 0, stream>>>(deform_w, wbf);
  k_deform<<<NB * 64, blk, 0, stream>>>(su, offb, wbf, deform_b, edge, dbuf);
  k_down<<<(NB * 64 * NHW) / 256, blk, 0, stream>>>(x2, dbuf, down_w, down_b, ebuf);
  k_ln<<<(NB * NHW) / 256, blk, 0, stream>>>(ebuf, ln_g, ln_b, hn);
  k_mlp1<<<(NB * 256 * NHW) / 256, blk, 0, stream>>>(hn, mlp1_w, mlp1_b, h1);
  k_dw<<<(NB * 256 * NHW) / 256, blk, 0, stream>>>(h1, dw_w, dw_b, h2);
  k_mlp2<<<(NB * 64 * NHW) / 256, blk, 0, stream>>>(h2, mlp2_w, mlp2_b, ebuf, tbuf);
  k_up<<<(NB * 256 * NHW) / 256, blk, 0, stream>>>(tbuf, up_w, up_b, (float*)d_out);
}

// Round 9
// 554.167 us; speedup vs baseline: 3.5450x; 1.2368x over previous
//
#include <hip/hip_runtime.h>
#include <hip/hip_bf16.h>
#include <math.h>

#define NB 4
#define NHW 4096

typedef const float* fp;
typedef unsigned short us;
typedef __attribute__((ext_vector_type(8))) short short8;
typedef __attribute__((ext_vector_type(4))) float floatx4;

__device__ __forceinline__ float b2f(__hip_bfloat16 v) { return __bfloat162float(v); }
__device__ __forceinline__ __hip_bfloat16 f2b(float v) { return __float2bfloat16(v); }
__device__ __forceinline__ us f2bu(float f) {
  __hip_bfloat16 h = __float2bfloat16(f);
  return *reinterpret_cast<us*>(&h);
}
__device__ __forceinline__ float bu2f(us u) {
  __hip_bfloat16 h = *reinterpret_cast<__hip_bfloat16*>(&u);
  return __bfloat162float(h);
}
__device__ __forceinline__ float gelu_ex(float x) { return 0.5f * x * (1.0f + erff(x * 0.70710678118654752f)); }
__device__ __forceinline__ short8 ld8(const us* p) { return *(const short8*)p; }

// ---------------- 0a. cast qkv weights f32 [96][256] -> bf16
__global__ __launch_bounds__(256) void k_wq(fp qw, us* wq) {
  int i = blockIdx.x * 256 + threadIdx.x;
  if (i >= 96 * 256) return;
  wq[i] = f2bu(qw[i]);
}

// ---------------- 0b. cast proj [256][32] + mlp1 [256][64] weights -> bf16
__global__ __launch_bounds__(256) void k_wcast(fp pw, fp m1w, us* wc) {
  int i = blockIdx.x * 256 + threadIdx.x;
  if (i >= 24576) return;
  wc[i] = f2bu(i < 8192 ? pw[i] : m1w[i - 8192]);
}

// ---------------- 0c. deform weights: dw[oc][c][tap] -> wbf[tap][oc][c] bf16 (r5/r8 verbatim)
__global__ __launch_bounds__(256) void k_wprep(fp dw, us* wbf) {
  int idx = blockIdx.x * 256 + threadIdx.x;
  if (idx >= 9 * 64 * 64) return;
  int c = idx & 63, oc = (idx >> 6) & 63, k = idx >> 12;
  wbf[idx] = f2bu(dw[(oc * 64 + c) * 9 + k]);
}

// ---------------- 1. bilinear upsample -> su f32 (r8 verbatim)
__global__ __launch_bounds__(256) void k_upsample(fp skip, float* su) {
  int idx = blockIdx.x * 256 + threadIdx.x;
  if (idx >= NB * 64 * NHW) return;
  int hw = idx & 4095, bc = idx >> 12;
  int y = hw >> 6, x = hw & 63;
  float fy = 0.5f * y - 0.25f, fx = 0.5f * x - 0.25f;
  float y0f = floorf(fy), x0f = floorf(fx);
  float wy = fy - y0f, wx = fx - x0f;
  int y0 = (int)y0f, x0 = (int)x0f;
  int y0c = min(31, max(0, y0)), y1c = min(31, max(0, y0 + 1));
  int x0c = min(31, max(0, x0)), x1c = min(31, max(0, x0 + 1));
  const float* p = skip + (size_t)bc * 1024;
  float v00 = p[y0c * 32 + x0c], v01 = p[y0c * 32 + x1c];
  float v10 = p[y1c * 32 + x0c], v11 = p[y1c * 32 + x1c];
  su[idx] = (1.f - wy) * ((1.f - wx) * v00 + wx * v01) + wy * ((1.f - wx) * v10 + wx * v11);
}

// ---------------- 2. transpose x f32 [b][256][4096] -> xT bf16 [b*4096][256] (r8 verbatim)
__global__ __launch_bounds__(256) void k_xpose(fp x, us* xT) {
  __shared__ float tile[64][65];
  int bid = blockIdx.x;
  int pt = bid & 63, ct = (bid >> 6) & 3, b = bid >> 8;
  int px0 = pt * 64, c0 = ct * 64;
  int tx = threadIdx.x & 63, ty = threadIdx.x >> 6;
  const float* src = x + ((size_t)(b * 256 + c0)) * NHW + px0;
#pragma unroll
  for (int i = 0; i < 16; i++) {
    int r = i * 4 + ty;
    tile[r][tx] = src[(size_t)r * NHW + tx];
  }
  __syncthreads();
  int cseg = threadIdx.x & 7, p0 = threadIdx.x >> 3;
#pragma unroll
  for (int h = 0; h < 2; h++) {
    int p = p0 + h * 32;
    short8 v;
#pragma unroll
    for (int j = 0; j < 8; j++) v[j] = (short)f2bu(tile[cseg * 8 + j][p]);
    *(short8*)&xT[((size_t)(b * NHW) + px0 + p) * 256 + c0 + cseg * 8] = v;
  }
}

// ---------------- 3. qkv GEMM -> bf16 [b][96][N] ch-major (r8 verbatim)
__global__ __launch_bounds__(256) void k_qkv_g(const us* xT, const us* wq, fp bias, us* qkvb) {
  int wave = threadIdx.x >> 6, lane = threadIdx.x & 63;
  int quad = lane >> 4, l16 = lane & 15;
  int pxg0 = blockIdx.x * 64 + wave * 16;
  int b = pxg0 >> 12, hw0 = pxg0 & 4095;
  floatx4 acc[6];
#pragma unroll
  for (int m = 0; m < 6; m++) acc[m] = (floatx4){0.f, 0.f, 0.f, 0.f};
  const us* xrow = xT + (size_t)(pxg0 + l16) * 256 + quad * 8;
#pragma unroll
  for (int k0 = 0; k0 < 256; k0 += 32) {
    short8 bf = ld8(xrow + k0);
#pragma unroll
    for (int m = 0; m < 6; m++) {
      short8 af = ld8(wq + (size_t)(m * 16 + l16) * 256 + k0 + quad * 8);
      acc[m] = __builtin_amdgcn_mfma_f32_16x16x32_bf16(af, bf, acc[m], 0, 0, 0);
    }
  }
#pragma unroll
  for (int m = 0; m < 6; m++)
#pragma unroll
    for (int r = 0; r < 4; r++) {
      int oc = m * 16 + quad * 4 + r;
      float v = acc[m][r] + bias[oc];
      if (oc < 32) v *= 0.17677669529663688f;
      qkvb[(size_t)(b * 96 + oc) * NHW + hw0 + l16] = f2bu(v);
    }
}

// ---------------- 4. MFMA flash attention, SPLIT-K (2 halves).  Writes unnormalized partials.
// grid 512: blk = (b, qtile, kh).  Opart [kh*NB+b][q][32] f32; ml: m @ [kh*16384+qg], l @ +32768
__global__ __launch_bounds__(256) void k_attn(const us* qkvb, float* Opart, float* ml) {
  __shared__ __align__(16) us kt[128 * 40];
  __shared__ __align__(16) us vt[32 * 136];
  __shared__ __align__(16) us pt[4][16 * 136];
  int tid = threadIdx.x;
  int wave = tid >> 6, lane = tid & 63;
  int quad = lane >> 4, l16 = lane & 15;
  int blk = blockIdx.x;
  int kh = blk & 1;
  int rest = blk >> 1;
  int b = rest >> 6;
  int qbase = (rest & 63) * 64 + wave * 16;
  const us* qp = qkvb + (size_t)b * 96 * NHW;
  const us* kp = qp + 32 * NHW;
  const us* vp = qp + 64 * NHW;

  short8 aq;
#pragma unroll
  for (int j = 0; j < 8; j++)
    aq[j] = (short)qp[(size_t)(quad * 8 + j) * NHW + qbase + l16];

  float m_r[4], l_r[4];
  floatx4 o0 = {0.f, 0.f, 0.f, 0.f}, o1 = {0.f, 0.f, 0.f, 0.f};
#pragma unroll
  for (int r = 0; r < 4; r++) { m_r[r] = -1e30f; l_r[r] = 0.f; }

  int sc = tid & 31, sg = tid >> 5;
  int vc = tid >> 3, vs = tid & 7;

  int kb0 = kh * 2048;
  for (int kb = kb0; kb < kb0 + 2048; kb += 128) {
    __syncthreads();
    {
      const us* src = kp + (size_t)sc * NHW + kb + sg * 16;
#pragma unroll
      for (int j = 0; j < 16; j++) kt[(sg * 16 + j) * 40 + sc] = src[j];
      const us* sv = vp + (size_t)vc * NHW + kb + vs * 16;
      uint4 d0 = *(const uint4*)sv;
      uint4 d1 = *(const uint4*)(sv + 8);
      *(uint4*)&vt[vc * 136 + vs * 16] = d0;
      *(uint4*)&vt[vc * 136 + vs * 16 + 8] = d1;
    }
    __syncthreads();

    floatx4 s[8];
#pragma unroll
    for (int t = 0; t < 8; t++) {
      short8 bk = *(const short8*)&kt[(t * 16 + l16) * 40 + quad * 8];
      floatx4 z = {0.f, 0.f, 0.f, 0.f};
      s[t] = __builtin_amdgcn_mfma_f32_16x16x32_bf16(aq, bk, z, 0, 0, 0);
    }

    float mnew[4], alpha[4];
#pragma unroll
    for (int r = 0; r < 4; r++) {
      float mx = s[0][r];
#pragma unroll
      for (int t = 1; t < 8; t++) mx = fmaxf(mx, s[t][r]);
#pragma unroll
      for (int msk = 1; msk < 16; msk <<= 1) mx = fmaxf(mx, __shfl_xor(mx, msk, 64));
      mnew[r] = fmaxf(m_r[r], mx);
      alpha[r] = __expf(m_r[r] - mnew[r]);
      m_r[r] = mnew[r];
    }
    float rs[4] = {0.f, 0.f, 0.f, 0.f};
#pragma unroll
    for (int t = 0; t < 8; t++) {
#pragma unroll
      for (int r = 0; r < 4; r++) {
        float p = __expf(s[t][r] - mnew[r]);
        rs[r] += p;
        pt[wave][(quad * 4 + r) * 136 + t * 16 + l16] = f2bu(p);
      }
    }
#pragma unroll
    for (int r = 0; r < 4; r++) {
      float sm = rs[r];
#pragma unroll
      for (int msk = 1; msk < 16; msk <<= 1) sm += __shfl_xor(sm, msk, 64);
      l_r[r] = l_r[r] * alpha[r] + sm;
      o0[r] *= alpha[r];
      o1[r] *= alpha[r];
    }

#pragma unroll
    for (int t = 0; t < 4; t++) {
      short8 ap  = *(const short8*)&pt[wave][l16 * 136 + t * 32 + quad * 8];
      short8 bv0 = *(const short8*)&vt[l16 * 136 + t * 32 + quad * 8];
      short8 bv1 = *(const short8*)&vt[(l16 + 16) * 136 + t * 32 + quad * 8];
      o0 = __builtin_amdgcn_mfma_f32_16x16x32_bf16(ap, bv0, o0, 0, 0, 0);
      o1 = __builtin_amdgcn_mfma_f32_16x16x32_bf16(ap, bv1, o1, 0, 0, 0);
    }
  }

#pragma unroll
  for (int r = 0; r < 4; r++) {
    int q = qbase + quad * 4 + r;
    int qg = b * NHW + q;
    float* dst = Opart + ((size_t)(kh * NB * NHW) + qg) * 32;
    dst[l16] = o0[r];
    dst[l16 + 16] = o1[r];
    if (l16 == 0) {
      ml[kh * (NB * NHW) + qg] = m_r[r];
      ml[2 * NB * NHW + kh * (NB * NHW) + qg] = l_r[r];
    }
  }
}

// ---------------- 4b. merge split-K partials -> avb px-major bf16 [b*N][32]
__global__ __launch_bounds__(256) void k_merge(const float* Opart, const float* ml, us* avb) {
  int idx = blockIdx.x * 256 + threadIdx.x;    // NB*NHW*32
  int ch = idx & 31, qg = idx >> 5;
  float m0 = ml[qg], m1 = ml[NB * NHW + qg];
  float l0 = ml[2 * NB * NHW + qg], l1 = ml[3 * NB * NHW + qg];
  float m = fmaxf(m0, m1);
  float a0 = __expf(m0 - m), a1 = __expf(m1 - m);
  float l = l0 * a0 + l1 * a1;
  float v0 = Opart[(size_t)qg * 32 + ch];
  float v1 = Opart[((size_t)(NB * NHW) + qg) * 32 + ch];
  avb[idx] = f2bu((v0 * a0 + v1 * a1) / l);
}

// ---------------- 5. proj GEMM (Flavor A, qkv_g pattern): M=256, K=32, + residual x -> x2 ch-major bf16
__global__ __launch_bounds__(256) void k_proj_g(const us* avb, fp x, const us* wpj, fp bias, __hip_bfloat16* x2) {
  int wave = threadIdx.x >> 6, lane = threadIdx.x & 63;
  int quad = lane >> 4, l16 = lane & 15;
  int pxg0 = blockIdx.x * 64 + wave * 16;
  int b = pxg0 >> 12, hw0 = pxg0 & 4095;
  short8 bf = ld8(avb + (size_t)(pxg0 + l16) * 32 + quad * 8);
  floatx4 acc[16];
#pragma unroll
  for (int m = 0; m < 16; m++) {
    short8 af = ld8(wpj + (size_t)(m * 16 + l16) * 32 + quad * 8);
    floatx4 z = {0.f, 0.f, 0.f, 0.f};
    acc[m] = __builtin_amdgcn_mfma_f32_16x16x32_bf16(af, bf, z, 0, 0, 0);
  }
#pragma unroll
  for (int m = 0; m < 16; m++)
#pragma unroll
    for (int r = 0; r < 4; r++) {
      int oc = m * 16 + quad * 4 + r;
      size_t oidx = (size_t)(b * 256 + oc) * NHW + hw0 + l16;
      x2[oidx] = f2b(acc[m][r] + bias[oc] + x[oidx]);
    }
}

// ---------------- 6. channel mean + thick (r8 verbatim)
__global__ __launch_bounds__(256) void k_meanthick(const float* su, fp tw, fp tb, float* sm, float* thick) {
  int idx = blockIdx.x * 256 + threadIdx.x;
  if (idx >= NB * NHW) return;
  int hw = idx & 4095, b = idx >> 12;
  const float* p = su + (size_t)b * 64 * NHW + hw;
  float s = 0.f, ts = 0.f;
#pragma unroll 8
  for (int c = 0; c < 64; c++) {
    float v = p[(size_t)c * NHW];
    s += v;
    ts += v * tw[c];
  }
  sm[idx] = s * (1.f / 64.f);
  float z = ts + tb[0];
  thick[idx] = 1.f / (1.f + __expf(-z));
}

// ---------------- 7. edge conv 3x3 (r8 verbatim)
__global__ __launch_bounds__(256) void k_edge(const float* sm, fp ew, float* edge) {
  int idx = blockIdx.x * 256 + threadIdx.x;
  if (idx >= NB * 64 * NHW) return;
  int hw = idx & 4095, t = idx >> 12;
  int o = t & 63, b = t >> 6;
  int y = hw >> 6, x = hw & 63;
  const float* s = sm + (size_t)b * NHW;
  float acc = 0.f;
#pragma unroll
  for (int ky = 0; ky < 3; ky++) {
#pragma unroll
    for (int kx = 0; kx < 3; kx++) {
      int yy = y + ky - 1, xx = x + kx - 1;
      if (yy >= 0 && yy < 64 && xx >= 0 && xx < 64)
        acc += s[yy * 64 + xx] * ew[o * 9 + ky * 3 + kx];
    }
  }
  edge[idx] = acc;
}

// ---------------- 8. offset conv 3x3 (r8 verbatim)
__global__ __launch_bounds__(256) void k_off(const float* edge, fp ow, fp ob, const float* thick, float* off) {
  int idx = blockIdx.x * 256 + threadIdx.x;
  if (idx >= NB * 18 * NHW) return;
  int hw = idx & 4095, t = idx >> 12;
  int o = t % 18, b = t / 18;
  int y = hw >> 6, x = hw & 63;
  const float* e = edge + (size_t)b * 64 * NHW;
  float acc = ob[o];
  for (int j = 0; j < 9; j++) {
    int yy = y + j / 3 - 1, xx = x + j % 3 - 1;
    if (yy < 0 || yy > 63 || xx < 0 || xx > 63) continue;
    int p = yy * 64 + xx;
    const float* wr = ow + o * 576 + j;
#pragma unroll 8
    for (int c = 0; c < 64; c++) acc += e[(size_t)c * NHW + p] * wr[c * 9];
  }
  off[idx] = acc * (1.f + 16.f * thick[b * NHW + hw]);
}

// ---------------- 9. MFMA deformable conv (r8 verbatim)
__global__ __launch_bounds__(256) void k_deform(const float* su, const float* offb,
                                                const us* wbf, fp db,
                                                const float* edge, __hip_bfloat16* dbuf) {
  __shared__ __align__(16) us samT[4][16][72];
  int tid = threadIdx.x;
  int wave = tid >> 6, lane = tid & 63;
  int quad = lane >> 4, l16 = lane & 15;
  int b = blockIdx.x >> 6, row = blockIdx.x & 63;
  const float* sub = su + (size_t)b * 64 * NHW;

  int sp = lane & 15, sq = lane >> 4;
  int hw_s = row * 64 + wave * 16 + sp;
  int x_s = wave * 16 + sp;

  floatx4 acc[4];
#pragma unroll
  for (int a = 0; a < 4; a++) acc[a] = (floatx4){0.f, 0.f, 0.f, 0.f};

  for (int k = 0; k < 9; k++) {
    float dy = offb[((size_t)(b * 18 + 2 * k)) * NHW + hw_s];
    float dx = offb[((size_t)(b * 18 + 2 * k + 1)) * NHW + hw_s];
    float py = (float)(row + k / 3 - 1) + dy;
    float pxf = (float)(x_s + k % 3 - 1) + dx;
    float y0f = floorf(py), x0f = floorf(pxf);
    float wy = py - y0f, wx = pxf - x0f;
    int y0 = (int)y0f, x0 = (int)x0f;
    int y1 = y0 + 1, x1 = x0 + 1;
    float vy0 = (y0 >= 0 && y0 < 64) ? 1.f : 0.f;
    float vy1 = (y1 >= 0 && y1 < 64) ? 1.f : 0.f;
    float vx0 = (x0 >= 0 && x0 < 64) ? 1.f : 0.f;
    float vx1 = (x1 >= 0 && x1 < 64) ? 1.f : 0.f;
    float w00 = (1.f - wy) * (1.f - wx) * vy0 * vx0;
    float w01 = (1.f - wy) * wx * vy0 * vx1;
    float w10 = wy * (1.f - wx) * vy1 * vx0;
    float w11 = wy * wx * vy1 * vx1;
    int y0c = min(63, max(0, y0)), y1c = min(63, max(0, y1));
    int x0c = min(63, max(0, x0)), x1c = min(63, max(0, x1));
    int i00 = y0c * 64 + x0c, i01 = y0c * 64 + x1c;
    int i10 = y1c * 64 + x0c, i11 = y1c * 64 + x1c;

#pragma unroll
    for (int i = 0; i < 16; i += 2) {
      int c0 = sq * 16 + i;
      const float* s0 = sub + (size_t)c0 * NHW;
      const float* s1 = s0 + NHW;
      float v0 = w00 * s0[i00] + w01 * s0[i01] + w10 * s0[i10] + w11 * s0[i11];
      float v1 = w00 * s1[i00] + w01 * s1[i01] + w10 * s1[i10] + w11 * s1[i11];
      unsigned int pk = (unsigned int)f2bu(v0) | ((unsigned int)f2bu(v1) << 16);
      *(unsigned int*)&samT[wave][sp][c0] = pk;
    }

#pragma unroll
    for (int s = 0; s < 2; s++) {
      short8 bfrag = *(const short8*)&samT[wave][l16][s * 32 + quad * 8];
#pragma unroll
      for (int a = 0; a < 4; a++) {
        short8 afrag = ld8(wbf + ((size_t)(k * 64 + a * 16 + l16) * 64 + s * 32 + quad * 8));
        acc[a] = __builtin_amdgcn_mfma_f32_16x16x32_bf16(afrag, bfrag, acc[a], 0, 0, 0);
      }
    }
  }

#pragma unroll
  for (int a = 0; a < 4; a++)
#pragma unroll
    for (int r = 0; r < 4; r++) {
      int oc = a * 16 + quad * 4 + r;
      int px = wave * 16 + l16;
      size_t oidx = ((size_t)(b * 64 + oc)) * NHW + row * 64 + px;
      dbuf[oidx] = f2b(acc[a][r] + db[oc] + edge[oidx]);
    }
}

// ---------------- 10. down 1x1 (r8 verbatim)
__global__ __launch_bounds__(256) void k_down(const __hip_bfloat16* x2, const __hip_bfloat16* dd,
                                              fp w, fp bias, float* e) {
  int idx = blockIdx.x * 256 + threadIdx.x;
  if (idx >= NB * 64 * NHW) return;
  int hw = idx & 4095, t = idx >> 12;
  int o = t & 63, b = t >> 6;
  const float* wr = w + o * 320;
  float acc = bias[o];
  const __hip_bfloat16* xp = x2 + (size_t)b * 256 * NHW + hw;
#pragma unroll 8
  for (int c = 0; c < 256; c++) acc += b2f(xp[(size_t)c * NHW]) * wr[c];
  const __hip_bfloat16* dp = dd + (size_t)b * 64 * NHW + hw;
#pragma unroll 8
  for (int c = 0; c < 64; c++) acc += b2f(dp[(size_t)c * NHW]) * wr[256 + c];
  e[idx] = acc;
}

// ---------------- 11. LayerNorm -> hnT px-major bf16 [b*N][64] (coalesced row writes)
__global__ __launch_bounds__(256) void k_ln(const float* e, fp g, fp bt, us* hnT) {
  int idx = blockIdx.x * 256 + threadIdx.x;
  if (idx >= NB * NHW) return;
  int hw = idx & 4095, b = idx >> 12;
  const float* p = e + (size_t)b * 64 * NHW + hw;
  float v[64];
  float s = 0.f;
#pragma unroll
  for (int c = 0; c < 64; c++) { v[c] = p[(size_t)c * NHW]; s += v[c]; }
  float mu = s * (1.f / 64.f);
  float q = 0.f;
#pragma unroll
  for (int c = 0; c < 64; c++) { float d = v[c] - mu; q += d * d; }
  float rstd = rsqrtf(q * (1.f / 64.f) + 1e-5f);
  us* o = hnT + (size_t)idx * 64;
#pragma unroll
  for (int j = 0; j < 8; j++) {
    short8 pk;
#pragma unroll
    for (int t = 0; t < 8; t++) {
      int c = j * 8 + t;
      pk[t] = (short)f2bu((v[c] - mu) * rstd * g[c] + bt[c]);
    }
    *(short8*)(o + j * 8) = pk;
  }
}

// ---------------- 12. mlp1 GEMM (Flavor A): M=256, K=64, GELU -> h1 ch-major bf16
__global__ __launch_bounds__(256) void k_mlp1_g(const us* hnT, const us* wm1, fp bias, __hip_bfloat16* h1) {
  int wave = threadIdx.x >> 6, lane = threadIdx.x & 63;
  int quad = lane >> 4, l16 = lane & 15;
  int pxg0 = blockIdx.x * 64 + wave * 16;
  int b = pxg0 >> 12, hw0 = pxg0 & 4095;
  floatx4 acc[16];
#pragma unroll
  for (int m = 0; m < 16; m++) acc[m] = (floatx4){0.f, 0.f, 0.f, 0.f};
  const us* hrow = hnT + (size_t)(pxg0 + l16) * 64 + quad * 8;
#pragma unroll
  for (int k0 = 0; k0 < 64; k0 += 32) {
    short8 bf = ld8(hrow + k0);
#pragma unroll
    for (int m = 0; m < 16; m++) {
      short8 af = ld8(wm1 + (size_t)(m * 16 + l16) * 64 + k0 + quad * 8);
      acc[m] = __builtin_amdgcn_mfma_f32_16x16x32_bf16(af, bf, acc[m], 0, 0, 0);
    }
  }
#pragma unroll
  for (int m = 0; m < 16; m++)
#pragma unroll
    for (int r = 0; r < 4; r++) {
      int oc = m * 16 + quad * 4 + r;
      size_t oidx = (size_t)(b * 256 + oc) * NHW + hw0 + l16;
      h1[oidx] = f2b(gelu_ex(acc[m][r] + bias[oc]));
    }
}

// ---------------- 13. depthwise 3x3 (r8 verbatim, ch-major)
__global__ __launch_bounds__(256) void k_dw(const __hip_bfloat16* h1, fp w, fp bias, __hip_bfloat16* h2) {
  int idx = blockIdx.x * 256 + threadIdx.x;
  if (idx >= NB * 256 * NHW) return;
  int hw = idx & 4095, t = idx >> 12;
  int c = t & 255, b = t >> 8;
  int y = hw >> 6, x = hw & 63;
  const __hip_bfloat16* p = h1 + ((size_t)(b * 256 + c)) * NHW;
  float acc = bias[c];
#pragma unroll
  for (int ky = 0; ky < 3; ky++) {
#pragma unroll
    for (int kx = 0; kx < 3; kx++) {
      int yy = y + ky - 1, xx = x + kx - 1;
      if (yy >= 0 && yy < 64 && xx >= 0 && xx < 64)
        acc += b2f(p[yy * 64 + xx]) * w[c * 9 + ky * 3 + kx];
    }
  }
  h2[idx] = f2b(gelu_ex(acc));
}

// ---------------- 14. mlp2 1x1 (r8 verbatim)
__global__ __launch_bounds__(256) void k_mlp2(const __hip_bfloat16* h2, fp w, fp bias, const float* e, float* tb_) {
  int idx = blockIdx.x * 256 + threadIdx.x;
  if (idx >= NB * 64 * NHW) return;
  int hw = idx & 4095, t = idx >> 12;
  int o = t & 63, b = t >> 6;
  const __hip_bfloat16* p = h2 + (size_t)b * 256 * NHW + hw;
  const float* wr = w + o * 256;
  float acc = bias[o];
#pragma unroll 8
  for (int c = 0; c < 256; c++) acc += b2f(p[(size_t)c * NHW]) * wr[c];
  tb_[idx] = acc + e[idx];
}

// ---------------- 15. up 1x1 (r8 verbatim)
__global__ __launch_bounds__(256) void k_up(const float* tb_, fp w, fp bias, float* out) {
  int idx = blockIdx.x * 256 + threadIdx.x;
  if (idx >= NB * 256 * NHW) return;
  int hw = idx & 4095, t = idx >> 12;
  int o = t & 255, b = t >> 8;
  const float* p = tb_ + (size_t)b * 64 * NHW + hw;
  const float* wr = w + o * 64;
  float acc = bias[o];
#pragma unroll 8
  for (int c = 0; c < 64; c++) acc += p[(size_t)c * NHW] * wr[c];
  out[idx] = acc;
}

extern "C" void kernel_launch(void* const* d_in, const int* in_sizes, int n_in,
                              void* d_out, int out_size, void* d_ws, size_t ws_size,
                              hipStream_t stream) {
  fp x = (fp)d_in[0], skip = (fp)d_in[1], qkv_w = (fp)d_in[2], qkv_b = (fp)d_in[3],
     proj_w = (fp)d_in[4], proj_b = (fp)d_in[5], edge_w = (fp)d_in[6], thick_w = (fp)d_in[7],
     thick_b = (fp)d_in[8], off_w = (fp)d_in[9], off_b = (fp)d_in[10], deform_w = (fp)d_in[11],
     deform_b = (fp)d_in[12], ln_g = (fp)d_in[13], ln_b = (fp)d_in[14], mlp1_w = (fp)d_in[15],
     mlp1_b = (fp)d_in[16], dw_w = (fp)d_in[17], dw_b = (fp)d_in[18], mlp2_w = (fp)d_in[19],
     mlp2_b = (fp)d_in[20], down_w = (fp)d_in[21], down_b = (fp)d_in[22], up_w = (fp)d_in[23],
     up_b = (fp)d_in[24];

  float* ws = (float*)d_ws;
  // ---- r8's workspace layout (8,192,000 slots = 31.25 MB proven), gap reused ----
  float* su    = ws + 0;              // f32 [0, 1048576)
  us* qkvb  = (us*)(ws + 1048576);    // bf16 [1048576, 1835008)
  us* avb   = (us*)(ws + 1835008);    // bf16 524,288 elems [1835008, 2097152)
  us* wc    = (us*)(ws + 2097152);    // bf16 24,576 elems  [2097152, 2109440)
  float* ml = ws + 2109440;           // f32 65,536         [2109440, 2174976)
  __hip_bfloat16* x2   = (__hip_bfloat16*)(ws + 3145728);  // bf16 [3145728, 5242880)
  float* edge  = ws + 5242880;        // f32 [5242880, 6291456)
  float* offb  = ws + 6291456;        // f32 [6291456, 6586368)
  float* sm    = ws + 6586368;        // f32 (dead after k_edge)
  float* thick = ws + 6602752;        // f32 (dead after k_off)
  __hip_bfloat16* dbuf = (__hip_bfloat16*)(ws + 6619136);  // bf16 [6619136, 7143424)
  float* ebuf  = ws + 7143424;        // f32 [7143424, 8192000)
  // aliases of dead/late regions:
  us* xT   = (us*)x2;                 // xT live #2..#4; x2 written #7 — disjoint
  us* wq   = (us*)dbuf;               // wq live #0..#4; dbuf written #12 — disjoint
  us* wbf  = (us*)sm;                 // deform weights, written after k_off (r8 discipline)
  float* Opart = ebuf;                // attn partials; dead before k_down writes ebuf
  us* hnT  = qkvb;                    // qkvb dead after k_attn; hnT = 1,048,576 bf16 fits 786,432-slot region
  __hip_bfloat16* h1 = x2;            // x2 dead after k_down
  __hip_bfloat16* h2 = (__hip_bfloat16*)ws;    // su+qkvb/hnT+avb regions dead by k_dw ([0, 2097152) slots)
  float* tbuf  = edge;                // edge dead after k_deform

  dim3 blk(256);
  k_wq<<<96, blk, 0, stream>>>(qkv_w, wq);
  k_wcast<<<96, blk, 0, stream>>>(proj_w, mlp1_w, wc);
  k_upsample<<<(NB * 64 * NHW) / 256, blk, 0, stream>>>(skip, su);
  k_xpose<<<1024, blk, 0, stream>>>(x, xT);
  k_qkv_g<<<(NB * NHW) / 64, blk, 0, stream>>>(xT, wq, qkv_b, qkvb);
  k_attn<<<(NB * NHW) / 32, blk, 0, stream>>>(qkvb, Opart, ml);
  k_merge<<<(NB * NHW * 32) / 256, blk, 0, stream>>>(Opart, ml, avb);
  k_proj_g<<<(NB * NHW) / 64, blk, 0, stream>>>(avb, x, wc, proj_b, x2);
  k_meanthick<<<(NB * NHW) / 256, blk, 0, stream>>>(su, thick_w, thick_b, sm, thick);
  k_edge<<<(NB * 64 * NHW) / 256, blk, 0, stream>>>(sm, edge_w, edge);
  k_off<<<(NB * 18 * NHW) / 256, blk, 0, stream>>>(edge, off_w, off_b, thick, offb);
  k_wprep<<<144, blk, 0, stream>>>(deform_w, wbf);
  k_deform<<<NB * 64, blk, 0, stream>>>(su, offb, wbf, deform_b, edge, dbuf);
  k_down<<<(NB * 64 * NHW) / 256, blk, 0, stream>>>(x2, dbuf, down_w, down_b, ebuf);
  k_ln<<<(NB * NHW) / 256, blk, 0, stream>>>(ebuf, ln_g, ln_b, hnT);
  k_mlp1_g<<<(NB * NHW) / 64, blk, 0, stream>>>(hnT, wc + 8192, mlp1_b, h1);
  k_dw<<<(NB * 256 * NHW) / 256, blk, 0, stream>>>(h1, dw_w, dw_b, h2);
  k_mlp2<<<(NB * 64 * NHW) / 256, blk, 0, stream>>>(h2, mlp2_w, mlp2_b, ebuf, tbuf);
  k_up<<<(NB * 256 * NHW) / 256, blk, 0, stream>>>(tbuf, up_w, up_b, (float*)d_out);
}

// Round 10
// 478.382 us; speedup vs baseline: 4.1066x; 1.1584x over previous
//
#include <hip/hip_runtime.h>
#include <hip/hip_bf16.h>
#include <math.h>

#define NB 4
#define NHW 4096

typedef const float* fp;
typedef unsigned short us;
typedef __attribute__((ext_vector_type(8))) short short8;
typedef __attribute__((ext_vector_type(4))) float floatx4;

__device__ __forceinline__ float b2f(__hip_bfloat16 v) { return __bfloat162float(v); }
__device__ __forceinline__ __hip_bfloat16 f2b(float v) { return __float2bfloat16(v); }
__device__ __forceinline__ us f2bu(float f) {
  __hip_bfloat16 h = __float2bfloat16(f);
  return *reinterpret_cast<us*>(&h);
}
__device__ __forceinline__ float bu2f(us u) {
  __hip_bfloat16 h = *reinterpret_cast<__hip_bfloat16*>(&u);
  return __bfloat162float(h);
}
__device__ __forceinline__ float gelu_ex(float x) { return 0.5f * x * (1.0f + erff(x * 0.70710678118654752f)); }
__device__ __forceinline__ short8 ld8(const us* p) { return *(const short8*)p; }

// ---------------- 0a. cast qkv weights f32 [96][256] -> bf16
__global__ __launch_bounds__(256) void k_wq(fp qw, us* wq) {
  int i = blockIdx.x * 256 + threadIdx.x;
  if (i >= 96 * 256) return;
  wq[i] = f2bu(qw[i]);
}

// ---------------- 0b. cast proj [256][32] + mlp1 [256][64] + down [64][320] weights -> bf16
__global__ __launch_bounds__(256) void k_wcast(fp pw, fp m1w, fp dnw, us* wc) {
  int i = blockIdx.x * 256 + threadIdx.x;
  if (i >= 45056) return;
  float v;
  if (i < 8192) v = pw[i];
  else if (i < 24576) v = m1w[i - 8192];
  else v = dnw[i - 24576];
  wc[i] = f2bu(v);
}

// ---------------- 0c. deform weights: dw[oc][c][tap] -> wbf[tap][oc][c] bf16 (r8 verbatim)
__global__ __launch_bounds__(256) void k_wprep(fp dw, us* wbf) {
  int idx = blockIdx.x * 256 + threadIdx.x;
  if (idx >= 9 * 64 * 64) return;
  int c = idx & 63, oc = (idx >> 6) & 63, k = idx >> 12;
  wbf[idx] = f2bu(dw[(oc * 64 + c) * 9 + k]);
}

// ---------------- 1. bilinear upsample -> su f32 (r8 verbatim)
__global__ __launch_bounds__(256) void k_upsample(fp skip, float* su) {
  int idx = blockIdx.x * 256 + threadIdx.x;
  if (idx >= NB * 64 * NHW) return;
  int hw = idx & 4095, bc = idx >> 12;
  int y = hw >> 6, x = hw & 63;
  float fy = 0.5f * y - 0.25f, fx = 0.5f * x - 0.25f;
  float y0f = floorf(fy), x0f = floorf(fx);
  float wy = fy - y0f, wx = fx - x0f;
  int y0 = (int)y0f, x0 = (int)x0f;
  int y0c = min(31, max(0, y0)), y1c = min(31, max(0, y0 + 1));
  int x0c = min(31, max(0, x0)), x1c = min(31, max(0, x0 + 1));
  const float* p = skip + (size_t)bc * 1024;
  float v00 = p[y0c * 32 + x0c], v01 = p[y0c * 32 + x1c];
  float v10 = p[y1c * 32 + x0c], v11 = p[y1c * 32 + x1c];
  su[idx] = (1.f - wy) * ((1.f - wx) * v00 + wx * v01) + wy * ((1.f - wx) * v10 + wx * v11);
}

// ---------------- 2. transpose x f32 -> xT bf16 [b*4096][256] (r8 verbatim)
__global__ __launch_bounds__(256) void k_xpose(fp x, us* xT) {
  __shared__ float tile[64][65];
  int bid = blockIdx.x;
  int pt = bid & 63, ct = (bid >> 6) & 3, b = bid >> 8;
  int px0 = pt * 64, c0 = ct * 64;
  int tx = threadIdx.x & 63, ty = threadIdx.x >> 6;
  const float* src = x + ((size_t)(b * 256 + c0)) * NHW + px0;
#pragma unroll
  for (int i = 0; i < 16; i++) {
    int r = i * 4 + ty;
    tile[r][tx] = src[(size_t)r * NHW + tx];
  }
  __syncthreads();
  int cseg = threadIdx.x & 7, p0 = threadIdx.x >> 3;
#pragma unroll
  for (int h = 0; h < 2; h++) {
    int p = p0 + h * 32;
    short8 v;
#pragma unroll
    for (int j = 0; j < 8; j++) v[j] = (short)f2bu(tile[cseg * 8 + j][p]);
    *(short8*)&xT[((size_t)(b * NHW) + px0 + p) * 256 + c0 + cseg * 8] = v;
  }
}

// ---------------- 3. qkv GEMM -> bf16 [b][96][N] ch-major (r8 verbatim)
__global__ __launch_bounds__(256) void k_qkv_g(const us* xT, const us* wq, fp bias, us* qkvb) {
  int wave = threadIdx.x >> 6, lane = threadIdx.x & 63;
  int quad = lane >> 4, l16 = lane & 15;
  int pxg0 = blockIdx.x * 64 + wave * 16;
  int b = pxg0 >> 12, hw0 = pxg0 & 4095;
  floatx4 acc[6];
#pragma unroll
  for (int m = 0; m < 6; m++) acc[m] = (floatx4){0.f, 0.f, 0.f, 0.f};
  const us* xrow = xT + (size_t)(pxg0 + l16) * 256 + quad * 8;
#pragma unroll
  for (int k0 = 0; k0 < 256; k0 += 32) {
    short8 bf = ld8(xrow + k0);
#pragma unroll
    for (int m = 0; m < 6; m++) {
      short8 af = ld8(wq + (size_t)(m * 16 + l16) * 256 + k0 + quad * 8);
      acc[m] = __builtin_amdgcn_mfma_f32_16x16x32_bf16(af, bf, acc[m], 0, 0, 0);
    }
  }
#pragma unroll
  for (int m = 0; m < 6; m++)
#pragma unroll
    for (int r = 0; r < 4; r++) {
      int oc = m * 16 + quad * 4 + r;
      float v = acc[m][r] + bias[oc];
      if (oc < 32) v *= 0.17677669529663688f;
      qkvb[(size_t)(b * 96 + oc) * NHW + hw0 + l16] = f2bu(v);
    }
}

// ---------------- 4. MFMA flash attention, SPLIT-K (r9 verbatim)
__global__ __launch_bounds__(256) void k_attn(const us* qkvb, float* Opart, float* ml) {
  __shared__ __align__(16) us kt[128 * 40];
  __shared__ __align__(16) us vt[32 * 136];
  __shared__ __align__(16) us pt[4][16 * 136];
  int tid = threadIdx.x;
  int wave = tid >> 6, lane = tid & 63;
  int quad = lane >> 4, l16 = lane & 15;
  int blk = blockIdx.x;
  int kh = blk & 1;
  int rest = blk >> 1;
  int b = rest >> 6;
  int qbase = (rest & 63) * 64 + wave * 16;
  const us* qp = qkvb + (size_t)b * 96 * NHW;
  const us* kp = qp + 32 * NHW;
  const us* vp = qp + 64 * NHW;

  short8 aq;
#pragma unroll
  for (int j = 0; j < 8; j++)
    aq[j] = (short)qp[(size_t)(quad * 8 + j) * NHW + qbase + l16];

  float m_r[4], l_r[4];
  floatx4 o0 = {0.f, 0.f, 0.f, 0.f}, o1 = {0.f, 0.f, 0.f, 0.f};
#pragma unroll
  for (int r = 0; r < 4; r++) { m_r[r] = -1e30f; l_r[r] = 0.f; }

  int sc = tid & 31, sg = tid >> 5;
  int vc = tid >> 3, vs = tid & 7;

  int kb0 = kh * 2048;
  for (int kb = kb0; kb < kb0 + 2048; kb += 128) {
    __syncthreads();
    {
      const us* src = kp + (size_t)sc * NHW + kb + sg * 16;
#pragma unroll
      for (int j = 0; j < 16; j++) kt[(sg * 16 + j) * 40 + sc] = src[j];
      const us* sv = vp + (size_t)vc * NHW + kb + vs * 16;
      uint4 d0 = *(const uint4*)sv;
      uint4 d1 = *(const uint4*)(sv + 8);
      *(uint4*)&vt[vc * 136 + vs * 16] = d0;
      *(uint4*)&vt[vc * 136 + vs * 16 + 8] = d1;
    }
    __syncthreads();

    floatx4 s[8];
#pragma unroll
    for (int t = 0; t < 8; t++) {
      short8 bk = *(const short8*)&kt[(t * 16 + l16) * 40 + quad * 8];
      floatx4 z = {0.f, 0.f, 0.f, 0.f};
      s[t] = __builtin_amdgcn_mfma_f32_16x16x32_bf16(aq, bk, z, 0, 0, 0);
    }

    float mnew[4], alpha[4];
#pragma unroll
    for (int r = 0; r < 4; r++) {
      float mx = s[0][r];
#pragma unroll
      for (int t = 1; t < 8; t++) mx = fmaxf(mx, s[t][r]);
#pragma unroll
      for (int msk = 1; msk < 16; msk <<= 1) mx = fmaxf(mx, __shfl_xor(mx, msk, 64));
      mnew[r] = fmaxf(m_r[r], mx);
      alpha[r] = __expf(m_r[r] - mnew[r]);
      m_r[r] = mnew[r];
    }
    float rs[4] = {0.f, 0.f, 0.f, 0.f};
#pragma unroll
    for (int t = 0; t < 8; t++) {
#pragma unroll
      for (int r = 0; r < 4; r++) {
        float p = __expf(s[t][r] - mnew[r]);
        rs[r] += p;
        pt[wave][(quad * 4 + r) * 136 + t * 16 + l16] = f2bu(p);
      }
    }
#pragma unroll
    for (int r = 0; r < 4; r++) {
      float sm = rs[r];
#pragma unroll
      for (int msk = 1; msk < 16; msk <<= 1) sm += __shfl_xor(sm, msk, 64);
      l_r[r] = l_r[r] * alpha[r] + sm;
      o0[r] *= alpha[r];
      o1[r] *= alpha[r];
    }

#pragma unroll
    for (int t = 0; t < 4; t++) {
      short8 ap  = *(const short8*)&pt[wave][l16 * 136 + t * 32 + quad * 8];
      short8 bv0 = *(const short8*)&vt[l16 * 136 + t * 32 + quad * 8];
      short8 bv1 = *(const short8*)&vt[(l16 + 16) * 136 + t * 32 + quad * 8];
      o0 = __builtin_amdgcn_mfma_f32_16x16x32_bf16(ap, bv0, o0, 0, 0, 0);
      o1 = __builtin_amdgcn_mfma_f32_16x16x32_bf16(ap, bv1, o1, 0, 0, 0);
    }
  }

#pragma unroll
  for (int r = 0; r < 4; r++) {
    int q = qbase + quad * 4 + r;
    int qg = b * NHW + q;
    float* dst = Opart + ((size_t)(kh * NB * NHW) + qg) * 32;
    dst[l16] = o0[r];
    dst[l16 + 16] = o1[r];
    if (l16 == 0) {
      ml[kh * (NB * NHW) + qg] = m_r[r];
      ml[2 * NB * NHW + kh * (NB * NHW) + qg] = l_r[r];
    }
  }
}

// ---------------- 4b. merge split-K partials -> avb px-major bf16 (r9 verbatim)
__global__ __launch_bounds__(256) void k_merge(const float* Opart, const float* ml, us* avb) {
  int idx = blockIdx.x * 256 + threadIdx.x;
  int ch = idx & 31, qg = idx >> 5;
  float m0 = ml[qg], m1 = ml[NB * NHW + qg];
  float l0 = ml[2 * NB * NHW + qg], l1 = ml[3 * NB * NHW + qg];
  float m = fmaxf(m0, m1);
  float a0 = __expf(m0 - m), a1 = __expf(m1 - m);
  float l = l0 * a0 + l1 * a1;
  float v0 = Opart[(size_t)qg * 32 + ch];
  float v1 = Opart[((size_t)(NB * NHW) + qg) * 32 + ch];
  avb[idx] = f2bu((v0 * a0 + v1 * a1) / l);
}

// ---------------- 5. proj GEMM (act-first): D[px][oc] -> x2T px-major bf16, residual from xT in-place
__global__ __launch_bounds__(256) void k_proj_g(const us* avb, const us* xT, const us* wpj, fp bias, us* x2T) {
  int wave = threadIdx.x >> 6, lane = threadIdx.x & 63;
  int quad = lane >> 4, l16 = lane & 15;
  int pxg0 = blockIdx.x * 64 + wave * 16;
  short8 act = ld8(avb + (size_t)(pxg0 + l16) * 32 + quad * 8);
  floatx4 acc[16];
#pragma unroll
  for (int n = 0; n < 16; n++) {
    short8 wf = ld8(wpj + (size_t)(n * 16 + l16) * 32 + quad * 8);
    floatx4 z = {0.f, 0.f, 0.f, 0.f};
    acc[n] = __builtin_amdgcn_mfma_f32_16x16x32_bf16(act, wf, z, 0, 0, 0);
  }
#pragma unroll
  for (int n = 0; n < 16; n++)
#pragma unroll
    for (int r = 0; r < 4; r++) {
      int px = pxg0 + quad * 4 + r;
      int oc = n * 16 + l16;
      size_t oidx = (size_t)px * 256 + oc;
      x2T[oidx] = f2bu(acc[n][r] + bias[oc] + bu2f(xT[oidx]));
    }
}

// ---------------- 6. channel mean + thick (r8 verbatim)
__global__ __launch_bounds__(256) void k_meanthick(const float* su, fp tw, fp tb, float* sm, float* thick) {
  int idx = blockIdx.x * 256 + threadIdx.x;
  if (idx >= NB * NHW) return;
  int hw = idx & 4095, b = idx >> 12;
  const float* p = su + (size_t)b * 64 * NHW + hw;
  float s = 0.f, ts = 0.f;
#pragma unroll 8
  for (int c = 0; c < 64; c++) {
    float v = p[(size_t)c * NHW];
    s += v;
    ts += v * tw[c];
  }
  sm[idx] = s * (1.f / 64.f);
  float z = ts + tb[0];
  thick[idx] = 1.f / (1.f + __expf(-z));
}

// ---------------- 7. edge conv 3x3 (r8 verbatim)
__global__ __launch_bounds__(256) void k_edge(const float* sm, fp ew, float* edge) {
  int idx = blockIdx.x * 256 + threadIdx.x;
  if (idx >= NB * 64 * NHW) return;
  int hw = idx & 4095, t = idx >> 12;
  int o = t & 63, b = t >> 6;
  int y = hw >> 6, x = hw & 63;
  const float* s = sm + (size_t)b * NHW;
  float acc = 0.f;
#pragma unroll
  for (int ky = 0; ky < 3; ky++) {
#pragma unroll
    for (int kx = 0; kx < 3; kx++) {
      int yy = y + ky - 1, xx = x + kx - 1;
      if (yy >= 0 && yy < 64 && xx >= 0 && xx < 64)
        acc += s[yy * 64 + xx] * ew[o * 9 + ky * 3 + kx];
    }
  }
  edge[idx] = acc;
}

// ---------------- 8. offset conv 3x3 (r8 verbatim)
__global__ __launch_bounds__(256) void k_off(const float* edge, fp ow, fp ob, const float* thick, float* off) {
  int idx = blockIdx.x * 256 + threadIdx.x;
  if (idx >= NB * 18 * NHW) return;
  int hw = idx & 4095, t = idx >> 12;
  int o = t % 18, b = t / 18;
  int y = hw >> 6, x = hw & 63;
  const float* e = edge + (size_t)b * 64 * NHW;
  float acc = ob[o];
  for (int j = 0; j < 9; j++) {
    int yy = y + j / 3 - 1, xx = x + j % 3 - 1;
    if (yy < 0 || yy > 63 || xx < 0 || xx > 63) continue;
    int p = yy * 64 + xx;
    const float* wr = ow + o * 576 + j;
#pragma unroll 8
    for (int c = 0; c < 64; c++) acc += e[(size_t)c * NHW + p] * wr[c * 9];
  }
  off[idx] = acc * (1.f + 16.f * thick[b * NHW + hw]);
}

// ---------------- 9. MFMA deformable conv (operand-swapped): D[px][oc] -> dbufT px-major bf16
__global__ __launch_bounds__(256) void k_deform(const float* su, const float* offb,
                                                const us* wbf, fp db,
                                                const float* edge, us* dbufT) {
  __shared__ __align__(16) us samT[4][16][72];
  int tid = threadIdx.x;
  int wave = tid >> 6, lane = tid & 63;
  int quad = lane >> 4, l16 = lane & 15;
  int b = blockIdx.x >> 6, row = blockIdx.x & 63;
  const float* sub = su + (size_t)b * 64 * NHW;

  int sp = lane & 15, sq = lane >> 4;
  int hw_s = row * 64 + wave * 16 + sp;
  int x_s = wave * 16 + sp;

  floatx4 acc[4];
#pragma unroll
  for (int a = 0; a < 4; a++) acc[a] = (floatx4){0.f, 0.f, 0.f, 0.f};

  for (int k = 0; k < 9; k++) {
    float dy = offb[((size_t)(b * 18 + 2 * k)) * NHW + hw_s];
    float dx = offb[((size_t)(b * 18 + 2 * k + 1)) * NHW + hw_s];
    float py = (float)(row + k / 3 - 1) + dy;
    float pxf = (float)(x_s + k % 3 - 1) + dx;
    float y0f = floorf(py), x0f = floorf(pxf);
    float wy = py - y0f, wx = pxf - x0f;
    int y0 = (int)y0f, x0 = (int)x0f;
    int y1 = y0 + 1, x1 = x0 + 1;
    float vy0 = (y0 >= 0 && y0 < 64) ? 1.f : 0.f;
    float vy1 = (y1 >= 0 && y1 < 64) ? 1.f : 0.f;
    float vx0 = (x0 >= 0 && x0 < 64) ? 1.f : 0.f;
    float vx1 = (x1 >= 0 && x1 < 64) ? 1.f : 0.f;
    float w00 = (1.f - wy) * (1.f - wx) * vy0 * vx0;
    float w01 = (1.f - wy) * wx * vy0 * vx1;
    float w10 = wy * (1.f - wx) * vy1 * vx0;
    float w11 = wy * wx * vy1 * vx1;
    int y0c = min(63, max(0, y0)), y1c = min(63, max(0, y1));
    int x0c = min(63, max(0, x0)), x1c = min(63, max(0, x1));
    int i00 = y0c * 64 + x0c, i01 = y0c * 64 + x1c;
    int i10 = y1c * 64 + x0c, i11 = y1c * 64 + x1c;

#pragma unroll
    for (int i = 0; i < 16; i += 2) {
      int c0 = sq * 16 + i;
      const float* s0 = sub + (size_t)c0 * NHW;
      const float* s1 = s0 + NHW;
      float v0 = w00 * s0[i00] + w01 * s0[i01] + w10 * s0[i10] + w11 * s0[i11];
      float v1 = w00 * s1[i00] + w01 * s1[i01] + w10 * s1[i10] + w11 * s1[i11];
      unsigned int pk = (unsigned int)f2bu(v0) | ((unsigned int)f2bu(v1) << 16);
      *(unsigned int*)&samT[wave][sp][c0] = pk;
    }

#pragma unroll
    for (int s = 0; s < 2; s++) {
      short8 bfrag = *(const short8*)&samT[wave][l16][s * 32 + quad * 8];
#pragma unroll
      for (int a = 0; a < 4; a++) {
        short8 afrag = ld8(wbf + ((size_t)(k * 64 + a * 16 + l16) * 64 + s * 32 + quad * 8));
        // samples-first: D row (quad*4+r) = px-local, col (l16) = oc
        acc[a] = __builtin_amdgcn_mfma_f32_16x16x32_bf16(bfrag, afrag, acc[a], 0, 0, 0);
      }
    }
  }

#pragma unroll
  for (int a = 0; a < 4; a++)
#pragma unroll
    for (int r = 0; r < 4; r++) {
      int oc = a * 16 + l16;
      int pxr = row * 64 + wave * 16 + quad * 4 + r;
      float v = acc[a][r] + db[oc] + edge[(size_t)(b * 64 + oc) * NHW + pxr];
      dbufT[((size_t)(b * NHW) + pxr) * 64 + oc] = f2bu(v);
    }
}

// ---------------- 10. down GEMM (qkv_g pattern): A=wd rows [64][320], B=x2T/dbufT rows -> ebuf ch-major f32
__global__ __launch_bounds__(256) void k_down_g(const us* x2T, const us* dbufT, const us* wd, fp bias, float* ebuf) {
  int wave = threadIdx.x >> 6, lane = threadIdx.x & 63;
  int quad = lane >> 4, l16 = lane & 15;
  int pxg0 = blockIdx.x * 64 + wave * 16;
  int b = pxg0 >> 12, hw0 = pxg0 & 4095;
  floatx4 acc[4];
#pragma unroll
  for (int m = 0; m < 4; m++) acc[m] = (floatx4){0.f, 0.f, 0.f, 0.f};
  const us* xrow = x2T + (size_t)(pxg0 + l16) * 256 + quad * 8;
#pragma unroll
  for (int k0 = 0; k0 < 256; k0 += 32) {
    short8 bf = ld8(xrow + k0);
#pragma unroll
    for (int m = 0; m < 4; m++) {
      short8 af = ld8(wd + (size_t)(m * 16 + l16) * 320 + k0 + quad * 8);
      acc[m] = __builtin_amdgcn_mfma_f32_16x16x32_bf16(af, bf, acc[m], 0, 0, 0);
    }
  }
  const us* drow = dbufT + (size_t)(pxg0 + l16) * 64 + quad * 8;
#pragma unroll
  for (int k0 = 0; k0 < 64; k0 += 32) {
    short8 bf = ld8(drow + k0);
#pragma unroll
    for (int m = 0; m < 4; m++) {
      short8 af = ld8(wd + (size_t)(m * 16 + l16) * 320 + 256 + k0 + quad * 8);
      acc[m] = __builtin_amdgcn_mfma_f32_16x16x32_bf16(af, bf, acc[m], 0, 0, 0);
    }
  }
#pragma unroll
  for (int m = 0; m < 4; m++)
#pragma unroll
    for (int r = 0; r < 4; r++) {
      int oc = m * 16 + quad * 4 + r;
      ebuf[(size_t)(b * 64 + oc) * NHW + hw0 + l16] = acc[m][r] + bias[oc];
    }
}

// ---------------- 11. LayerNorm ch-major in -> hnT px-major bf16 (r9 verbatim)
__global__ __launch_bounds__(256) void k_ln(const float* e, fp g, fp bt, us* hnT) {
  int idx = blockIdx.x * 256 + threadIdx.x;
  if (idx >= NB * NHW) return;
  int hw = idx & 4095, b = idx >> 12;
  const float* p = e + (size_t)b * 64 * NHW + hw;
  float v[64];
  float s = 0.f;
#pragma unroll
  for (int c = 0; c < 64; c++) { v[c] = p[(size_t)c * NHW]; s += v[c]; }
  float mu = s * (1.f / 64.f);
  float q = 0.f;
#pragma unroll
  for (int c = 0; c < 64; c++) { float d = v[c] - mu; q += d * d; }
  float rstd = rsqrtf(q * (1.f / 64.f) + 1e-5f);
  us* o = hnT + (size_t)idx * 64;
#pragma unroll
  for (int j = 0; j < 8; j++) {
    short8 pk;
#pragma unroll
    for (int t = 0; t < 8; t++) {
      int c = j * 8 + t;
      pk[t] = (short)f2bu((v[c] - mu) * rstd * g[c] + bt[c]);
    }
    *(short8*)(o + j * 8) = pk;
  }
}

// ---------------- 12. mlp1 GEMM (r9 verbatim): M=256, K=64, GELU -> h1 ch-major bf16
__global__ __launch_bounds__(256) void k_mlp1_g(const us* hnT, const us* wm1, fp bias, __hip_bfloat16* h1) {
  int wave = threadIdx.x >> 6, lane = threadIdx.x & 63;
  int quad = lane >> 4, l16 = lane & 15;
  int pxg0 = blockIdx.x * 64 + wave * 16;
  int b = pxg0 >> 12, hw0 = pxg0 & 4095;
  floatx4 acc[16];
#pragma unroll
  for (int m = 0; m < 16; m++) acc[m] = (floatx4){0.f, 0.f, 0.f, 0.f};
  const us* hrow = hnT + (size_t)(pxg0 + l16) * 64 + quad * 8;
#pragma unroll
  for (int k0 = 0; k0 < 64; k0 += 32) {
    short8 bf = ld8(hrow + k0);
#pragma unroll
    for (int m = 0; m < 16; m++) {
      short8 af = ld8(wm1 + (size_t)(m * 16 + l16) * 64 + k0 + quad * 8);
      acc[m] = __builtin_amdgcn_mfma_f32_16x16x32_bf16(af, bf, acc[m], 0, 0, 0);
    }
  }
#pragma unroll
  for (int m = 0; m < 16; m++)
#pragma unroll
    for (int r = 0; r < 4; r++) {
      int oc = m * 16 + quad * 4 + r;
      size_t oidx = (size_t)(b * 256 + oc) * NHW + hw0 + l16;
      h1[oidx] = f2b(gelu_ex(acc[m][r] + bias[oc]));
    }
}

// ---------------- 13. depthwise 3x3 (r8 verbatim, ch-major)
__global__ __launch_bounds__(256) void k_dw(const __hip_bfloat16* h1, fp w, fp bias, __hip_bfloat16* h2) {
  int idx = blockIdx.x * 256 + threadIdx.x;
  if (idx >= NB * 256 * NHW) return;
  int hw = idx & 4095, t = idx >> 12;
  int c = t & 255, b = t >> 8;
  int y = hw >> 6, x = hw & 63;
  const __hip_bfloat16* p = h1 + ((size_t)(b * 256 + c)) * NHW;
  float acc = bias[c];
#pragma unroll
  for (int ky = 0; ky < 3; ky++) {
#pragma unroll
    for (int kx = 0; kx < 3; kx++) {
      int yy = y + ky - 1, xx = x + kx - 1;
      if (yy >= 0 && yy < 64 && xx >= 0 && xx < 64)
        acc += b2f(p[yy * 64 + xx]) * w[c * 9 + ky * 3 + kx];
    }
  }
  h2[idx] = f2b(gelu_ex(acc));
}

// ---------------- 14. mlp2 1x1 (r8 verbatim)
__global__ __launch_bounds__(256) void k_mlp2(const __hip_bfloat16* h2, fp w, fp bias, const float* e, float* tb_) {
  int idx = blockIdx.x * 256 + threadIdx.x;
  if (idx >= NB * 64 * NHW) return;
  int hw = idx & 4095, t = idx >> 12;
  int o = t & 63, b = t >> 6;
  const __hip_bfloat16* p = h2 + (size_t)b * 256 * NHW + hw;
  const float* wr = w + o * 256;
  float acc = bias[o];
#pragma unroll 8
  for (int c = 0; c < 256; c++) acc += b2f(p[(size_t)c * NHW]) * wr[c];
  tb_[idx] = acc + e[idx];
}

// ---------------- 15. up 1x1 (r8 verbatim)
__global__ __launch_bounds__(256) void k_up(const float* tb_, fp w, fp bias, float* out) {
  int idx = blockIdx.x * 256 + threadIdx.x;
  if (idx >= NB * 256 * NHW) return;
  int hw = idx & 4095, t = idx >> 12;
  int o = t & 255, b = t >> 8;
  const float* p = tb_ + (size_t)b * 64 * NHW + hw;
  const float* wr = w + o * 64;
  float acc = bias[o];
#pragma unroll 8
  for (int c = 0; c < 64; c++) acc += p[(size_t)c * NHW] * wr[c];
  out[idx] = acc;
}

extern "C" void kernel_launch(void* const* d_in, const int* in_sizes, int n_in,
                              void* d_out, int out_size, void* d_ws, size_t ws_size,
                              hipStream_t stream) {
  fp x = (fp)d_in[0], skip = (fp)d_in[1], qkv_w = (fp)d_in[2], qkv_b = (fp)d_in[3],
     proj_w = (fp)d_in[4], proj_b = (fp)d_in[5], edge_w = (fp)d_in[6], thick_w = (fp)d_in[7],
     thick_b = (fp)d_in[8], off_w = (fp)d_in[9], off_b = (fp)d_in[10], deform_w = (fp)d_in[11],
     deform_b = (fp)d_in[12], ln_g = (fp)d_in[13], ln_b = (fp)d_in[14], mlp1_w = (fp)d_in[15],
     mlp1_b = (fp)d_in[16], dw_w = (fp)d_in[17], dw_b = (fp)d_in[18], mlp2_w = (fp)d_in[19],
     mlp2_b = (fp)d_in[20], down_w = (fp)d_in[21], down_b = (fp)d_in[22], up_w = (fp)d_in[23],
     up_b = (fp)d_in[24];

  float* ws = (float*)d_ws;
  // ---- r9's workspace layout (31.25 MB proven); wc grown, ml moved within gap ----
  float* su    = ws + 0;              // f32 [0, 1048576)
  us* qkvb  = (us*)(ws + 1048576);    // bf16 [1048576, 1835008)
  us* avb   = (us*)(ws + 1835008);    // bf16 524,288 elems [1835008, 2097152)
  us* wc    = (us*)(ws + 2097152);    // bf16 45,056 elems  [2097152, 2119680)
  float* ml = ws + 2119680;           // f32 65,536         [2119680, 2185216)
  us* x2T   = (us*)(ws + 3145728);    // bf16 px-major [b*N][256]: [3145728, 5242880)
  float* edge  = ws + 5242880;        // f32 [5242880, 6291456)
  float* offb  = ws + 6291456;        // f32 [6291456, 6586368)
  float* sm    = ws + 6586368;        // f32 (dead after k_edge)
  float* thick = ws + 6602752;        // f32 (dead after k_off)
  us* dbufT = (us*)(ws + 6619136);    // bf16 px-major [b*N][64]: [6619136, 7143424)
  float* ebuf  = ws + 7143424;        // f32 [7143424, 8192000)
  // aliases of dead/late regions:
  us* xT   = x2T;                     // xT live #3..#7; proj_g updates in-place at #7
  us* wq   = dbufT;                   // wq live #0..#4; dbufT written #12 — disjoint
  us* wbf  = (us*)sm;                 // deform weights, written after k_off
  float* Opart = ebuf;                // attn partials; dead before k_down_g writes ebuf
  us* hnT  = qkvb;                    // qkvb dead after k_attn
  __hip_bfloat16* h1 = (__hip_bfloat16*)x2T;   // x2T dead after k_down_g
  __hip_bfloat16* h2 = (__hip_bfloat16*)ws;    // [0, 2097152) slots all dead by k_dw
  float* tbuf  = edge;                // edge dead after k_deform

  dim3 blk(256);
  k_wq<<<96, blk, 0, stream>>>(qkv_w, wq);
  k_wcast<<<176, blk, 0, stream>>>(proj_w, mlp1_w, down_w, wc);
  k_upsample<<<(NB * 64 * NHW) / 256, blk, 0, stream>>>(skip, su);
  k_xpose<<<1024, blk, 0, stream>>>(x, xT);
  k_qkv_g<<<(NB * NHW) / 64, blk, 0, stream>>>(xT, wq, qkv_b, qkvb);
  k_attn<<<(NB * NHW) / 32, blk, 0, stream>>>(qkvb, Opart, ml);
  k_merge<<<(NB * NHW * 32) / 256, blk, 0, stream>>>(Opart, ml, avb);
  k_proj_g<<<(NB * NHW) / 64, blk, 0, stream>>>(avb, xT, wc, proj_b, x2T);
  k_meanthick<<<(NB * NHW) / 256, blk, 0, stream>>>(su, thick_w, thick_b, sm, thick);
  k_edge<<<(NB * 64 * NHW) / 256, blk, 0, stream>>>(sm, edge_w, edge);
  k_off<<<(NB * 18 * NHW) / 256, blk, 0, stream>>>(edge, off_w, off_b, thick, offb);
  k_wprep<<<144, blk, 0, stream>>>(deform_w, wbf);
  k_deform<<<NB * 64, blk, 0, stream>>>(su, offb, wbf, deform_b, edge, dbufT);
  k_down_g<<<(NB * NHW) / 64, blk, 0, stream>>>(x2T, dbufT, wc + 24576, down_b, ebuf);
  k_ln<<<(NB * NHW) / 256, blk, 0, stream>>>(ebuf, ln_g, ln_b, hnT);
  k_mlp1_g<<<(NB * NHW) / 64, blk, 0, stream>>>(hnT, wc + 8192, mlp1_b, h1);
  k_dw<<<(NB * 256 * NHW) / 256, blk, 0, stream>>>(h1, dw_w, dw_b, h2);
  k_mlp2<<<(NB * 64 * NHW) / 256, blk, 0, stream>>>(h2, mlp2_w, mlp2_b, ebuf, tbuf);
  k_up<<<(NB * 256 * NHW) / 256, blk, 0, stream>>>(tbuf, up_w, up_b, (float*)d_out);
}

// Round 11
// 413.101 us; speedup vs baseline: 4.7555x; 1.1580x over previous
//
#include <hip/hip_runtime.h>
#include <hip/hip_bf16.h>
#include <math.h>

#define NB 4
#define NHW 4096

typedef const float* fp;
typedef unsigned short us;
typedef __attribute__((ext_vector_type(8))) short short8;
typedef __attribute__((ext_vector_type(4))) float floatx4;

__device__ __forceinline__ float b2f(__hip_bfloat16 v) { return __bfloat162float(v); }
__device__ __forceinline__ __hip_bfloat16 f2b(float v) { return __float2bfloat16(v); }
__device__ __forceinline__ us f2bu(float f) {
  __hip_bfloat16 h = __float2bfloat16(f);
  return *reinterpret_cast<us*>(&h);
}
__device__ __forceinline__ float bu2f(us u) {
  __hip_bfloat16 h = *reinterpret_cast<__hip_bfloat16*>(&u);
  return __bfloat162float(h);
}
__device__ __forceinline__ float gelu_ex(float x) { return 0.5f * x * (1.0f + erff(x * 0.70710678118654752f)); }
__device__ __forceinline__ short8 ld8(const us* p) { return *(const short8*)p; }

// ---------------- 0a. cast qkv weights f32 [96][256] -> bf16
__global__ __launch_bounds__(256) void k_wq(fp qw, us* wq) {
  int i = blockIdx.x * 256 + threadIdx.x;
  if (i >= 96 * 256) return;
  wq[i] = f2bu(qw[i]);
}

// ---------------- 0b. cast proj/mlp1/down/mlp2/up weights -> bf16 (offsets in shorts)
// proj [256][32] @0, mlp1 [256][64] @8192, down [64][320] @24576, mlp2 [64][256] @45056, up [256][64] @61440
__global__ __launch_bounds__(256) void k_wcast(fp pw, fp m1w, fp dnw, fp m2w, fp uw, us* wc) {
  int i = blockIdx.x * 256 + threadIdx.x;
  if (i >= 77824) return;
  float v;
  if (i < 8192) v = pw[i];
  else if (i < 24576) v = m1w[i - 8192];
  else if (i < 45056) v = dnw[i - 24576];
  else if (i < 61440) v = m2w[i - 45056];
  else v = uw[i - 61440];
  wc[i] = f2bu(v);
}

// ---------------- 0c. deform weights: dw[oc][c][tap] -> wbf[tap][oc][c] bf16 (r8 verbatim)
__global__ __launch_bounds__(256) void k_wprep(fp dw, us* wbf) {
  int idx = blockIdx.x * 256 + threadIdx.x;
  if (idx >= 9 * 64 * 64) return;
  int c = idx & 63, oc = (idx >> 6) & 63, k = idx >> 12;
  wbf[idx] = f2bu(dw[(oc * 64 + c) * 9 + k]);
}

// ---------------- 1. bilinear upsample -> su f32 (r8 verbatim)
__global__ __launch_bounds__(256) void k_upsample(fp skip, float* su) {
  int idx = blockIdx.x * 256 + threadIdx.x;
  if (idx >= NB * 64 * NHW) return;
  int hw = idx & 4095, bc = idx >> 12;
  int y = hw >> 6, x = hw & 63;
  float fy = 0.5f * y - 0.25f, fx = 0.5f * x - 0.25f;
  float y0f = floorf(fy), x0f = floorf(fx);
  float wy = fy - y0f, wx = fx - x0f;
  int y0 = (int)y0f, x0 = (int)x0f;
  int y0c = min(31, max(0, y0)), y1c = min(31, max(0, y0 + 1));
  int x0c = min(31, max(0, x0)), x1c = min(31, max(0, x0 + 1));
  const float* p = skip + (size_t)bc * 1024;
  float v00 = p[y0c * 32 + x0c], v01 = p[y0c * 32 + x1c];
  float v10 = p[y1c * 32 + x0c], v11 = p[y1c * 32 + x1c];
  su[idx] = (1.f - wy) * ((1.f - wx) * v00 + wx * v01) + wy * ((1.f - wx) * v10 + wx * v11);
}

// ---------------- 2. transpose x f32 -> xT bf16 [b*4096][256] (r8 verbatim)
__global__ __launch_bounds__(256) void k_xpose(fp x, us* xT) {
  __shared__ float tile[64][65];
  int bid = blockIdx.x;
  int pt = bid & 63, ct = (bid >> 6) & 3, b = bid >> 8;
  int px0 = pt * 64, c0 = ct * 64;
  int tx = threadIdx.x & 63, ty = threadIdx.x >> 6;
  const float* src = x + ((size_t)(b * 256 + c0)) * NHW + px0;
#pragma unroll
  for (int i = 0; i < 16; i++) {
    int r = i * 4 + ty;
    tile[r][tx] = src[(size_t)r * NHW + tx];
  }
  __syncthreads();
  int cseg = threadIdx.x & 7, p0 = threadIdx.x >> 3;
#pragma unroll
  for (int h = 0; h < 2; h++) {
    int p = p0 + h * 32;
    short8 v;
#pragma unroll
    for (int j = 0; j < 8; j++) v[j] = (short)f2bu(tile[cseg * 8 + j][p]);
    *(short8*)&xT[((size_t)(b * NHW) + px0 + p) * 256 + c0 + cseg * 8] = v;
  }
}

// ---------------- 3. qkv GEMM -> bf16 [b][96][N] ch-major (r8 verbatim)
__global__ __launch_bounds__(256) void k_qkv_g(const us* xT, const us* wq, fp bias, us* qkvb) {
  int wave = threadIdx.x >> 6, lane = threadIdx.x & 63;
  int quad = lane >> 4, l16 = lane & 15;
  int pxg0 = blockIdx.x * 64 + wave * 16;
  int b = pxg0 >> 12, hw0 = pxg0 & 4095;
  floatx4 acc[6];
#pragma unroll
  for (int m = 0; m < 6; m++) acc[m] = (floatx4){0.f, 0.f, 0.f, 0.f};
  const us* xrow = xT + (size_t)(pxg0 + l16) * 256 + quad * 8;
#pragma unroll
  for (int k0 = 0; k0 < 256; k0 += 32) {
    short8 bf = ld8(xrow + k0);
#pragma unroll
    for (int m = 0; m < 6; m++) {
      short8 af = ld8(wq + (size_t)(m * 16 + l16) * 256 + k0 + quad * 8);
      acc[m] = __builtin_amdgcn_mfma_f32_16x16x32_bf16(af, bf, acc[m], 0, 0, 0);
    }
  }
#pragma unroll
  for (int m = 0; m < 6; m++)
#pragma unroll
    for (int r = 0; r < 4; r++) {
      int oc = m * 16 + quad * 4 + r;
      float v = acc[m][r] + bias[oc];
      if (oc < 32) v *= 0.17677669529663688f;
      qkvb[(size_t)(b * 96 + oc) * NHW + hw0 + l16] = f2bu(v);
    }
}

// ---------------- 4. MFMA flash attention, SPLIT-K (r9 verbatim)
__global__ __launch_bounds__(256) void k_attn(const us* qkvb, float* Opart, float* ml) {
  __shared__ __align__(16) us kt[128 * 40];
  __shared__ __align__(16) us vt[32 * 136];
  __shared__ __align__(16) us pt[4][16 * 136];
  int tid = threadIdx.x;
  int wave = tid >> 6, lane = tid & 63;
  int quad = lane >> 4, l16 = lane & 15;
  int blk = blockIdx.x;
  int kh = blk & 1;
  int rest = blk >> 1;
  int b = rest >> 6;
  int qbase = (rest & 63) * 64 + wave * 16;
  const us* qp = qkvb + (size_t)b * 96 * NHW;
  const us* kp = qp + 32 * NHW;
  const us* vp = qp + 64 * NHW;

  short8 aq;
#pragma unroll
  for (int j = 0; j < 8; j++)
    aq[j] = (short)qp[(size_t)(quad * 8 + j) * NHW + qbase + l16];

  float m_r[4], l_r[4];
  floatx4 o0 = {0.f, 0.f, 0.f, 0.f}, o1 = {0.f, 0.f, 0.f, 0.f};
#pragma unroll
  for (int r = 0; r < 4; r++) { m_r[r] = -1e30f; l_r[r] = 0.f; }

  int sc = tid & 31, sg = tid >> 5;
  int vc = tid >> 3, vs = tid & 7;

  int kb0 = kh * 2048;
  for (int kb = kb0; kb < kb0 + 2048; kb += 128) {
    __syncthreads();
    {
      const us* src = kp + (size_t)sc * NHW + kb + sg * 16;
#pragma unroll
      for (int j = 0; j < 16; j++) kt[(sg * 16 + j) * 40 + sc] = src[j];
      const us* sv = vp + (size_t)vc * NHW + kb + vs * 16;
      uint4 d0 = *(const uint4*)sv;
      uint4 d1 = *(const uint4*)(sv + 8);
      *(uint4*)&vt[vc * 136 + vs * 16] = d0;
      *(uint4*)&vt[vc * 136 + vs * 16 + 8] = d1;
    }
    __syncthreads();

    floatx4 s[8];
#pragma unroll
    for (int t = 0; t < 8; t++) {
      short8 bk = *(const short8*)&kt[(t * 16 + l16) * 40 + quad * 8];
      floatx4 z = {0.f, 0.f, 0.f, 0.f};
      s[t] = __builtin_amdgcn_mfma_f32_16x16x32_bf16(aq, bk, z, 0, 0, 0);
    }

    float mnew[4], alpha[4];
#pragma unroll
    for (int r = 0; r < 4; r++) {
      float mx = s[0][r];
#pragma unroll
      for (int t = 1; t < 8; t++) mx = fmaxf(mx, s[t][r]);
#pragma unroll
      for (int msk = 1; msk < 16; msk <<= 1) mx = fmaxf(mx, __shfl_xor(mx, msk, 64));
      mnew[r] = fmaxf(m_r[r], mx);
      alpha[r] = __expf(m_r[r] - mnew[r]);
      m_r[r] = mnew[r];
    }
    float rs[4] = {0.f, 0.f, 0.f, 0.f};
#pragma unroll
    for (int t = 0; t < 8; t++) {
#pragma unroll
      for (int r = 0; r < 4; r++) {
        float p = __expf(s[t][r] - mnew[r]);
        rs[r] += p;
        pt[wave][(quad * 4 + r) * 136 + t * 16 + l16] = f2bu(p);
      }
    }
#pragma unroll
    for (int r = 0; r < 4; r++) {
      float sm = rs[r];
#pragma unroll
      for (int msk = 1; msk < 16; msk <<= 1) sm += __shfl_xor(sm, msk, 64);
      l_r[r] = l_r[r] * alpha[r] + sm;
      o0[r] *= alpha[r];
      o1[r] *= alpha[r];
    }

#pragma unroll
    for (int t = 0; t < 4; t++) {
      short8 ap  = *(const short8*)&pt[wave][l16 * 136 + t * 32 + quad * 8];
      short8 bv0 = *(const short8*)&vt[l16 * 136 + t * 32 + quad * 8];
      short8 bv1 = *(const short8*)&vt[(l16 + 16) * 136 + t * 32 + quad * 8];
      o0 = __builtin_amdgcn_mfma_f32_16x16x32_bf16(ap, bv0, o0, 0, 0, 0);
      o1 = __builtin_amdgcn_mfma_f32_16x16x32_bf16(ap, bv1, o1, 0, 0, 0);
    }
  }

#pragma unroll
  for (int r = 0; r < 4; r++) {
    int q = qbase + quad * 4 + r;
    int qg = b * NHW + q;
    float* dst = Opart + ((size_t)(kh * NB * NHW) + qg) * 32;
    dst[l16] = o0[r];
    dst[l16 + 16] = o1[r];
    if (l16 == 0) {
      ml[kh * (NB * NHW) + qg] = m_r[r];
      ml[2 * NB * NHW + kh * (NB * NHW) + qg] = l_r[r];
    }
  }
}

// ---------------- 4b. merge split-K partials -> avb px-major bf16 (r9 verbatim)
__global__ __launch_bounds__(256) void k_merge(const float* Opart, const float* ml, us* avb) {
  int idx = blockIdx.x * 256 + threadIdx.x;
  int ch = idx & 31, qg = idx >> 5;
  float m0 = ml[qg], m1 = ml[NB * NHW + qg];
  float l0 = ml[2 * NB * NHW + qg], l1 = ml[3 * NB * NHW + qg];
  float m = fmaxf(m0, m1);
  float a0 = __expf(m0 - m), a1 = __expf(m1 - m);
  float l = l0 * a0 + l1 * a1;
  float v0 = Opart[(size_t)qg * 32 + ch];
  float v1 = Opart[((size_t)(NB * NHW) + qg) * 32 + ch];
  avb[idx] = f2bu((v0 * a0 + v1 * a1) / l);
}

// ---------------- 5. proj GEMM act-first -> x2T px-major bf16, residual xT in-place (r10 verbatim)
__global__ __launch_bounds__(256) void k_proj_g(const us* avb, const us* xT, const us* wpj, fp bias, us* x2T) {
  int wave = threadIdx.x >> 6, lane = threadIdx.x & 63;
  int quad = lane >> 4, l16 = lane & 15;
  int pxg0 = blockIdx.x * 64 + wave * 16;
  short8 act = ld8(avb + (size_t)(pxg0 + l16) * 32 + quad * 8);
  floatx4 acc[16];
#pragma unroll
  for (int n = 0; n < 16; n++) {
    short8 wf = ld8(wpj + (size_t)(n * 16 + l16) * 32 + quad * 8);
    floatx4 z = {0.f, 0.f, 0.f, 0.f};
    acc[n] = __builtin_amdgcn_mfma_f32_16x16x32_bf16(act, wf, z, 0, 0, 0);
  }
#pragma unroll
  for (int n = 0; n < 16; n++)
#pragma unroll
    for (int r = 0; r < 4; r++) {
      int px = pxg0 + quad * 4 + r;
      int oc = n * 16 + l16;
      size_t oidx = (size_t)px * 256 + oc;
      x2T[oidx] = f2bu(acc[n][r] + bias[oc] + bu2f(xT[oidx]));
    }
}

// ---------------- 6. channel mean + thick (r8 verbatim)
__global__ __launch_bounds__(256) void k_meanthick(const float* su, fp tw, fp tb, float* sm, float* thick) {
  int idx = blockIdx.x * 256 + threadIdx.x;
  if (idx >= NB * NHW) return;
  int hw = idx & 4095, b = idx >> 12;
  const float* p = su + (size_t)b * 64 * NHW + hw;
  float s = 0.f, ts = 0.f;
#pragma unroll 8
  for (int c = 0; c < 64; c++) {
    float v = p[(size_t)c * NHW];
    s += v;
    ts += v * tw[c];
  }
  sm[idx] = s * (1.f / 64.f);
  float z = ts + tb[0];
  thick[idx] = 1.f / (1.f + __expf(-z));
}

// ---------------- 7. edge conv 3x3 (r8 verbatim)
__global__ __launch_bounds__(256) void k_edge(const float* sm, fp ew, float* edge) {
  int idx = blockIdx.x * 256 + threadIdx.x;
  if (idx >= NB * 64 * NHW) return;
  int hw = idx & 4095, t = idx >> 12;
  int o = t & 63, b = t >> 6;
  int y = hw >> 6, x = hw & 63;
  const float* s = sm + (size_t)b * NHW;
  float acc = 0.f;
#pragma unroll
  for (int ky = 0; ky < 3; ky++) {
#pragma unroll
    for (int kx = 0; kx < 3; kx++) {
      int yy = y + ky - 1, xx = x + kx - 1;
      if (yy >= 0 && yy < 64 && xx >= 0 && xx < 64)
        acc += s[yy * 64 + xx] * ew[o * 9 + ky * 3 + kx];
    }
  }
  edge[idx] = acc;
}

// ---------------- 8. offset conv 3x3 (r8 verbatim)
__global__ __launch_bounds__(256) void k_off(const float* edge, fp ow, fp ob, const float* thick, float* off) {
  int idx = blockIdx.x * 256 + threadIdx.x;
  if (idx >= NB * 18 * NHW) return;
  int hw = idx & 4095, t = idx >> 12;
  int o = t % 18, b = t / 18;
  int y = hw >> 6, x = hw & 63;
  const float* e = edge + (size_t)b * 64 * NHW;
  float acc = ob[o];
  for (int j = 0; j < 9; j++) {
    int yy = y + j / 3 - 1, xx = x + j % 3 - 1;
    if (yy < 0 || yy > 63 || xx < 0 || xx > 63) continue;
    int p = yy * 64 + xx;
    const float* wr = ow + o * 576 + j;
#pragma unroll 8
    for (int c = 0; c < 64; c++) acc += e[(size_t)c * NHW + p] * wr[c * 9];
  }
  off[idx] = acc * (1.f + 16.f * thick[b * NHW + hw]);
}

// ---------------- 9. MFMA deformable conv (r10 verbatim, px-major out)
__global__ __launch_bounds__(256) void k_deform(const float* su, const float* offb,
                                                const us* wbf, fp db,
                                                const float* edge, us* dbufT) {
  __shared__ __align__(16) us samT[4][16][72];
  int tid = threadIdx.x;
  int wave = tid >> 6, lane = tid & 63;
  int quad = lane >> 4, l16 = lane & 15;
  int b = blockIdx.x >> 6, row = blockIdx.x & 63;
  const float* sub = su + (size_t)b * 64 * NHW;

  int sp = lane & 15, sq = lane >> 4;
  int hw_s = row * 64 + wave * 16 + sp;
  int x_s = wave * 16 + sp;

  floatx4 acc[4];
#pragma unroll
  for (int a = 0; a < 4; a++) acc[a] = (floatx4){0.f, 0.f, 0.f, 0.f};

  for (int k = 0; k < 9; k++) {
    float dy = offb[((size_t)(b * 18 + 2 * k)) * NHW + hw_s];
    float dx = offb[((size_t)(b * 18 + 2 * k + 1)) * NHW + hw_s];
    float py = (float)(row + k / 3 - 1) + dy;
    float pxf = (float)(x_s + k % 3 - 1) + dx;
    float y0f = floorf(py), x0f = floorf(pxf);
    float wy = py - y0f, wx = pxf - x0f;
    int y0 = (int)y0f, x0 = (int)x0f;
    int y1 = y0 + 1, x1 = x0 + 1;
    float vy0 = (y0 >= 0 && y0 < 64) ? 1.f : 0.f;
    float vy1 = (y1 >= 0 && y1 < 64) ? 1.f : 0.f;
    float vx0 = (x0 >= 0 && x0 < 64) ? 1.f : 0.f;
    float vx1 = (x1 >= 0 && x1 < 64) ? 1.f : 0.f;
    float w00 = (1.f - wy) * (1.f - wx) * vy0 * vx0;
    float w01 = (1.f - wy) * wx * vy0 * vx1;
    float w10 = wy * (1.f - wx) * vy1 * vx0;
    float w11 = wy * wx * vy1 * vx1;
    int y0c = min(63, max(0, y0)), y1c = min(63, max(0, y1));
    int x0c = min(63, max(0, x0)), x1c = min(63, max(0, x1));
    int i00 = y0c * 64 + x0c, i01 = y0c * 64 + x1c;
    int i10 = y1c * 64 + x0c, i11 = y1c * 64 + x1c;

#pragma unroll
    for (int i = 0; i < 16; i += 2) {
      int c0 = sq * 16 + i;
      const float* s0 = sub + (size_t)c0 * NHW;
      const float* s1 = s0 + NHW;
      float v0 = w00 * s0[i00] + w01 * s0[i01] + w10 * s0[i10] + w11 * s0[i11];
      float v1 = w00 * s1[i00] + w01 * s1[i01] + w10 * s1[i10] + w11 * s1[i11];
      unsigned int pk = (unsigned int)f2bu(v0) | ((unsigned int)f2bu(v1) << 16);
      *(unsigned int*)&samT[wave][sp][c0] = pk;
    }

#pragma unroll
    for (int s = 0; s < 2; s++) {
      short8 bfrag = *(const short8*)&samT[wave][l16][s * 32 + quad * 8];
#pragma unroll
      for (int a = 0; a < 4; a++) {
        short8 afrag = ld8(wbf + ((size_t)(k * 64 + a * 16 + l16) * 64 + s * 32 + quad * 8));
        acc[a] = __builtin_amdgcn_mfma_f32_16x16x32_bf16(bfrag, afrag, acc[a], 0, 0, 0);
      }
    }
  }

#pragma unroll
  for (int a = 0; a < 4; a++)
#pragma unroll
    for (int r = 0; r < 4; r++) {
      int oc = a * 16 + l16;
      int pxr = row * 64 + wave * 16 + quad * 4 + r;
      float v = acc[a][r] + db[oc] + edge[(size_t)(b * 64 + oc) * NHW + pxr];
      dbufT[((size_t)(b * NHW) + pxr) * 64 + oc] = f2bu(v);
    }
}

// ---------------- 10. down GEMM act-first -> ebufT px-major f32 [b*N][64]
__global__ __launch_bounds__(256) void k_down_g(const us* x2T, const us* dbufT, const us* wd, fp bias, float* ebufT) {
  int wave = threadIdx.x >> 6, lane = threadIdx.x & 63;
  int quad = lane >> 4, l16 = lane & 15;
  int pxg0 = blockIdx.x * 64 + wave * 16;
  floatx4 acc[4];
#pragma unroll
  for (int m = 0; m < 4; m++) acc[m] = (floatx4){0.f, 0.f, 0.f, 0.f};
  const us* xrow = x2T + (size_t)(pxg0 + l16) * 256 + quad * 8;
#pragma unroll
  for (int k0 = 0; k0 < 256; k0 += 32) {
    short8 act = ld8(xrow + k0);
#pragma unroll
    for (int m = 0; m < 4; m++) {
      short8 wf = ld8(wd + (size_t)(m * 16 + l16) * 320 + k0 + quad * 8);
      acc[m] = __builtin_amdgcn_mfma_f32_16x16x32_bf16(act, wf, acc[m], 0, 0, 0);
    }
  }
  const us* drow = dbufT + (size_t)(pxg0 + l16) * 64 + quad * 8;
#pragma unroll
  for (int k0 = 0; k0 < 64; k0 += 32) {
    short8 act = ld8(drow + k0);
#pragma unroll
    for (int m = 0; m < 4; m++) {
      short8 wf = ld8(wd + (size_t)(m * 16 + l16) * 320 + 256 + k0 + quad * 8);
      acc[m] = __builtin_amdgcn_mfma_f32_16x16x32_bf16(act, wf, acc[m], 0, 0, 0);
    }
  }
#pragma unroll
  for (int m = 0; m < 4; m++)
#pragma unroll
    for (int r = 0; r < 4; r++) {
      int px = pxg0 + quad * 4 + r;
      int oc = m * 16 + l16;
      ebufT[(size_t)px * 64 + oc] = acc[m][r] + bias[oc];
    }
}

// ---------------- 11. LayerNorm px-major in -> hnT px-major bf16
__global__ __launch_bounds__(256) void k_ln(const float* eT, fp g, fp bt, us* hnT) {
  int idx = blockIdx.x * 256 + threadIdx.x;
  if (idx >= NB * NHW) return;
  const float* p = eT + (size_t)idx * 64;
  float v[64];
  float s = 0.f;
#pragma unroll
  for (int i = 0; i < 16; i++) {
    float4 t = ((const float4*)p)[i];
    v[i * 4] = t.x; v[i * 4 + 1] = t.y; v[i * 4 + 2] = t.z; v[i * 4 + 3] = t.w;
    s += t.x + t.y + t.z + t.w;
  }
  float mu = s * (1.f / 64.f);
  float q = 0.f;
#pragma unroll
  for (int c = 0; c < 64; c++) { float d = v[c] - mu; q += d * d; }
  float rstd = rsqrtf(q * (1.f / 64.f) + 1e-5f);
  us* o = hnT + (size_t)idx * 64;
#pragma unroll
  for (int j = 0; j < 8; j++) {
    short8 pk;
#pragma unroll
    for (int t = 0; t < 8; t++) {
      int c = j * 8 + t;
      pk[t] = (short)f2bu((v[c] - mu) * rstd * g[c] + bt[c]);
    }
    *(short8*)(o + j * 8) = pk;
  }
}

// ---------------- 12. mlp1 GEMM act-first: K=64, O=256, GELU -> h1T px-major bf16
__global__ __launch_bounds__(256) void k_mlp1_g(const us* hnT, const us* wm1, fp bias, us* h1T) {
  int wave = threadIdx.x >> 6, lane = threadIdx.x & 63;
  int quad = lane >> 4, l16 = lane & 15;
  int pxg0 = blockIdx.x * 64 + wave * 16;
  floatx4 acc[16];
#pragma unroll
  for (int m = 0; m < 16; m++) acc[m] = (floatx4){0.f, 0.f, 0.f, 0.f};
  const us* hrow = hnT + (size_t)(pxg0 + l16) * 64 + quad * 8;
#pragma unroll
  for (int k0 = 0; k0 < 64; k0 += 32) {
    short8 act = ld8(hrow + k0);
#pragma unroll
    for (int m = 0; m < 16; m++) {
      short8 wf = ld8(wm1 + (size_t)(m * 16 + l16) * 64 + k0 + quad * 8);
      acc[m] = __builtin_amdgcn_mfma_f32_16x16x32_bf16(act, wf, acc[m], 0, 0, 0);
    }
  }
#pragma unroll
  for (int m = 0; m < 16; m++)
#pragma unroll
    for (int r = 0; r < 4; r++) {
      int px = pxg0 + quad * 4 + r;
      int oc = m * 16 + l16;
      h1T[(size_t)px * 256 + oc] = f2bu(gelu_ex(acc[m][r] + bias[oc]));
    }
}

// ---------------- 13. depthwise 3x3 + GELU, px-major: thread = (px, 8-ch block)
__global__ __launch_bounds__(256) void k_dw(const us* h1T, fp w, fp bias, us* h2T) {
  int idx = blockIdx.x * 256 + threadIdx.x;   // NB*NHW*32
  int cb = idx & 31, pxg = idx >> 5;
  int b = pxg >> 12, hw = pxg & 4095;
  int y = hw >> 6, x = hw & 63;
  int c0 = cb * 8;
  float acc[8];
#pragma unroll
  for (int j = 0; j < 8; j++) acc[j] = bias[c0 + j];
#pragma unroll
  for (int ky = 0; ky < 3; ky++) {
#pragma unroll
    for (int kx = 0; kx < 3; kx++) {
      int yy = y + ky - 1, xx = x + kx - 1;
      if (yy >= 0 && yy < 64 && xx >= 0 && xx < 64) {
        short8 vv = ld8(h1T + ((size_t)(b * NHW + yy * 64 + xx)) * 256 + c0);
#pragma unroll
        for (int j = 0; j < 8; j++)
          acc[j] += bu2f((us)vv[j]) * w[(c0 + j) * 9 + ky * 3 + kx];
      }
    }
  }
  short8 pk;
#pragma unroll
  for (int j = 0; j < 8; j++) pk[j] = (short)f2bu(gelu_ex(acc[j]));
  *(short8*)(h2T + (size_t)pxg * 256 + c0) = pk;
}

// ---------------- 14. mlp2 GEMM act-first: K=256, O=64, + bias + ebufT residual -> tbufT px-major bf16
__global__ __launch_bounds__(256) void k_mlp2_g(const us* h2T, const us* wm2, fp bias, const float* ebufT, us* tbufT) {
  int wave = threadIdx.x >> 6, lane = threadIdx.x & 63;
  int quad = lane >> 4, l16 = lane & 15;
  int pxg0 = blockIdx.x * 64 + wave * 16;
  floatx4 acc[4];
#pragma unroll
  for (int m = 0; m < 4; m++) acc[m] = (floatx4){0.f, 0.f, 0.f, 0.f};
  const us* hrow = h2T + (size_t)(pxg0 + l16) * 256 + quad * 8;
#pragma unroll
  for (int k0 = 0; k0 < 256; k0 += 32) {
    short8 act = ld8(hrow + k0);
#pragma unroll
    for (int m = 0; m < 4; m++) {
      short8 wf = ld8(wm2 + (size_t)(m * 16 + l16) * 256 + k0 + quad * 8);
      acc[m] = __builtin_amdgcn_mfma_f32_16x16x32_bf16(act, wf, acc[m], 0, 0, 0);
    }
  }
#pragma unroll
  for (int m = 0; m < 4; m++)
#pragma unroll
    for (int r = 0; r < 4; r++) {
      int px = pxg0 + quad * 4 + r;
      int oc = m * 16 + l16;
      size_t oidx = (size_t)px * 64 + oc;
      tbufT[oidx] = f2bu(acc[m][r] + bias[oc] + ebufT[oidx]);
    }
}

// ---------------- 15. up GEMM W-first (mlp1_g r9 pattern): M=256, K=64 -> out ch-major f32
__global__ __launch_bounds__(256) void k_up_g(const us* tbufT, const us* wu, fp bias, float* out) {
  int wave = threadIdx.x >> 6, lane = threadIdx.x & 63;
  int quad = lane >> 4, l16 = lane & 15;
  int pxg0 = blockIdx.x * 64 + wave * 16;
  int b = pxg0 >> 12, hw0 = pxg0 & 4095;
  floatx4 acc[16];
#pragma unroll
  for (int m = 0; m < 16; m++) acc[m] = (floatx4){0.f, 0.f, 0.f, 0.f};
  const us* trow = tbufT + (size_t)(pxg0 + l16) * 64 + quad * 8;
#pragma unroll
  for (int k0 = 0; k0 < 64; k0 += 32) {
    short8 bf = ld8(trow + k0);
#pragma unroll
    for (int m = 0; m < 16; m++) {
      short8 af = ld8(wu + (size_t)(m * 16 + l16) * 64 + k0 + quad * 8);
      acc[m] = __builtin_amdgcn_mfma_f32_16x16x32_bf16(af, bf, acc[m], 0, 0, 0);
    }
  }
#pragma unroll
  for (int m = 0; m < 16; m++)
#pragma unroll
    for (int r = 0; r < 4; r++) {
      int oc = m * 16 + quad * 4 + r;
      out[(size_t)(b * 256 + oc) * NHW + hw0 + l16] = acc[m][r] + bias[oc];
    }
}

extern "C" void kernel_launch(void* const* d_in, const int* in_sizes, int n_in,
                              void* d_out, int out_size, void* d_ws, size_t ws_size,
                              hipStream_t stream) {
  fp x = (fp)d_in[0], skip = (fp)d_in[1], qkv_w = (fp)d_in[2], qkv_b = (fp)d_in[3],
     proj_w = (fp)d_in[4], proj_b = (fp)d_in[5], edge_w = (fp)d_in[6], thick_w = (fp)d_in[7],
     thick_b = (fp)d_in[8], off_w = (fp)d_in[9], off_b = (fp)d_in[10], deform_w = (fp)d_in[11],
     deform_b = (fp)d_in[12], ln_g = (fp)d_in[13], ln_b = (fp)d_in[14], mlp1_w = (fp)d_in[15],
     mlp1_b = (fp)d_in[16], dw_w = (fp)d_in[17], dw_b = (fp)d_in[18], mlp2_w = (fp)d_in[19],
     mlp2_b = (fp)d_in[20], down_w = (fp)d_in[21], down_b = (fp)d_in[22], up_w = (fp)d_in[23],
     up_b = (fp)d_in[24];

  float* ws = (float*)d_ws;
  // ---- r10 layout (31.25 MB proven); wc grown to 77,824 shorts, ml shifted ----
  float* su    = ws + 0;              // f32 [0, 1048576)
  us* qkvb  = (us*)(ws + 1048576);    // bf16 [1048576, 1835008)
  us* avb   = (us*)(ws + 1835008);    // bf16 524,288 elems [1835008, 2097152)
  us* wc    = (us*)(ws + 2097152);    // bf16 77,824 elems  [2097152, 2136064)
  float* ml = ws + 2136064;           // f32 65,536         [2136064, 2201600)
  us* x2T   = (us*)(ws + 3145728);    // bf16 px-major [b*N][256]: [3145728, 5242880)
  float* edge  = ws + 5242880;        // f32 [5242880, 6291456)
  float* offb  = ws + 6291456;        // f32 [6291456, 6586368)
  float* sm    = ws + 6586368;        // f32 (dead after k_edge)
  float* thick = ws + 6602752;        // f32 (dead after k_off)
  us* dbufT = (us*)(ws + 6619136);    // bf16 px-major [b*N][64]: [6619136, 7143424)
  float* ebufT = ws + 7143424;        // f32 px-major [b*N][64]: [7143424, 8192000)
  // aliases of dead/late regions:
  us* xT   = x2T;                     // xT live #3..#7; proj_g updates in-place at #7
  us* wq   = dbufT;                   // wq live #0..#4; dbufT written #12 — disjoint
  us* wbf  = (us*)sm;                 // deform weights, written after k_off
  float* Opart = ebufT;               // attn partials; dead before k_down_g writes ebufT
  us* hnT  = qkvb;                    // qkvb dead after k_attn
  us* h1T  = x2T;                     // x2T dead after k_down_g
  us* h2T  = (us*)ws;                 // [0, 2097152) slots all dead by k_dw
  us* tbufT = (us*)edge;              // edge dead after k_deform; 1,048,576 bf16 fits

  dim3 blk(256);
  k_wq<<<96, blk, 0, stream>>>(qkv_w, wq);
  k_wcast<<<304, blk, 0, stream>>>(proj_w, mlp1_w, down_w, mlp2_w, up_w, wc);
  k_upsample<<<(NB * 64 * NHW) / 256, blk, 0, stream>>>(skip, su);
  k_xpose<<<1024, blk, 0, stream>>>(x, xT);
  k_qkv_g<<<(NB * NHW) / 64, blk, 0, stream>>>(xT, wq, qkv_b, qkvb);
  k_attn<<<(NB * NHW) / 32, blk, 0, stream>>>(qkvb, Opart, ml);
  k_merge<<<(NB * NHW * 32) / 256, blk, 0, stream>>>(Opart, ml, avb);
  k_proj_g<<<(NB * NHW) / 64, blk, 0, stream>>>(avb, xT, wc, proj_b, x2T);
  k_meanthick<<<(NB * NHW) / 256, blk, 0, stream>>>(su, thick_w, thick_b, sm, thick);
  k_edge<<<(NB * 64 * NHW) / 256, blk, 0, stream>>>(sm, edge_w, edge);
  k_off<<<(NB * 18 * NHW) / 256, blk, 0, stream>>>(edge, off_w, off_b, thick, offb);
  k_wprep<<<144, blk, 0, stream>>>(deform_w, wbf);
  k_deform<<<NB * 64, blk, 0, stream>>>(su, offb, wbf, deform_b, edge, dbufT);
  k_down_g<<<(NB * NHW) / 64, blk, 0, stream>>>(x2T, dbufT, wc + 24576, down_b, ebufT);
  k_ln<<<(NB * NHW) / 256, blk, 0, stream>>>(ebufT, ln_g, ln_b, hnT);
  k_mlp1_g<<<(NB * NHW) / 64, blk, 0, stream>>>(hnT, wc + 8192, mlp1_b, h1T);
  k_dw<<<(NB * NHW * 32) / 256, blk, 0, stream>>>(h1T, dw_w, dw_b, h2T);
  k_mlp2_g<<<(NB * NHW) / 64, blk, 0, stream>>>(h2T, wc + 45056, mlp2_b, ebufT, tbufT);
  k_up_g<<<(NB * NHW) / 64, blk, 0, stream>>>(tbufT, wc + 61440, up_b, (float*)d_out);
}

// Round 12
// 355.267 us; speedup vs baseline: 5.5297x; 1.1628x over previous
//
#include <hip/hip_runtime.h>
#include <hip/hip_bf16.h>
#include <math.h>

#define NB 4
#define NHW 4096

typedef const float* fp;
typedef unsigned short us;
typedef __attribute__((ext_vector_type(8))) short short8;
typedef __attribute__((ext_vector_type(4))) float floatx4;

__device__ __forceinline__ float b2f(__hip_bfloat16 v) { return __bfloat162float(v); }
__device__ __forceinline__ __hip_bfloat16 f2b(float v) { return __float2bfloat16(v); }
__device__ __forceinline__ us f2bu(float f) {
  __hip_bfloat16 h = __float2bfloat16(f);
  return *reinterpret_cast<us*>(&h);
}
__device__ __forceinline__ float bu2f(us u) {
  __hip_bfloat16 h = *reinterpret_cast<__hip_bfloat16*>(&u);
  return __bfloat162float(h);
}
__device__ __forceinline__ float gelu_ex(float x) { return 0.5f * x * (1.0f + erff(x * 0.70710678118654752f)); }
__device__ __forceinline__ short8 ld8(const us* p) { return *(const short8*)p; }

// ---------------- 0a. cast qkv weights f32 [96][256] -> bf16
__global__ __launch_bounds__(256) void k_wq(fp qw, us* wq) {
  int i = blockIdx.x * 256 + threadIdx.x;
  if (i >= 96 * 256) return;
  wq[i] = f2bu(qw[i]);
}

// ---------------- 0b. cast proj/mlp1/down/mlp2/up/dw weights -> bf16 (offsets in shorts)
// proj @0, mlp1 @8192, down @24576, mlp2 @45056, up @61440, dwT[tap][ch] @77824; total 80128
__global__ __launch_bounds__(256) void k_wcast(fp pw, fp m1w, fp dnw, fp m2w, fp uw, fp dww, us* wc) {
  int i = blockIdx.x * 256 + threadIdx.x;
  if (i >= 80128) return;
  float v;
  if (i < 8192) v = pw[i];
  else if (i < 24576) v = m1w[i - 8192];
  else if (i < 45056) v = dnw[i - 24576];
  else if (i < 61440) v = m2w[i - 45056];
  else if (i < 77824) v = uw[i - 61440];
  else {
    int i2 = i - 77824;           // dwT[tap][ch]: tap = i2>>8, ch = i2&255
    v = dww[(i2 & 255) * 9 + (i2 >> 8)];
  }
  wc[i] = f2bu(v);
}

// ---------------- 0c. deform weights: dw[oc][c][tap] -> wbf[tap][oc][c] bf16 (r8 verbatim)
__global__ __launch_bounds__(256) void k_wprep(fp dw, us* wbf) {
  int idx = blockIdx.x * 256 + threadIdx.x;
  if (idx >= 9 * 64 * 64) return;
  int c = idx & 63, oc = (idx >> 6) & 63, k = idx >> 12;
  wbf[idx] = f2bu(dw[(oc * 64 + c) * 9 + k]);
}

// ---------------- 1. bilinear upsample -> su f32 (r8 verbatim)
__global__ __launch_bounds__(256) void k_upsample(fp skip, float* su) {
  int idx = blockIdx.x * 256 + threadIdx.x;
  if (idx >= NB * 64 * NHW) return;
  int hw = idx & 4095, bc = idx >> 12;
  int y = hw >> 6, x = hw & 63;
  float fy = 0.5f * y - 0.25f, fx = 0.5f * x - 0.25f;
  float y0f = floorf(fy), x0f = floorf(fx);
  float wy = fy - y0f, wx = fx - x0f;
  int y0 = (int)y0f, x0 = (int)x0f;
  int y0c = min(31, max(0, y0)), y1c = min(31, max(0, y0 + 1));
  int x0c = min(31, max(0, x0)), x1c = min(31, max(0, x0 + 1));
  const float* p = skip + (size_t)bc * 1024;
  float v00 = p[y0c * 32 + x0c], v01 = p[y0c * 32 + x1c];
  float v10 = p[y1c * 32 + x0c], v11 = p[y1c * 32 + x1c];
  su[idx] = (1.f - wy) * ((1.f - wx) * v00 + wx * v01) + wy * ((1.f - wx) * v10 + wx * v11);
}

// ---------------- 2. transpose x f32 -> xT bf16 [b*4096][256] (r8 verbatim)
__global__ __launch_bounds__(256) void k_xpose(fp x, us* xT) {
  __shared__ float tile[64][65];
  int bid = blockIdx.x;
  int pt = bid & 63, ct = (bid >> 6) & 3, b = bid >> 8;
  int px0 = pt * 64, c0 = ct * 64;
  int tx = threadIdx.x & 63, ty = threadIdx.x >> 6;
  const float* src = x + ((size_t)(b * 256 + c0)) * NHW + px0;
#pragma unroll
  for (int i = 0; i < 16; i++) {
    int r = i * 4 + ty;
    tile[r][tx] = src[(size_t)r * NHW + tx];
  }
  __syncthreads();
  int cseg = threadIdx.x & 7, p0 = threadIdx.x >> 3;
#pragma unroll
  for (int h = 0; h < 2; h++) {
    int p = p0 + h * 32;
    short8 v;
#pragma unroll
    for (int j = 0; j < 8; j++) v[j] = (short)f2bu(tile[cseg * 8 + j][p]);
    *(short8*)&xT[((size_t)(b * NHW) + px0 + p) * 256 + c0 + cseg * 8] = v;
  }
}

// ---------------- 3. qkv GEMM -> bf16 [b][96][N] ch-major (r8 verbatim)
__global__ __launch_bounds__(256) void k_qkv_g(const us* xT, const us* wq, fp bias, us* qkvb) {
  int wave = threadIdx.x >> 6, lane = threadIdx.x & 63;
  int quad = lane >> 4, l16 = lane & 15;
  int pxg0 = blockIdx.x * 64 + wave * 16;
  int b = pxg0 >> 12, hw0 = pxg0 & 4095;
  floatx4 acc[6];
#pragma unroll
  for (int m = 0; m < 6; m++) acc[m] = (floatx4){0.f, 0.f, 0.f, 0.f};
  const us* xrow = xT + (size_t)(pxg0 + l16) * 256 + quad * 8;
#pragma unroll
  for (int k0 = 0; k0 < 256; k0 += 32) {
    short8 bf = ld8(xrow + k0);
#pragma unroll
    for (int m = 0; m < 6; m++) {
      short8 af = ld8(wq + (size_t)(m * 16 + l16) * 256 + k0 + quad * 8);
      acc[m] = __builtin_amdgcn_mfma_f32_16x16x32_bf16(af, bf, acc[m], 0, 0, 0);
    }
  }
#pragma unroll
  for (int m = 0; m < 6; m++)
#pragma unroll
    for (int r = 0; r < 4; r++) {
      int oc = m * 16 + quad * 4 + r;
      float v = acc[m][r] + bias[oc];
      if (oc < 32) v *= 0.17677669529663688f;
      qkvb[(size_t)(b * 96 + oc) * NHW + hw0 + l16] = f2bu(v);
    }
}

// ---------------- 4. MFMA flash attention, SPLIT-K (r9 verbatim)
__global__ __launch_bounds__(256) void k_attn(const us* qkvb, float* Opart, float* ml) {
  __shared__ __align__(16) us kt[128 * 40];
  __shared__ __align__(16) us vt[32 * 136];
  __shared__ __align__(16) us pt[4][16 * 136];
  int tid = threadIdx.x;
  int wave = tid >> 6, lane = tid & 63;
  int quad = lane >> 4, l16 = lane & 15;
  int blk = blockIdx.x;
  int kh = blk & 1;
  int rest = blk >> 1;
  int b = rest >> 6;
  int qbase = (rest & 63) * 64 + wave * 16;
  const us* qp = qkvb + (size_t)b * 96 * NHW;
  const us* kp = qp + 32 * NHW;
  const us* vp = qp + 64 * NHW;

  short8 aq;
#pragma unroll
  for (int j = 0; j < 8; j++)
    aq[j] = (short)qp[(size_t)(quad * 8 + j) * NHW + qbase + l16];

  float m_r[4], l_r[4];
  floatx4 o0 = {0.f, 0.f, 0.f, 0.f}, o1 = {0.f, 0.f, 0.f, 0.f};
#pragma unroll
  for (int r = 0; r < 4; r++) { m_r[r] = -1e30f; l_r[r] = 0.f; }

  int sc = tid & 31, sg = tid >> 5;
  int vc = tid >> 3, vs = tid & 7;

  int kb0 = kh * 2048;
  for (int kb = kb0; kb < kb0 + 2048; kb += 128) {
    __syncthreads();
    {
      const us* src = kp + (size_t)sc * NHW + kb + sg * 16;
#pragma unroll
      for (int j = 0; j < 16; j++) kt[(sg * 16 + j) * 40 + sc] = src[j];
      const us* sv = vp + (size_t)vc * NHW + kb + vs * 16;
      uint4 d0 = *(const uint4*)sv;
      uint4 d1 = *(const uint4*)(sv + 8);
      *(uint4*)&vt[vc * 136 + vs * 16] = d0;
      *(uint4*)&vt[vc * 136 + vs * 16 + 8] = d1;
    }
    __syncthreads();

    floatx4 s[8];
#pragma unroll
    for (int t = 0; t < 8; t++) {
      short8 bk = *(const short8*)&kt[(t * 16 + l16) * 40 + quad * 8];
      floatx4 z = {0.f, 0.f, 0.f, 0.f};
      s[t] = __builtin_amdgcn_mfma_f32_16x16x32_bf16(aq, bk, z, 0, 0, 0);
    }

    float mnew[4], alpha[4];
#pragma unroll
    for (int r = 0; r < 4; r++) {
      float mx = s[0][r];
#pragma unroll
      for (int t = 1; t < 8; t++) mx = fmaxf(mx, s[t][r]);
#pragma unroll
      for (int msk = 1; msk < 16; msk <<= 1) mx = fmaxf(mx, __shfl_xor(mx, msk, 64));
      mnew[r] = fmaxf(m_r[r], mx);
      alpha[r] = __expf(m_r[r] - mnew[r]);
      m_r[r] = mnew[r];
    }
    float rs[4] = {0.f, 0.f, 0.f, 0.f};
#pragma unroll
    for (int t = 0; t < 8; t++) {
#pragma unroll
      for (int r = 0; r < 4; r++) {
        float p = __expf(s[t][r] - mnew[r]);
        rs[r] += p;
        pt[wave][(quad * 4 + r) * 136 + t * 16 + l16] = f2bu(p);
      }
    }
#pragma unroll
    for (int r = 0; r < 4; r++) {
      float sm = rs[r];
#pragma unroll
      for (int msk = 1; msk < 16; msk <<= 1) sm += __shfl_xor(sm, msk, 64);
      l_r[r] = l_r[r] * alpha[r] + sm;
      o0[r] *= alpha[r];
      o1[r] *= alpha[r];
    }

#pragma unroll
    for (int t = 0; t < 4; t++) {
      short8 ap  = *(const short8*)&pt[wave][l16 * 136 + t * 32 + quad * 8];
      short8 bv0 = *(const short8*)&vt[l16 * 136 + t * 32 + quad * 8];
      short8 bv1 = *(const short8*)&vt[(l16 + 16) * 136 + t * 32 + quad * 8];
      o0 = __builtin_amdgcn_mfma_f32_16x16x32_bf16(ap, bv0, o0, 0, 0, 0);
      o1 = __builtin_amdgcn_mfma_f32_16x16x32_bf16(ap, bv1, o1, 0, 0, 0);
    }
  }

#pragma unroll
  for (int r = 0; r < 4; r++) {
    int q = qbase + quad * 4 + r;
    int qg = b * NHW + q;
    float* dst = Opart + ((size_t)(kh * NB * NHW) + qg) * 32;
    dst[l16] = o0[r];
    dst[l16 + 16] = o1[r];
    if (l16 == 0) {
      ml[kh * (NB * NHW) + qg] = m_r[r];
      ml[2 * NB * NHW + kh * (NB * NHW) + qg] = l_r[r];
    }
  }
}

// ---------------- 4b. merge split-K partials -> avb px-major bf16 (r9 verbatim)
__global__ __launch_bounds__(256) void k_merge(const float* Opart, const float* ml, us* avb) {
  int idx = blockIdx.x * 256 + threadIdx.x;
  int ch = idx & 31, qg = idx >> 5;
  float m0 = ml[qg], m1 = ml[NB * NHW + qg];
  float l0 = ml[2 * NB * NHW + qg], l1 = ml[3 * NB * NHW + qg];
  float m = fmaxf(m0, m1);
  float a0 = __expf(m0 - m), a1 = __expf(m1 - m);
  float l = l0 * a0 + l1 * a1;
  float v0 = Opart[(size_t)qg * 32 + ch];
  float v1 = Opart[((size_t)(NB * NHW) + qg) * 32 + ch];
  avb[idx] = f2bu((v0 * a0 + v1 * a1) / l);
}

// ---------------- 5. proj GEMM act-first -> x2T px-major bf16, residual xT in-place (r10 verbatim)
__global__ __launch_bounds__(256) void k_proj_g(const us* avb, const us* xT, const us* wpj, fp bias, us* x2T) {
  int wave = threadIdx.x >> 6, lane = threadIdx.x & 63;
  int quad = lane >> 4, l16 = lane & 15;
  int pxg0 = blockIdx.x * 64 + wave * 16;
  short8 act = ld8(avb + (size_t)(pxg0 + l16) * 32 + quad * 8);
  floatx4 acc[16];
#pragma unroll
  for (int n = 0; n < 16; n++) {
    short8 wf = ld8(wpj + (size_t)(n * 16 + l16) * 32 + quad * 8);
    floatx4 z = {0.f, 0.f, 0.f, 0.f};
    acc[n] = __builtin_amdgcn_mfma_f32_16x16x32_bf16(act, wf, z, 0, 0, 0);
  }
#pragma unroll
  for (int n = 0; n < 16; n++)
#pragma unroll
    for (int r = 0; r < 4; r++) {
      int px = pxg0 + quad * 4 + r;
      int oc = n * 16 + l16;
      size_t oidx = (size_t)px * 256 + oc;
      x2T[oidx] = f2bu(acc[n][r] + bias[oc] + bu2f(xT[oidx]));
    }
}

// ---------------- 6. channel mean + thick (r8 verbatim)
__global__ __launch_bounds__(256) void k_meanthick(const float* su, fp tw, fp tb, float* sm, float* thick) {
  int idx = blockIdx.x * 256 + threadIdx.x;
  if (idx >= NB * NHW) return;
  int hw = idx & 4095, b = idx >> 12;
  const float* p = su + (size_t)b * 64 * NHW + hw;
  float s = 0.f, ts = 0.f;
#pragma unroll 8
  for (int c = 0; c < 64; c++) {
    float v = p[(size_t)c * NHW];
    s += v;
    ts += v * tw[c];
  }
  sm[idx] = s * (1.f / 64.f);
  float z = ts + tb[0];
  thick[idx] = 1.f / (1.f + __expf(-z));
}

// ---------------- 7. edge conv 3x3 (r8 verbatim)
__global__ __launch_bounds__(256) void k_edge(const float* sm, fp ew, float* edge) {
  int idx = blockIdx.x * 256 + threadIdx.x;
  if (idx >= NB * 64 * NHW) return;
  int hw = idx & 4095, t = idx >> 12;
  int o = t & 63, b = t >> 6;
  int y = hw >> 6, x = hw & 63;
  const float* s = sm + (size_t)b * NHW;
  float acc = 0.f;
#pragma unroll
  for (int ky = 0; ky < 3; ky++) {
#pragma unroll
    for (int kx = 0; kx < 3; kx++) {
      int yy = y + ky - 1, xx = x + kx - 1;
      if (yy >= 0 && yy < 64 && xx >= 0 && xx < 64)
        acc += s[yy * 64 + xx] * ew[o * 9 + ky * 3 + kx];
    }
  }
  edge[idx] = acc;
}

// ---------------- 8. offset conv 3x3 (r8 verbatim)
__global__ __launch_bounds__(256) void k_off(const float* edge, fp ow, fp ob, const float* thick, float* off) {
  int idx = blockIdx.x * 256 + threadIdx.x;
  if (idx >= NB * 18 * NHW) return;
  int hw = idx & 4095, t = idx >> 12;
  int o = t % 18, b = t / 18;
  int y = hw >> 6, x = hw & 63;
  const float* e = edge + (size_t)b * 64 * NHW;
  float acc = ob[o];
  for (int j = 0; j < 9; j++) {
    int yy = y + j / 3 - 1, xx = x + j % 3 - 1;
    if (yy < 0 || yy > 63 || xx < 0 || xx > 63) continue;
    int p = yy * 64 + xx;
    const float* wr = ow + o * 576 + j;
#pragma unroll 8
    for (int c = 0; c < 64; c++) acc += e[(size_t)c * NHW + p] * wr[c * 9];
  }
  off[idx] = acc * (1.f + 16.f * thick[b * NHW + hw]);
}

// ---------------- 9. MFMA deformable conv (r10 verbatim, px-major out)
__global__ __launch_bounds__(256) void k_deform(const float* su, const float* offb,
                                                const us* wbf, fp db,
                                                const float* edge, us* dbufT) {
  __shared__ __align__(16) us samT[4][16][72];
  int tid = threadIdx.x;
  int wave = tid >> 6, lane = tid & 63;
  int quad = lane >> 4, l16 = lane & 15;
  int b = blockIdx.x >> 6, row = blockIdx.x & 63;
  const float* sub = su + (size_t)b * 64 * NHW;

  int sp = lane & 15, sq = lane >> 4;
  int hw_s = row * 64 + wave * 16 + sp;
  int x_s = wave * 16 + sp;

  floatx4 acc[4];
#pragma unroll
  for (int a = 0; a < 4; a++) acc[a] = (floatx4){0.f, 0.f, 0.f, 0.f};

  for (int k = 0; k < 9; k++) {
    float dy = offb[((size_t)(b * 18 + 2 * k)) * NHW + hw_s];
    float dx = offb[((size_t)(b * 18 + 2 * k + 1)) * NHW + hw_s];
    float py = (float)(row + k / 3 - 1) + dy;
    float pxf = (float)(x_s + k % 3 - 1) + dx;
    float y0f = floorf(py), x0f = floorf(pxf);
    float wy = py - y0f, wx = pxf - x0f;
    int y0 = (int)y0f, x0 = (int)x0f;
    int y1 = y0 + 1, x1 = x0 + 1;
    float vy0 = (y0 >= 0 && y0 < 64) ? 1.f : 0.f;
    float vy1 = (y1 >= 0 && y1 < 64) ? 1.f : 0.f;
    float vx0 = (x0 >= 0 && x0 < 64) ? 1.f : 0.f;
    float vx1 = (x1 >= 0 && x1 < 64) ? 1.f : 0.f;
    float w00 = (1.f - wy) * (1.f - wx) * vy0 * vx0;
    float w01 = (1.f - wy) * wx * vy0 * vx1;
    float w10 = wy * (1.f - wx) * vy1 * vx0;
    float w11 = wy * wx * vy1 * vx1;
    int y0c = min(63, max(0, y0)), y1c = min(63, max(0, y1));
    int x0c = min(63, max(0, x0)), x1c = min(63, max(0, x1));
    int i00 = y0c * 64 + x0c, i01 = y0c * 64 + x1c;
    int i10 = y1c * 64 + x0c, i11 = y1c * 64 + x1c;

#pragma unroll
    for (int i = 0; i < 16; i += 2) {
      int c0 = sq * 16 + i;
      const float* s0 = sub + (size_t)c0 * NHW;
      const float* s1 = s0 + NHW;
      float v0 = w00 * s0[i00] + w01 * s0[i01] + w10 * s0[i10] + w11 * s0[i11];
      float v1 = w00 * s1[i00] + w01 * s1[i01] + w10 * s1[i10] + w11 * s1[i11];
      unsigned int pk = (unsigned int)f2bu(v0) | ((unsigned int)f2bu(v1) << 16);
      *(unsigned int*)&samT[wave][sp][c0] = pk;
    }

#pragma unroll
    for (int s = 0; s < 2; s++) {
      short8 bfrag = *(const short8*)&samT[wave][l16][s * 32 + quad * 8];
#pragma unroll
      for (int a = 0; a < 4; a++) {
        short8 afrag = ld8(wbf + ((size_t)(k * 64 + a * 16 + l16) * 64 + s * 32 + quad * 8));
        acc[a] = __builtin_amdgcn_mfma_f32_16x16x32_bf16(bfrag, afrag, acc[a], 0, 0, 0);
      }
    }
  }

#pragma unroll
  for (int a = 0; a < 4; a++)
#pragma unroll
    for (int r = 0; r < 4; r++) {
      int oc = a * 16 + l16;
      int pxr = row * 64 + wave * 16 + quad * 4 + r;
      float v = acc[a][r] + db[oc] + edge[(size_t)(b * 64 + oc) * NHW + pxr];
      dbufT[((size_t)(b * NHW) + pxr) * 64 + oc] = f2bu(v);
    }
}

// ---------------- 10. down GEMM act-first -> ebufT px-major f32 (r11 verbatim)
__global__ __launch_bounds__(256) void k_down_g(const us* x2T, const us* dbufT, const us* wd, fp bias, float* ebufT) {
  int wave = threadIdx.x >> 6, lane = threadIdx.x & 63;
  int quad = lane >> 4, l16 = lane & 15;
  int pxg0 = blockIdx.x * 64 + wave * 16;
  floatx4 acc[4];
#pragma unroll
  for (int m = 0; m < 4; m++) acc[m] = (floatx4){0.f, 0.f, 0.f, 0.f};
  const us* xrow = x2T + (size_t)(pxg0 + l16) * 256 + quad * 8;
#pragma unroll
  for (int k0 = 0; k0 < 256; k0 += 32) {
    short8 act = ld8(xrow + k0);
#pragma unroll
    for (int m = 0; m < 4; m++) {
      short8 wf = ld8(wd + (size_t)(m * 16 + l16) * 320 + k0 + quad * 8);
      acc[m] = __builtin_amdgcn_mfma_f32_16x16x32_bf16(act, wf, acc[m], 0, 0, 0);
    }
  }
  const us* drow = dbufT + (size_t)(pxg0 + l16) * 64 + quad * 8;
#pragma unroll
  for (int k0 = 0; k0 < 64; k0 += 32) {
    short8 act = ld8(drow + k0);
#pragma unroll
    for (int m = 0; m < 4; m++) {
      short8 wf = ld8(wd + (size_t)(m * 16 + l16) * 320 + 256 + k0 + quad * 8);
      acc[m] = __builtin_amdgcn_mfma_f32_16x16x32_bf16(act, wf, acc[m], 0, 0, 0);
    }
  }
#pragma unroll
  for (int m = 0; m < 4; m++)
#pragma unroll
    for (int r = 0; r < 4; r++) {
      int px = pxg0 + quad * 4 + r;
      int oc = m * 16 + l16;
      ebufT[(size_t)px * 64 + oc] = acc[m][r] + bias[oc];
    }
}

// ---------------- 11. LayerNorm px-major (r11 verbatim)
__global__ __launch_bounds__(256) void k_ln(const float* eT, fp g, fp bt, us* hnT) {
  int idx = blockIdx.x * 256 + threadIdx.x;
  if (idx >= NB * NHW) return;
  const float* p = eT + (size_t)idx * 64;
  float v[64];
  float s = 0.f;
#pragma unroll
  for (int i = 0; i < 16; i++) {
    float4 t = ((const float4*)p)[i];
    v[i * 4] = t.x; v[i * 4 + 1] = t.y; v[i * 4 + 2] = t.z; v[i * 4 + 3] = t.w;
    s += t.x + t.y + t.z + t.w;
  }
  float mu = s * (1.f / 64.f);
  float q = 0.f;
#pragma unroll
  for (int c = 0; c < 64; c++) { float d = v[c] - mu; q += d * d; }
  float rstd = rsqrtf(q * (1.f / 64.f) + 1e-5f);
  us* o = hnT + (size_t)idx * 64;
#pragma unroll
  for (int j = 0; j < 8; j++) {
    short8 pk;
#pragma unroll
    for (int t = 0; t < 8; t++) {
      int c = j * 8 + t;
      pk[t] = (short)f2bu((v[c] - mu) * rstd * g[c] + bt[c]);
    }
    *(short8*)(o + j * 8) = pk;
  }
}

// ---------------- 12. mlp1 GEMM act-first (r11 verbatim)
__global__ __launch_bounds__(256) void k_mlp1_g(const us* hnT, const us* wm1, fp bias, us* h1T) {
  int wave = threadIdx.x >> 6, lane = threadIdx.x & 63;
  int quad = lane >> 4, l16 = lane & 15;
  int pxg0 = blockIdx.x * 64 + wave * 16;
  floatx4 acc[16];
#pragma unroll
  for (int m = 0; m < 16; m++) acc[m] = (floatx4){0.f, 0.f, 0.f, 0.f};
  const us* hrow = hnT + (size_t)(pxg0 + l16) * 64 + quad * 8;
#pragma unroll
  for (int k0 = 0; k0 < 64; k0 += 32) {
    short8 act = ld8(hrow + k0);
#pragma unroll
    for (int m = 0; m < 16; m++) {
      short8 wf = ld8(wm1 + (size_t)(m * 16 + l16) * 64 + k0 + quad * 8);
      acc[m] = __builtin_amdgcn_mfma_f32_16x16x32_bf16(act, wf, acc[m], 0, 0, 0);
    }
  }
#pragma unroll
  for (int m = 0; m < 16; m++)
#pragma unroll
    for (int r = 0; r < 4; r++) {
      int px = pxg0 + quad * 4 + r;
      int oc = m * 16 + l16;
      h1T[(size_t)px * 256 + oc] = f2bu(gelu_ex(acc[m][r] + bias[oc]));
    }
}

// ---------------- 13. depthwise 3x3 + GELU, px-major; weights via wdwT[tap][ch] bf16 ld8
__global__ __launch_bounds__(256) void k_dw(const us* h1T, const us* wdwT, fp bias, us* h2T) {
  int idx = blockIdx.x * 256 + threadIdx.x;   // NB*NHW*32
  int cb = idx & 31, pxg = idx >> 5;
  int b = pxg >> 12, hw = pxg & 4095;
  int y = hw >> 6, x = hw & 63;
  int c0 = cb * 8;
  float4 b0 = *(const float4*)(bias + c0);
  float4 b1 = *(const float4*)(bias + c0 + 4);
  float acc[8] = {b0.x, b0.y, b0.z, b0.w, b1.x, b1.y, b1.z, b1.w};
#pragma unroll
  for (int ky = 0; ky < 3; ky++) {
#pragma unroll
    for (int kx = 0; kx < 3; kx++) {
      int tap = ky * 3 + kx;
      short8 wv = ld8(wdwT + tap * 256 + c0);   // coalesced 16B weight load
      int yy = y + ky - 1, xx = x + kx - 1;
      if (yy >= 0 && yy < 64 && xx >= 0 && xx < 64) {
        short8 vv = ld8(h1T + ((size_t)(b * NHW + yy * 64 + xx)) * 256 + c0);
#pragma unroll
        for (int j = 0; j < 8; j++)
          acc[j] += bu2f((us)vv[j]) * bu2f((us)wv[j]);
      }
    }
  }
  short8 pk;
#pragma unroll
  for (int j = 0; j < 8; j++) pk[j] = (short)f2bu(gelu_ex(acc[j]));
  *(short8*)(h2T + (size_t)pxg * 256 + c0) = pk;
}

// ---------------- 14. mlp2 GEMM act-first (r11 verbatim)
__global__ __launch_bounds__(256) void k_mlp2_g(const us* h2T, const us* wm2, fp bias, const float* ebufT, us* tbufT) {
  int wave = threadIdx.x >> 6, lane = threadIdx.x & 63;
  int quad = lane >> 4, l16 = lane & 15;
  int pxg0 = blockIdx.x * 64 + wave * 16;
  floatx4 acc[4];
#pragma unroll
  for (int m = 0; m < 4; m++) acc[m] = (floatx4){0.f, 0.f, 0.f, 0.f};
  const us* hrow = h2T + (size_t)(pxg0 + l16) * 256 + quad * 8;
#pragma unroll
  for (int k0 = 0; k0 < 256; k0 += 32) {
    short8 act = ld8(hrow + k0);
#pragma unroll
    for (int m = 0; m < 4; m++) {
      short8 wf = ld8(wm2 + (size_t)(m * 16 + l16) * 256 + k0 + quad * 8);
      acc[m] = __builtin_amdgcn_mfma_f32_16x16x32_bf16(act, wf, acc[m], 0, 0, 0);
    }
  }
#pragma unroll
  for (int m = 0; m < 4; m++)
#pragma unroll
    for (int r = 0; r < 4; r++) {
      int px = pxg0 + quad * 4 + r;
      int oc = m * 16 + l16;
      size_t oidx = (size_t)px * 64 + oc;
      tbufT[oidx] = f2bu(acc[m][r] + bias[oc] + ebufT[oidx]);
    }
}

// ---------------- 15. up GEMM W-first (r11 verbatim)
__global__ __launch_bounds__(256) void k_up_g(const us* tbufT, const us* wu, fp bias, float* out) {
  int wave = threadIdx.x >> 6, lane = threadIdx.x & 63;
  int quad = lane >> 4, l16 = lane & 15;
  int pxg0 = blockIdx.x * 64 + wave * 16;
  int b = pxg0 >> 12, hw0 = pxg0 & 4095;
  floatx4 acc[16];
#pragma unroll
  for (int m = 0; m < 16; m++) acc[m] = (floatx4){0.f, 0.f, 0.f, 0.f};
  const us* trow = tbufT + (size_t)(pxg0 + l16) * 64 + quad * 8;
#pragma unroll
  for (int k0 = 0; k0 < 64; k0 += 32) {
    short8 bf = ld8(trow + k0);
#pragma unroll
    for (int m = 0; m < 16; m++) {
      short8 af = ld8(wu + (size_t)(m * 16 + l16) * 64 + k0 + quad * 8);
      acc[m] = __builtin_amdgcn_mfma_f32_16x16x32_bf16(af, bf, acc[m], 0, 0, 0);
    }
  }
#pragma unroll
  for (int m = 0; m < 16; m++)
#pragma unroll
    for (int r = 0; r < 4; r++) {
      int oc = m * 16 + quad * 4 + r;
      out[(size_t)(b * 256 + oc) * NHW + hw0 + l16] = acc[m][r] + bias[oc];
    }
}

extern "C" void kernel_launch(void* const* d_in, const int* in_sizes, int n_in,
                              void* d_out, int out_size, void* d_ws, size_t ws_size,
                              hipStream_t stream) {
  fp x = (fp)d_in[0], skip = (fp)d_in[1], qkv_w = (fp)d_in[2], qkv_b = (fp)d_in[3],
     proj_w = (fp)d_in[4], proj_b = (fp)d_in[5], edge_w = (fp)d_in[6], thick_w = (fp)d_in[7],
     thick_b = (fp)d_in[8], off_w = (fp)d_in[9], off_b = (fp)d_in[10], deform_w = (fp)d_in[11],
     deform_b = (fp)d_in[12], ln_g = (fp)d_in[13], ln_b = (fp)d_in[14], mlp1_w = (fp)d_in[15],
     mlp1_b = (fp)d_in[16], dw_w = (fp)d_in[17], dw_b = (fp)d_in[18], mlp2_w = (fp)d_in[19],
     mlp2_b = (fp)d_in[20], down_w = (fp)d_in[21], down_b = (fp)d_in[22], up_w = (fp)d_in[23],
     up_b = (fp)d_in[24];

  float* ws = (float*)d_ws;
  // ---- r11 layout (31.25 MB proven); wc grown to 80,128 shorts, ml shifted past it ----
  float* su    = ws + 0;              // f32 [0, 1048576)
  us* qkvb  = (us*)(ws + 1048576);    // bf16 [1048576, 1835008)
  us* avb   = (us*)(ws + 1835008);    // bf16 524,288 elems [1835008, 2097152)
  us* wc    = (us*)(ws + 2097152);    // bf16 80,128 elems  [2097152, 2137216)
  float* ml = ws + 2137216;           // f32 65,536         [2137216, 2202752)
  us* x2T   = (us*)(ws + 3145728);    // bf16 px-major [b*N][256]: [3145728, 5242880)
  float* edge  = ws + 5242880;        // f32 [5242880, 6291456)
  float* offb  = ws + 6291456;        // f32 [6291456, 6586368)
  float* sm    = ws + 6586368;        // f32 (dead after k_edge)
  float* thick = ws + 6602752;        // f32 (dead after k_off)
  us* dbufT = (us*)(ws + 6619136);    // bf16 px-major [b*N][64]: [6619136, 7143424)
  float* ebufT = ws + 7143424;        // f32 px-major [b*N][64]: [7143424, 8192000)
  // aliases of dead/late regions:
  us* xT   = x2T;                     // xT live #3..#7; proj_g updates in-place at #7
  us* wq   = dbufT;                   // wq live #0..#4; dbufT written #12 — disjoint
  us* wbf  = (us*)sm;                 // deform weights, written after k_off
  float* Opart = ebufT;               // attn partials; dead before k_down_g writes ebufT
  us* hnT  = qkvb;                    // qkvb dead after k_attn
  us* h1T  = x2T;                     // x2T dead after k_down_g
  us* h2T  = (us*)ws;                 // [0, 2097152) slots all dead by k_dw
  us* tbufT = (us*)edge;              // edge dead after k_deform; 1,048,576 bf16 fits

  dim3 blk(256);
  k_wq<<<96, blk, 0, stream>>>(qkv_w, wq);
  k_wcast<<<313, blk, 0, stream>>>(proj_w, mlp1_w, down_w, mlp2_w, up_w, dw_w, wc);
  k_upsample<<<(NB * 64 * NHW) / 256, blk, 0, stream>>>(skip, su);
  k_xpose<<<1024, blk, 0, stream>>>(x, xT);
  k_qkv_g<<<(NB * NHW) / 64, blk, 0, stream>>>(xT, wq, qkv_b, qkvb);
  k_attn<<<(NB * NHW) / 32, blk, 0, stream>>>(qkvb, Opart, ml);
  k_merge<<<(NB * NHW * 32) / 256, blk, 0, stream>>>(Opart, ml, avb);
  k_proj_g<<<(NB * NHW) / 64, blk, 0, stream>>>(avb, xT, wc, proj_b, x2T);
  k_meanthick<<<(NB * NHW) / 256, blk, 0, stream>>>(su, thick_w, thick_b, sm, thick);
  k_edge<<<(NB * 64 * NHW) / 256, blk, 0, stream>>>(sm, edge_w, edge);
  k_off<<<(NB * 18 * NHW) / 256, blk, 0, stream>>>(edge, off_w, off_b, thick, offb);
  k_wprep<<<144, blk, 0, stream>>>(deform_w, wbf);
  k_deform<<<NB * 64, blk, 0, stream>>>(su, offb, wbf, deform_b, edge, dbufT);
  k_down_g<<<(NB * NHW) / 64, blk, 0, stream>>>(x2T, dbufT, wc + 24576, down_b, ebufT);
  k_ln<<<(NB * NHW) / 256, blk, 0, stream>>>(ebufT, ln_g, ln_b, hnT);
  k_mlp1_g<<<(NB * NHW) / 64, blk, 0, stream>>>(hnT, wc + 8192, mlp1_b, h1T);
  k_dw<<<(NB * NHW * 32) / 256, blk, 0, stream>>>(h1T, wc + 77824, dw_b, h2T);
  k_mlp2_g<<<(NB * NHW) / 64, blk, 0, stream>>>(h2T, wc + 45056, mlp2_b, ebufT, tbufT);
  k_up_g<<<(NB * NHW) / 64, blk, 0, stream>>>(tbufT, wc + 61440, up_b, (float*)d_out);
}

// Round 13
// 307.157 us; speedup vs baseline: 6.3958x; 1.1566x over previous
//
#include <hip/hip_runtime.h>
#include <hip/hip_bf16.h>
#include <math.h>

#define NB 4
#define NHW 4096
#define NBN (NB * NHW)

typedef const float* fp;
typedef unsigned short us;
typedef __attribute__((ext_vector_type(8))) short short8;
typedef __attribute__((ext_vector_type(4))) float floatx4;

__device__ __forceinline__ float b2f(__hip_bfloat16 v) { return __bfloat162float(v); }
__device__ __forceinline__ __hip_bfloat16 f2b(float v) { return __float2bfloat16(v); }
__device__ __forceinline__ us f2bu(float f) {
  __hip_bfloat16 h = __float2bfloat16(f);
  return *reinterpret_cast<us*>(&h);
}
__device__ __forceinline__ float bu2f(us u) {
  __hip_bfloat16 h = *reinterpret_cast<__hip_bfloat16*>(&u);
  return __bfloat162float(h);
}
__device__ __forceinline__ float gelu_ex(float x) { return 0.5f * x * (1.0f + erff(x * 0.70710678118654752f)); }
__device__ __forceinline__ short8 ld8(const us* p) { return *(const short8*)p; }

// ---------------- 0a. cast qkv weights f32 [96][256] -> bf16
__global__ __launch_bounds__(256) void k_wq(fp qw, us* wq) {
  int i = blockIdx.x * 256 + threadIdx.x;
  if (i >= 96 * 256) return;
  wq[i] = f2bu(qw[i]);
}

// ---------------- 0b. cast weights -> bf16 (offsets in shorts)
// proj @0, mlp1 @8192, down @24576, mlp2 @45056, up @61440, dwT[tap][ch] @77824,
// ewT[tap][oc] @80128, woff[32 pad][9*64] @80704; total 99136
__global__ __launch_bounds__(256) void k_wcast(fp pw, fp m1w, fp dnw, fp m2w, fp uw, fp dww,
                                               fp ew, fp ow, us* wc) {
  int i = blockIdx.x * 256 + threadIdx.x;
  if (i >= 99136) return;
  float v;
  if (i < 8192) v = pw[i];
  else if (i < 24576) v = m1w[i - 8192];
  else if (i < 45056) v = dnw[i - 24576];
  else if (i < 61440) v = m2w[i - 45056];
  else if (i < 77824) v = uw[i - 61440];
  else if (i < 80128) {
    int i2 = i - 77824;           // dwT: tap = i2>>8, ch = i2&255
    v = dww[(i2 & 255) * 9 + (i2 >> 8)];
  } else if (i < 80704) {
    int i2 = i - 80128;           // ewT: tap = i2>>6, oc = i2&63
    v = ew[(i2 & 63) * 9 + (i2 >> 6)];
  } else {
    int i2 = i - 80704;           // woff[oc][tap*64+c], oc padded to 32
    int oc = i2 / 576, rem = i2 % 576;
    int tap = rem >> 6, c = rem & 63;
    v = (oc < 18) ? ow[(oc * 64 + c) * 9 + tap] : 0.f;
  }
  wc[i] = f2bu(v);
}

// ---------------- 0c. deform weights: dw[oc][c][tap] -> wbf[tap][oc][c] bf16 (r8 verbatim)
__global__ __launch_bounds__(256) void k_wprep(fp dw, us* wbf) {
  int idx = blockIdx.x * 256 + threadIdx.x;
  if (idx >= 9 * 64 * 64) return;
  int c = idx & 63, oc = (idx >> 6) & 63, k = idx >> 12;
  wbf[idx] = f2bu(dw[(oc * 64 + c) * 9 + k]);
}

// ---------------- 1. bilinear upsample -> su f32 (r8 verbatim)
__global__ __launch_bounds__(256) void k_upsample(fp skip, float* su) {
  int idx = blockIdx.x * 256 + threadIdx.x;
  if (idx >= NB * 64 * NHW) return;
  int hw = idx & 4095, bc = idx >> 12;
  int y = hw >> 6, x = hw & 63;
  float fy = 0.5f * y - 0.25f, fx = 0.5f * x - 0.25f;
  float y0f = floorf(fy), x0f = floorf(fx);
  float wy = fy - y0f, wx = fx - x0f;
  int y0 = (int)y0f, x0 = (int)x0f;
  int y0c = min(31, max(0, y0)), y1c = min(31, max(0, y0 + 1));
  int x0c = min(31, max(0, x0)), x1c = min(31, max(0, x0 + 1));
  const float* p = skip + (size_t)bc * 1024;
  float v00 = p[y0c * 32 + x0c], v01 = p[y0c * 32 + x1c];
  float v10 = p[y1c * 32 + x0c], v11 = p[y1c * 32 + x1c];
  su[idx] = (1.f - wy) * ((1.f - wx) * v00 + wx * v01) + wy * ((1.f - wx) * v10 + wx * v11);
}

// ---------------- 2. transpose x f32 -> xT bf16 [b*4096][256] (r8 verbatim)
__global__ __launch_bounds__(256) void k_xpose(fp x, us* xT) {
  __shared__ float tile[64][65];
  int bid = blockIdx.x;
  int pt = bid & 63, ct = (bid >> 6) & 3, b = bid >> 8;
  int px0 = pt * 64, c0 = ct * 64;
  int tx = threadIdx.x & 63, ty = threadIdx.x >> 6;
  const float* src = x + ((size_t)(b * 256 + c0)) * NHW + px0;
#pragma unroll
  for (int i = 0; i < 16; i++) {
    int r = i * 4 + ty;
    tile[r][tx] = src[(size_t)r * NHW + tx];
  }
  __syncthreads();
  int cseg = threadIdx.x & 7, p0 = threadIdx.x >> 3;
#pragma unroll
  for (int h = 0; h < 2; h++) {
    int p = p0 + h * 32;
    short8 v;
#pragma unroll
    for (int j = 0; j < 8; j++) v[j] = (short)f2bu(tile[cseg * 8 + j][p]);
    *(short8*)&xT[((size_t)(b * NHW) + px0 + p) * 256 + c0 + cseg * 8] = v;
  }
}

// ---------------- 3. qkv GEMM -> bf16 [b][96][N] ch-major (r8 verbatim)
__global__ __launch_bounds__(256) void k_qkv_g(const us* xT, const us* wq, fp bias, us* qkvb) {
  int wave = threadIdx.x >> 6, lane = threadIdx.x & 63;
  int quad = lane >> 4, l16 = lane & 15;
  int pxg0 = blockIdx.x * 64 + wave * 16;
  int b = pxg0 >> 12, hw0 = pxg0 & 4095;
  floatx4 acc[6];
#pragma unroll
  for (int m = 0; m < 6; m++) acc[m] = (floatx4){0.f, 0.f, 0.f, 0.f};
  const us* xrow = xT + (size_t)(pxg0 + l16) * 256 + quad * 8;
#pragma unroll
  for (int k0 = 0; k0 < 256; k0 += 32) {
    short8 bf = ld8(xrow + k0);
#pragma unroll
    for (int m = 0; m < 6; m++) {
      short8 af = ld8(wq + (size_t)(m * 16 + l16) * 256 + k0 + quad * 8);
      acc[m] = __builtin_amdgcn_mfma_f32_16x16x32_bf16(af, bf, acc[m], 0, 0, 0);
    }
  }
#pragma unroll
  for (int m = 0; m < 6; m++)
#pragma unroll
    for (int r = 0; r < 4; r++) {
      int oc = m * 16 + quad * 4 + r;
      float v = acc[m][r] + bias[oc];
      if (oc < 32) v *= 0.17677669529663688f;
      qkvb[(size_t)(b * 96 + oc) * NHW + hw0 + l16] = f2bu(v);
    }
}

// ---------------- 4. MFMA flash attention, SPLIT-K x4.  Partials in bf16.
__global__ __launch_bounds__(256) void k_attn(const us* qkvb, us* Opart, float* ml) {
  __shared__ __align__(16) us kt[128 * 40];
  __shared__ __align__(16) us vt[32 * 136];
  __shared__ __align__(16) us pt[4][16 * 136];
  int tid = threadIdx.x;
  int wave = tid >> 6, lane = tid & 63;
  int quad = lane >> 4, l16 = lane & 15;
  int blk = blockIdx.x;
  int kh = blk & 3;
  int rest = blk >> 2;
  int b = rest >> 6;
  int qbase = (rest & 63) * 64 + wave * 16;
  const us* qp = qkvb + (size_t)b * 96 * NHW;
  const us* kp = qp + 32 * NHW;
  const us* vp = qp + 64 * NHW;

  short8 aq;
#pragma unroll
  for (int j = 0; j < 8; j++)
    aq[j] = (short)qp[(size_t)(quad * 8 + j) * NHW + qbase + l16];

  float m_r[4], l_r[4];
  floatx4 o0 = {0.f, 0.f, 0.f, 0.f}, o1 = {0.f, 0.f, 0.f, 0.f};
#pragma unroll
  for (int r = 0; r < 4; r++) { m_r[r] = -1e30f; l_r[r] = 0.f; }

  int sc = tid & 31, sg = tid >> 5;
  int vc = tid >> 3, vs = tid & 7;

  int kb0 = kh * 1024;
  for (int kb = kb0; kb < kb0 + 1024; kb += 128) {
    __syncthreads();
    {
      const us* src = kp + (size_t)sc * NHW + kb + sg * 16;
#pragma unroll
      for (int j = 0; j < 16; j++) kt[(sg * 16 + j) * 40 + sc] = src[j];
      const us* sv = vp + (size_t)vc * NHW + kb + vs * 16;
      uint4 d0 = *(const uint4*)sv;
      uint4 d1 = *(const uint4*)(sv + 8);
      *(uint4*)&vt[vc * 136 + vs * 16] = d0;
      *(uint4*)&vt[vc * 136 + vs * 16 + 8] = d1;
    }
    __syncthreads();

    floatx4 s[8];
#pragma unroll
    for (int t = 0; t < 8; t++) {
      short8 bk = *(const short8*)&kt[(t * 16 + l16) * 40 + quad * 8];
      floatx4 z = {0.f, 0.f, 0.f, 0.f};
      s[t] = __builtin_amdgcn_mfma_f32_16x16x32_bf16(aq, bk, z, 0, 0, 0);
    }

    float mnew[4], alpha[4];
#pragma unroll
    for (int r = 0; r < 4; r++) {
      float mx = s[0][r];
#pragma unroll
      for (int t = 1; t < 8; t++) mx = fmaxf(mx, s[t][r]);
#pragma unroll
      for (int msk = 1; msk < 16; msk <<= 1) mx = fmaxf(mx, __shfl_xor(mx, msk, 64));
      mnew[r] = fmaxf(m_r[r], mx);
      alpha[r] = __expf(m_r[r] - mnew[r]);
      m_r[r] = mnew[r];
    }
    float rs[4] = {0.f, 0.f, 0.f, 0.f};
#pragma unroll
    for (int t = 0; t < 8; t++) {
#pragma unroll
      for (int r = 0; r < 4; r++) {
        float p = __expf(s[t][r] - mnew[r]);
        rs[r] += p;
        pt[wave][(quad * 4 + r) * 136 + t * 16 + l16] = f2bu(p);
      }
    }
#pragma unroll
    for (int r = 0; r < 4; r++) {
      float sm = rs[r];
#pragma unroll
      for (int msk = 1; msk < 16; msk <<= 1) sm += __shfl_xor(sm, msk, 64);
      l_r[r] = l_r[r] * alpha[r] + sm;
      o0[r] *= alpha[r];
      o1[r] *= alpha[r];
    }

#pragma unroll
    for (int t = 0; t < 4; t++) {
      short8 ap  = *(const short8*)&pt[wave][l16 * 136 + t * 32 + quad * 8];
      short8 bv0 = *(const short8*)&vt[l16 * 136 + t * 32 + quad * 8];
      short8 bv1 = *(const short8*)&vt[(l16 + 16) * 136 + t * 32 + quad * 8];
      o0 = __builtin_amdgcn_mfma_f32_16x16x32_bf16(ap, bv0, o0, 0, 0, 0);
      o1 = __builtin_amdgcn_mfma_f32_16x16x32_bf16(ap, bv1, o1, 0, 0, 0);
    }
  }

#pragma unroll
  for (int r = 0; r < 4; r++) {
    int q = qbase + quad * 4 + r;
    int qg = b * NHW + q;
    us* dst = Opart + ((size_t)(kh * NBN) + qg) * 32;
    dst[l16] = f2bu(o0[r]);
    dst[l16 + 16] = f2bu(o1[r]);
    if (l16 == 0) {
      ml[kh * NBN + qg] = m_r[r];
      ml[4 * NBN + kh * NBN + qg] = l_r[r];
    }
  }
}

// ---------------- 4b. merge 4 split-K partials -> avb px-major bf16
__global__ __launch_bounds__(256) void k_merge(const us* Opart, const float* ml, us* avb) {
  int idx = blockIdx.x * 256 + threadIdx.x;
  int ch = idx & 31, qg = idx >> 5;
  float mk[4];
  float m = -1e30f;
#pragma unroll
  for (int kh = 0; kh < 4; kh++) { mk[kh] = ml[kh * NBN + qg]; m = fmaxf(m, mk[kh]); }
  float l = 0.f, v = 0.f;
#pragma unroll
  for (int kh = 0; kh < 4; kh++) {
    float a = __expf(mk[kh] - m);
    l += ml[4 * NBN + kh * NBN + qg] * a;
    v += bu2f(Opart[((size_t)(kh * NBN) + qg) * 32 + ch]) * a;
  }
  avb[idx] = f2bu(v / l);
}

// ---------------- 5. proj GEMM act-first (r10 verbatim)
__global__ __launch_bounds__(256) void k_proj_g(const us* avb, const us* xT, const us* wpj, fp bias, us* x2T) {
  int wave = threadIdx.x >> 6, lane = threadIdx.x & 63;
  int quad = lane >> 4, l16 = lane & 15;
  int pxg0 = blockIdx.x * 64 + wave * 16;
  short8 act = ld8(avb + (size_t)(pxg0 + l16) * 32 + quad * 8);
  floatx4 acc[16];
#pragma unroll
  for (int n = 0; n < 16; n++) {
    short8 wf = ld8(wpj + (size_t)(n * 16 + l16) * 32 + quad * 8);
    floatx4 z = {0.f, 0.f, 0.f, 0.f};
    acc[n] = __builtin_amdgcn_mfma_f32_16x16x32_bf16(act, wf, z, 0, 0, 0);
  }
#pragma unroll
  for (int n = 0; n < 16; n++)
#pragma unroll
    for (int r = 0; r < 4; r++) {
      int px = pxg0 + quad * 4 + r;
      int oc = n * 16 + l16;
      size_t oidx = (size_t)px * 256 + oc;
      x2T[oidx] = f2bu(acc[n][r] + bias[oc] + bu2f(xT[oidx]));
    }
}

// ---------------- 6. channel mean + thick (r8 verbatim)
__global__ __launch_bounds__(256) void k_meanthick(const float* su, fp tw, fp tb, float* sm, float* thick) {
  int idx = blockIdx.x * 256 + threadIdx.x;
  if (idx >= NB * NHW) return;
  int hw = idx & 4095, b = idx >> 12;
  const float* p = su + (size_t)b * 64 * NHW + hw;
  float s = 0.f, ts = 0.f;
#pragma unroll 8
  for (int c = 0; c < 64; c++) {
    float v = p[(size_t)c * NHW];
    s += v;
    ts += v * tw[c];
  }
  sm[idx] = s * (1.f / 64.f);
  float z = ts + tb[0];
  thick[idx] = 1.f / (1.f + __expf(-z));
}

// ---------------- 7. edge conv 3x3 px-major: thread=(px, 8-oc block) -> edgeT bf16 [b*N][64]
__global__ __launch_bounds__(256) void k_edge_px(const float* sm, const us* ewT, us* edgeT) {
  int idx = blockIdx.x * 256 + threadIdx.x;   // NB*NHW*8
  int cb = idx & 7, pxg = idx >> 3;
  int b = pxg >> 12, hw = pxg & 4095;
  int y = hw >> 6, x = hw & 63;
  int c0 = cb * 8;
  float acc[8] = {0.f, 0.f, 0.f, 0.f, 0.f, 0.f, 0.f, 0.f};
#pragma unroll
  for (int ky = 0; ky < 3; ky++) {
#pragma unroll
    for (int kx = 0; kx < 3; kx++) {
      int yy = y + ky - 1, xx = x + kx - 1;
      if (yy >= 0 && yy < 64 && xx >= 0 && xx < 64) {
        float sv = sm[b * NHW + yy * 64 + xx];
        short8 wv = ld8(ewT + (ky * 3 + kx) * 64 + c0);
#pragma unroll
        for (int j = 0; j < 8; j++) acc[j] += sv * bu2f((us)wv[j]);
      }
    }
  }
  short8 pk;
#pragma unroll
  for (int j = 0; j < 8; j++) pk[j] = (short)f2bu(acc[j]);
  *(short8*)(edgeT + (size_t)pxg * 64 + c0) = pk;
}

// ---------------- 8. offset conv as MFMA GEMM: K=9x64, N=32(18 used), act=shifted edgeT rows
__global__ __launch_bounds__(256) void k_off_g(const us* edgeT, const us* woff, fp ob,
                                               const float* thick, float* offb) {
  int wave = threadIdx.x >> 6, lane = threadIdx.x & 63;
  int quad = lane >> 4, l16 = lane & 15;
  int pxg0 = blockIdx.x * 64 + wave * 16;
  int b = pxg0 >> 12;
  int pxl = pxg0 + l16;
  int hwl = pxl & 4095;
  int yl = hwl >> 6, xl = hwl & 63;
  floatx4 acc[2];
  acc[0] = (floatx4){0.f, 0.f, 0.f, 0.f};
  acc[1] = (floatx4){0.f, 0.f, 0.f, 0.f};
  const short8 zz = {0, 0, 0, 0, 0, 0, 0, 0};
#pragma unroll
  for (int t = 0; t < 9; t++) {
    int yy = yl + t / 3 - 1, xx = xl + t % 3 - 1;
    bool valid = (yy >= 0 && yy < 64 && xx >= 0 && xx < 64);
    const us* arow = edgeT + ((size_t)(b * NHW + yy * 64 + xx)) * 64;
#pragma unroll
    for (int s = 0; s < 2; s++) {
      short8 act = valid ? ld8(arow + s * 32 + quad * 8) : zz;   // k_dw-style conditional row load
      int kk = t * 64 + s * 32 + quad * 8;
#pragma unroll
      for (int n = 0; n < 2; n++) {
        short8 wf = ld8(woff + (size_t)(n * 16 + l16) * 576 + kk);
        acc[n] = __builtin_amdgcn_mfma_f32_16x16x32_bf16(act, wf, acc[n], 0, 0, 0);
      }
    }
  }
#pragma unroll
  for (int n = 0; n < 2; n++)
#pragma unroll
    for (int r = 0; r < 4; r++) {
      int oc = n * 16 + l16;
      if (oc < 18) {
        int px = pxg0 + quad * 4 + r;
        int hw = px & 4095;
        float v = (acc[n][r] + ob[oc]) * (1.f + 16.f * thick[px]);
        offb[(size_t)(b * 18 + oc) * NHW + hw] = v;
      }
    }
}

// ---------------- 9. MFMA deformable conv (r10 structure; edge residual from edgeT rows)
__global__ __launch_bounds__(256) void k_deform(const float* su, const float* offb,
                                                const us* wbf, fp db,
                                                const us* edgeT, us* dbufT) {
  __shared__ __align__(16) us samT[4][16][72];
  int tid = threadIdx.x;
  int wave = tid >> 6, lane = tid & 63;
  int quad = lane >> 4, l16 = lane & 15;
  int b = blockIdx.x >> 6, row = blockIdx.x & 63;
  const float* sub = su + (size_t)b * 64 * NHW;

  int sp = lane & 15, sq = lane >> 4;
  int hw_s = row * 64 + wave * 16 + sp;
  int x_s = wave * 16 + sp;

  floatx4 acc[4];
#pragma unroll
  for (int a = 0; a < 4; a++) acc[a] = (floatx4){0.f, 0.f, 0.f, 0.f};

  for (int k = 0; k < 9; k++) {
    float dy = offb[((size_t)(b * 18 + 2 * k)) * NHW + hw_s];
    float dx = offb[((size_t)(b * 18 + 2 * k + 1)) * NHW + hw_s];
    float py = (float)(row + k / 3 - 1) + dy;
    float pxf = (float)(x_s + k % 3 - 1) + dx;
    float y0f = floorf(py), x0f = floorf(pxf);
    float wy = py - y0f, wx = pxf - x0f;
    int y0 = (int)y0f, x0 = (int)x0f;
    int y1 = y0 + 1, x1 = x0 + 1;
    float vy0 = (y0 >= 0 && y0 < 64) ? 1.f : 0.f;
    float vy1 = (y1 >= 0 && y1 < 64) ? 1.f : 0.f;
    float vx0 = (x0 >= 0 && x0 < 64) ? 1.f : 0.f;
    float vx1 = (x1 >= 0 && x1 < 64) ? 1.f : 0.f;
    float w00 = (1.f - wy) * (1.f - wx) * vy0 * vx0;
    float w01 = (1.f - wy) * wx * vy0 * vx1;
    float w10 = wy * (1.f - wx) * vy1 * vx0;
    float w11 = wy * wx * vy1 * vx1;
    int y0c = min(63, max(0, y0)), y1c = min(63, max(0, y1));
    int x0c = min(63, max(0, x0)), x1c = min(63, max(0, x1));
    int i00 = y0c * 64 + x0c, i01 = y0c * 64 + x1c;
    int i10 = y1c * 64 + x0c, i11 = y1c * 64 + x1c;

#pragma unroll
    for (int i = 0; i < 16; i += 2) {
      int c0 = sq * 16 + i;
      const float* s0 = sub + (size_t)c0 * NHW;
      const float* s1 = s0 + NHW;
      float v0 = w00 * s0[i00] + w01 * s0[i01] + w10 * s0[i10] + w11 * s0[i11];
      float v1 = w00 * s1[i00] + w01 * s1[i01] + w10 * s1[i10] + w11 * s1[i11];
      unsigned int pk = (unsigned int)f2bu(v0) | ((unsigned int)f2bu(v1) << 16);
      *(unsigned int*)&samT[wave][sp][c0] = pk;
    }

#pragma unroll
    for (int s = 0; s < 2; s++) {
      short8 bfrag = *(const short8*)&samT[wave][l16][s * 32 + quad * 8];
#pragma unroll
      for (int a = 0; a < 4; a++) {
        short8 afrag = ld8(wbf + ((size_t)(k * 64 + a * 16 + l16) * 64 + s * 32 + quad * 8));
        acc[a] = __builtin_amdgcn_mfma_f32_16x16x32_bf16(bfrag, afrag, acc[a], 0, 0, 0);
      }
    }
  }

#pragma unroll
  for (int a = 0; a < 4; a++)
#pragma unroll
    for (int r = 0; r < 4; r++) {
      int oc = a * 16 + l16;
      int pxr = row * 64 + wave * 16 + quad * 4 + r;
      size_t rowi = (size_t)(b * NHW) + pxr;
      float v = acc[a][r] + db[oc] + bu2f(edgeT[rowi * 64 + oc]);
      dbufT[rowi * 64 + oc] = f2bu(v);
    }
}

// ---------------- 10. down GEMM act-first -> ebufT px-major f32 (r11 verbatim)
__global__ __launch_bounds__(256) void k_down_g(const us* x2T, const us* dbufT, const us* wd, fp bias, float* ebufT) {
  int wave = threadIdx.x >> 6, lane = threadIdx.x & 63;
  int quad = lane >> 4, l16 = lane & 15;
  int pxg0 = blockIdx.x * 64 + wave * 16;
  floatx4 acc[4];
#pragma unroll
  for (int m = 0; m < 4; m++) acc[m] = (floatx4){0.f, 0.f, 0.f, 0.f};
  const us* xrow = x2T + (size_t)(pxg0 + l16) * 256 + quad * 8;
#pragma unroll
  for (int k0 = 0; k0 < 256; k0 += 32) {
    short8 act = ld8(xrow + k0);
#pragma unroll
    for (int m = 0; m < 4; m++) {
      short8 wf = ld8(wd + (size_t)(m * 16 + l16) * 320 + k0 + quad * 8);
      acc[m] = __builtin_amdgcn_mfma_f32_16x16x32_bf16(act, wf, acc[m], 0, 0, 0);
    }
  }
  const us* drow = dbufT + (size_t)(pxg0 + l16) * 64 + quad * 8;
#pragma unroll
  for (int k0 = 0; k0 < 64; k0 += 32) {
    short8 act = ld8(drow + k0);
#pragma unroll
    for (int m = 0; m < 4; m++) {
      short8 wf = ld8(wd + (size_t)(m * 16 + l16) * 320 + 256 + k0 + quad * 8);
      acc[m] = __builtin_amdgcn_mfma_f32_16x16x32_bf16(act, wf, acc[m], 0, 0, 0);
    }
  }
#pragma unroll
  for (int m = 0; m < 4; m++)
#pragma unroll
    for (int r = 0; r < 4; r++) {
      int px = pxg0 + quad * 4 + r;
      int oc = m * 16 + l16;
      ebufT[(size_t)px * 64 + oc] = acc[m][r] + bias[oc];
    }
}

// ---------------- 11. LayerNorm px-major (r11 verbatim)
__global__ __launch_bounds__(256) void k_ln(const float* eT, fp g, fp bt, us* hnT) {
  int idx = blockIdx.x * 256 + threadIdx.x;
  if (idx >= NB * NHW) return;
  const float* p = eT + (size_t)idx * 64;
  float v[64];
  float s = 0.f;
#pragma unroll
  for (int i = 0; i < 16; i++) {
    float4 t = ((const float4*)p)[i];
    v[i * 4] = t.x; v[i * 4 + 1] = t.y; v[i * 4 + 2] = t.z; v[i * 4 + 3] = t.w;
    s += t.x + t.y + t.z + t.w;
  }
  float mu = s * (1.f / 64.f);
  float q = 0.f;
#pragma unroll
  for (int c = 0; c < 64; c++) { float d = v[c] - mu; q += d * d; }
  float rstd = rsqrtf(q * (1.f / 64.f) + 1e-5f);
  us* o = hnT + (size_t)idx * 64;
#pragma unroll
  for (int j = 0; j < 8; j++) {
    short8 pk;
#pragma unroll
    for (int t = 0; t < 8; t++) {
      int c = j * 8 + t;
      pk[t] = (short)f2bu((v[c] - mu) * rstd * g[c] + bt[c]);
    }
    *(short8*)(o + j * 8) = pk;
  }
}

// ---------------- 12. mlp1 GEMM act-first (r11 verbatim)
__global__ __launch_bounds__(256) void k_mlp1_g(const us* hnT, const us* wm1, fp bias, us* h1T) {
  int wave = threadIdx.x >> 6, lane = threadIdx.x & 63;
  int quad = lane >> 4, l16 = lane & 15;
  int pxg0 = blockIdx.x * 64 + wave * 16;
  floatx4 acc[16];
#pragma unroll
  for (int m = 0; m < 16; m++) acc[m] = (floatx4){0.f, 0.f, 0.f, 0.f};
  const us* hrow = hnT + (size_t)(pxg0 + l16) * 64 + quad * 8;
#pragma unroll
  for (int k0 = 0; k0 < 64; k0 += 32) {
    short8 act = ld8(hrow + k0);
#pragma unroll
    for (int m = 0; m < 16; m++) {
      short8 wf = ld8(wm1 + (size_t)(m * 16 + l16) * 64 + k0 + quad * 8);
      acc[m] = __builtin_amdgcn_mfma_f32_16x16x32_bf16(act, wf, acc[m], 0, 0, 0);
    }
  }
#pragma unroll
  for (int m = 0; m < 16; m++)
#pragma unroll
    for (int r = 0; r < 4; r++) {
      int px = pxg0 + quad * 4 + r;
      int oc = m * 16 + l16;
      h1T[(size_t)px * 256 + oc] = f2bu(gelu_ex(acc[m][r] + bias[oc]));
    }
}

// ---------------- 13. depthwise 3x3 + GELU, px-major (r12 verbatim)
__global__ __launch_bounds__(256) void k_dw(const us* h1T, const us* wdwT, fp bias, us* h2T) {
  int idx = blockIdx.x * 256 + threadIdx.x;   // NB*NHW*32
  int cb = idx & 31, pxg = idx >> 5;
  int b = pxg >> 12, hw = pxg & 4095;
  int y = hw >> 6, x = hw & 63;
  int c0 = cb * 8;
  float4 b0 = *(const float4*)(bias + c0);
  float4 b1 = *(const float4*)(bias + c0 + 4);
  float acc[8] = {b0.x, b0.y, b0.z, b0.w, b1.x, b1.y, b1.z, b1.w};
#pragma unroll
  for (int ky = 0; ky < 3; ky++) {
#pragma unroll
    for (int kx = 0; kx < 3; kx++) {
      int tap = ky * 3 + kx;
      short8 wv = ld8(wdwT + tap * 256 + c0);
      int yy = y + ky - 1, xx = x + kx - 1;
      if (yy >= 0 && yy < 64 && xx >= 0 && xx < 64) {
        short8 vv = ld8(h1T + ((size_t)(b * NHW + yy * 64 + xx)) * 256 + c0);
#pragma unroll
        for (int j = 0; j < 8; j++)
          acc[j] += bu2f((us)vv[j]) * bu2f((us)wv[j]);
      }
    }
  }
  short8 pk;
#pragma unroll
  for (int j = 0; j < 8; j++) pk[j] = (short)f2bu(gelu_ex(acc[j]));
  *(short8*)(h2T + (size_t)pxg * 256 + c0) = pk;
}

// ---------------- 14. mlp2 GEMM act-first (r11 verbatim)
__global__ __launch_bounds__(256) void k_mlp2_g(const us* h2T, const us* wm2, fp bias, const float* ebufT, us* tbufT) {
  int wave = threadIdx.x >> 6, lane = threadIdx.x & 63;
  int quad = lane >> 4, l16 = lane & 15;
  int pxg0 = blockIdx.x * 64 + wave * 16;
  floatx4 acc[4];
#pragma unroll
  for (int m = 0; m < 4; m++) acc[m] = (floatx4){0.f, 0.f, 0.f, 0.f};
  const us* hrow = h2T + (size_t)(pxg0 + l16) * 256 + quad * 8;
#pragma unroll
  for (int k0 = 0; k0 < 256; k0 += 32) {
    short8 act = ld8(hrow + k0);
#pragma unroll
    for (int m = 0; m < 4; m++) {
      short8 wf = ld8(wm2 + (size_t)(m * 16 + l16) * 256 + k0 + quad * 8);
      acc[m] = __builtin_amdgcn_mfma_f32_16x16x32_bf16(act, wf, acc[m], 0, 0, 0);
    }
  }
#pragma unroll
  for (int m = 0; m < 4; m++)
#pragma unroll
    for (int r = 0; r < 4; r++) {
      int px = pxg0 + quad * 4 + r;
      int oc = m * 16 + l16;
      size_t oidx = (size_t)px * 64 + oc;
      tbufT[oidx] = f2bu(acc[m][r] + bias[oc] + ebufT[oidx]);
    }
}

// ---------------- 15. up GEMM W-first (r11 verbatim)
__global__ __launch_bounds__(256) void k_up_g(const us* tbufT, const us* wu, fp bias, float* out) {
  int wave = threadIdx.x >> 6, lane = threadIdx.x & 63;
  int quad = lane >> 4, l16 = lane & 15;
  int pxg0 = blockIdx.x * 64 + wave * 16;
  int b = pxg0 >> 12, hw0 = pxg0 & 4095;
  floatx4 acc[16];
#pragma unroll
  for (int m = 0; m < 16; m++) acc[m] = (floatx4){0.f, 0.f, 0.f, 0.f};
  const us* trow = tbufT + (size_t)(pxg0 + l16) * 64 + quad * 8;
#pragma unroll
  for (int k0 = 0; k0 < 64; k0 += 32) {
    short8 bf = ld8(trow + k0);
#pragma unroll
    for (int m = 0; m < 16; m++) {
      short8 af = ld8(wu + (size_t)(m * 16 + l16) * 64 + k0 + quad * 8);
      acc[m] = __builtin_amdgcn_mfma_f32_16x16x32_bf16(af, bf, acc[m], 0, 0, 0);
    }
  }
#pragma unroll
  for (int m = 0; m < 16; m++)
#pragma unroll
    for (int r = 0; r < 4; r++) {
      int oc = m * 16 + quad * 4 + r;
      out[(size_t)(b * 256 + oc) * NHW + hw0 + l16] = acc[m][r] + bias[oc];
    }
}

extern "C" void kernel_launch(void* const* d_in, const int* in_sizes, int n_in,
                              void* d_out, int out_size, void* d_ws, size_t ws_size,
                              hipStream_t stream) {
  fp x = (fp)d_in[0], skip = (fp)d_in[1], qkv_w = (fp)d_in[2], qkv_b = (fp)d_in[3],
     proj_w = (fp)d_in[4], proj_b = (fp)d_in[5], edge_w = (fp)d_in[6], thick_w = (fp)d_in[7],
     thick_b = (fp)d_in[8], off_w = (fp)d_in[9], off_b = (fp)d_in[10], deform_w = (fp)d_in[11],
     deform_b = (fp)d_in[12], ln_g = (fp)d_in[13], ln_b = (fp)d_in[14], mlp1_w = (fp)d_in[15],
     mlp1_b = (fp)d_in[16], dw_w = (fp)d_in[17], dw_b = (fp)d_in[18], mlp2_w = (fp)d_in[19],
     mlp2_b = (fp)d_in[20], down_w = (fp)d_in[21], down_b = (fp)d_in[22], up_w = (fp)d_in[23],
     up_b = (fp)d_in[24];

  float* ws = (float*)d_ws;
  // ---- r12 layout (31.25 MB proven); wc 99,136 shorts, ml 131,072 f32 ----
  float* su    = ws + 0;              // f32 [0, 1048576)
  us* qkvb  = (us*)(ws + 1048576);    // bf16 [1048576, 1835008)
  us* avb   = (us*)(ws + 1835008);    // bf16 524,288 elems [1835008, 2097152)
  us* wc    = (us*)(ws + 2097152);    // bf16 99,136 elems  [2097152, 2146720)
  float* ml = ws + 2146720;           // f32 131,072        [2146720, 2277792)
  us* x2T   = (us*)(ws + 3145728);    // bf16 px-major [b*N][256]: [3145728, 5242880)
  us* edgeT = (us*)(ws + 5242880);    // bf16 px-major [b*N][64]: 524,288 slots of 1M region
  float* offb  = ws + 6291456;        // f32 [6291456, 6586368)
  float* sm    = ws + 6586368;        // f32 (dead after k_edge_px)
  float* thick = ws + 6602752;        // f32 (dead after k_off_g)
  us* dbufT = (us*)(ws + 6619136);    // bf16 px-major [b*N][64]: [6619136, 7143424)
  float* ebufT = ws + 7143424;        // f32 px-major [b*N][64]: [7143424, 8192000)
  // aliases of dead/late regions:
  us* xT   = x2T;                     // xT live #3..#7; proj_g updates in-place
  us* wq   = dbufT;                   // wq live #0..#4; dbufT written later — disjoint
  us* wbf  = (us*)sm;                 // deform weights, written after k_off_g
  us* Opart = (us*)ebufT;             // attn bf16 partials: 2,097,152 shorts = exact region
  us* hnT  = qkvb;                    // qkvb dead after k_attn
  us* h1T  = x2T;                     // x2T dead after k_down_g
  us* h2T  = (us*)ws;                 // [0, 2097152) slots all dead by k_dw
  us* tbufT = edgeT;                  // edgeT dead after k_deform

  dim3 blk(256);
  k_wq<<<96, blk, 0, stream>>>(qkv_w, wq);
  k_wcast<<<388, blk, 0, stream>>>(proj_w, mlp1_w, down_w, mlp2_w, up_w, dw_w, edge_w, off_w, wc);
  k_upsample<<<(NB * 64 * NHW) / 256, blk, 0, stream>>>(skip, su);
  k_xpose<<<1024, blk, 0, stream>>>(x, xT);
  k_qkv_g<<<(NB * NHW) / 64, blk, 0, stream>>>(xT, wq, qkv_b, qkvb);
  k_attn<<<(NB * NHW) / 16, blk, 0, stream>>>(qkvb, Opart, ml);
  k_merge<<<(NB * NHW * 32) / 256, blk, 0, stream>>>(Opart, ml, avb);
  k_proj_g<<<(NB * NHW) / 64, blk, 0, stream>>>(avb, xT, wc, proj_b, x2T);
  k_meanthick<<<(NB * NHW) / 256, blk, 0, stream>>>(su, thick_w, thick_b, sm, thick);
  k_edge_px<<<(NB * NHW * 8) / 256, blk, 0, stream>>>(sm, wc + 80128, edgeT);
  k_off_g<<<(NB * NHW) / 64, blk, 0, stream>>>(edgeT, wc + 80704, off_b, thick, offb);
  k_wprep<<<144, blk, 0, stream>>>(deform_w, wbf);
  k_deform<<<NB * 64, blk, 0, stream>>>(su, offb, wbf, deform_b, edgeT, dbufT);
  k_down_g<<<(NB * NHW) / 64, blk, 0, stream>>>(x2T, dbufT, wc + 24576, down_b, ebufT);
  k_ln<<<(NB * NHW) / 256, blk, 0, stream>>>(ebufT, ln_g, ln_b, hnT);
  k_mlp1_g<<<(NB * NHW) / 64, blk, 0, stream>>>(hnT, wc + 8192, mlp1_b, h1T);
  k_dw<<<(NB * NHW * 32) / 256, blk, 0, stream>>>(h1T, wc + 77824, dw_b, h2T);
  k_mlp2_g<<<(NB * NHW) / 64, blk, 0, stream>>>(h2T, wc + 45056, mlp2_b, ebufT, tbufT);
  k_up_g<<<(NB * NHW) / 64, blk, 0, stream>>>(tbufT, wc + 61440, up_b, (float*)d_out);
}